// Round 3
// baseline (31286.121 us; speedup 1.0000x reference)
//
#include <hip/hip_runtime.h>
#include <cstdint>
#include <cstddef>

#define B_ 64
#define S_ 512
#define IN_ 512
#define H_ 1024
#define NH_ 4
#define HD_ 256
#define A_ 18
#define HID_ 1024
#define TCH_ 128            // scan time-chunk
#define NCH_ (S_ / TCH_)    // 4 chunks

// ---------------- helpers ----------------
__device__ __forceinline__ unsigned short f2bf(float f) {
  union { float f; unsigned u; } c; c.f = f;
  unsigned r = c.u + 0x7FFFu + ((c.u >> 16) & 1u);  // RNE
  return (unsigned short)(r >> 16);
}
__device__ __forceinline__ float bf2f(unsigned short h) {
  union { unsigned u; float f; } c; c.u = ((unsigned)h) << 16;
  return c.f;
}

// ---------------- R transcode: fp32 [nh][d][g][e] -> bf16 [nh][d4][g*256+e][4] ----------------
__global__ __launch_bounds__(256) void rtrans_k(const float* __restrict__ R,
                                                unsigned short* __restrict__ Rb) {
  const int i = blockIdx.x * 256 + threadIdx.x;   // [0, 262144)
  const int t = i & 1023;            // g*256+e
  const int d4 = (i >> 10) & 63;
  const int nh = i >> 16;
  const int g = t >> 8, e = t & 255;
  const float* rp = R + (((size_t)nh * 256 + 4 * d4) * 4 + g) * 256 + e;  // p-stride = 1024
  ushort4 o = {f2bf(rp[0]), f2bf(rp[1024]), f2bf(rp[2048]), f2bf(rp[3072])};
  *(ushort4*)(Rb + (size_t)i * 4) = o;
}

// ---------------- row stats for LN1 fusion (xproj is bf16) ----------------
__global__ __launch_bounds__(256) void rowstats_k(const unsigned short* __restrict__ x,
                                                  float* __restrict__ rs) {
  const int r = blockIdx.x, tid = threadIdx.x;
  const int lane = tid & 63, wave = tid >> 6;
  ushort4 u = *(const ushort4*)(x + (size_t)r * H_ + tid * 4);
  float v0 = bf2f(u.x), v1 = bf2f(u.y), v2 = bf2f(u.z), v3 = bf2f(u.w);
  float s1 = v0 + v1 + v2 + v3;
  float s2 = v0 * v0 + v1 * v1 + v2 * v2 + v3 * v3;
#pragma unroll
  for (int off = 32; off; off >>= 1) { s1 += __shfl_xor(s1, off); s2 += __shfl_xor(s2, off); }
  __shared__ float a1[4], a2[4];
  if (lane == 0) { a1[wave] = s1; a2[wave] = s2; }
  __syncthreads();
  if (tid == 0) {
    float S1 = a1[0] + a1[1] + a1[2] + a1[3];
    float S2 = a2[0] + a2[1] + a2[2] + a2[3];
    float mu = S1 * (1.f / H_);
    float var = S2 * (1.f / H_) - mu * mu;
    rs[r * 2] = mu;
    rs[r * 2 + 1] = rsqrtf(var + 1e-5f);
  }
}

// ---------------- generic tiled GEMM, fp32 math, bf16 out ----------------
template <bool TRANSB, bool ABF16, bool LNA, bool RELU, int OUTMODE>
__global__ __launch_bounds__(256) void gemm_k(
    const void* __restrict__ Av, const float* __restrict__ Wt,
    const float* __restrict__ bias, const float* __restrict__ rs,
    const float* __restrict__ lnw, unsigned short* __restrict__ Cb,
    int K, int lda, int ldc, int chunk) {
  __shared__ float As[16][132];
  __shared__ float Bs[16][132];
  const int tid = threadIdx.x;
  const int tx = tid & 15, ty = tid >> 4;
  const int col0 = blockIdx.y * 128;
  int aoff = 0, nh = 0, g = 0;
  const float* W = Wt;
  if constexpr (OUTMODE == 1) {
    int z = blockIdx.z; nh = z >> 2; g = z & 3;
    aoff = nh * HD_;
    W = Wt + (size_t)(g * NH_ + nh) * HD_ * HD_;
  }
  auto arow = [&](int mm) -> int {
    if constexpr (OUTMODE == 1) return (int)blockIdx.x * 512 + chunk * TCH_ + mm;
    else return (int)blockIdx.x * 128 + mm;
  };
  float acc[8][8];
#pragma unroll
  for (int i = 0; i < 8; ++i)
#pragma unroll
    for (int j = 0; j < 8; ++j) acc[i][j] = 0.f;

  for (int k0 = 0; k0 < K; k0 += 16) {
    {  // A tile: As[k][m]
      const int m = tid >> 2;
      const int kq = (tid & 3) * 4;
#pragma unroll
      for (int half = 0; half < 2; ++half) {
        int mm = m + half * 64;
        int rg = arow(mm);
        float av[4];
        if constexpr (ABF16) {
          ushort4 u = *(const ushort4*)((const unsigned short*)Av + (size_t)rg * lda + aoff + k0 + kq);
          av[0] = bf2f(u.x); av[1] = bf2f(u.y); av[2] = bf2f(u.z); av[3] = bf2f(u.w);
        } else {
          float4 f = *(const float4*)((const float*)Av + (size_t)rg * lda + aoff + k0 + kq);
          av[0] = f.x; av[1] = f.y; av[2] = f.z; av[3] = f.w;
        }
        if constexpr (LNA) {
          float mu = rs[rg * 2], rstd = rs[rg * 2 + 1];
#pragma unroll
          for (int j = 0; j < 4; ++j) av[j] = (av[j] - mu) * rstd * lnw[aoff + k0 + kq + j];
        }
#pragma unroll
        for (int j = 0; j < 4; ++j) As[kq + j][mm] = av[j];
      }
    }
    // B tile: Bs[k][n]
    if constexpr (TRANSB) {
      const int nn0 = tid >> 2;
      const int kq = (tid & 3) * 4;
#pragma unroll
      for (int half = 0; half < 2; ++half) {
        int nn = nn0 + half * 64;
        float4 wv = *(const float4*)(W + (size_t)(col0 + nn) * K + k0 + kq);
        Bs[kq + 0][nn] = wv.x; Bs[kq + 1][nn] = wv.y;
        Bs[kq + 2][nn] = wv.z; Bs[kq + 3][nn] = wv.w;
      }
    } else {
      const int kk = tid >> 4;
      const int nn = (tid & 15) * 8;
      const float* wp = W + (size_t)(k0 + kk) * 256 + col0 + nn;
      float4 w0 = *(const float4*)wp;
      float4 w1 = *(const float4*)(wp + 4);
      *(float4*)&Bs[kk][nn] = w0;
      *(float4*)&Bs[kk][nn + 4] = w1;
    }
    __syncthreads();
#pragma unroll
    for (int k = 0; k < 16; ++k) {
      float4 a0 = *(const float4*)&As[k][ty * 4];
      float4 a1 = *(const float4*)&As[k][ty * 4 + 64];
      float4 b0 = *(const float4*)&Bs[k][tx * 4];
      float4 b1 = *(const float4*)&Bs[k][tx * 4 + 64];
      float av[8] = {a0.x, a0.y, a0.z, a0.w, a1.x, a1.y, a1.z, a1.w};
      float bv[8] = {b0.x, b0.y, b0.z, b0.w, b1.x, b1.y, b1.z, b1.w};
#pragma unroll
      for (int i = 0; i < 8; ++i)
#pragma unroll
        for (int j = 0; j < 8; ++j) acc[i][j] = fmaf(av[i], bv[j], acc[i][j]);
    }
    __syncthreads();
  }
  if constexpr (OUTMODE == 0) {
    float4 bia0 = {0, 0, 0, 0}, bia1 = {0, 0, 0, 0};
    if (bias) {
      bia0 = *(const float4*)(bias + col0 + tx * 4);
      bia1 = *(const float4*)(bias + col0 + tx * 4 + 64);
    }
#pragma unroll
    for (int i = 0; i < 8; ++i) {
      int r = arow(ty * 4 + (i & 3) + (i >> 2) * 64);
      float v[8] = {acc[i][0] + bia0.x, acc[i][1] + bia0.y, acc[i][2] + bia0.z, acc[i][3] + bia0.w,
                    acc[i][4] + bia1.x, acc[i][5] + bia1.y, acc[i][6] + bia1.z, acc[i][7] + bia1.w};
      if constexpr (RELU) {
#pragma unroll
        for (int j = 0; j < 8; ++j) v[j] = fmaxf(v[j], 0.f);
      }
      ushort4 s0 = {f2bf(v[0]), f2bf(v[1]), f2bf(v[2]), f2bf(v[3])};
      ushort4 s1 = {f2bf(v[4]), f2bf(v[5]), f2bf(v[6]), f2bf(v[7])};
      *(ushort4*)(Cb + (size_t)r * ldc + col0 + tx * 4) = s0;
      *(ushort4*)(Cb + (size_t)r * ldc + col0 + tx * 4 + 64) = s1;
    }
  } else {
    // gx chunk: idx = ((sl*64+b)*4+nh)*1024 + g*256 + e ; sl = tile-local row
    const int b = blockIdx.x;
#pragma unroll
    for (int i = 0; i < 8; ++i) {
      int sl = ty * 4 + (i & 3) + (i >> 2) * 64;
      size_t base = (size_t)(sl * 64 + b) * 4096 + nh * 1024 + g * 256;
#pragma unroll
      for (int q = 0; q < 2; ++q) {
        int e = col0 + tx * 4 + q * 64;
        ushort4 pv = {f2bf(acc[i][q * 4 + 0]), f2bf(acc[i][q * 4 + 1]),
                      f2bf(acc[i][q * 4 + 2]), f2bf(acc[i][q * 4 + 3])};
        *(ushort4*)(Cb + base + e) = pv;
      }
    }
  }
}

// ---------------- sLSTM scan chunk: R bf16 streamed from L2 (shared across blocks) ----------------
__global__ __launch_bounds__(1024) void scan_k(
    const unsigned short* __restrict__ gxc, const unsigned short* __restrict__ Rb,
    const float* __restrict__ bgates, float* __restrict__ state,
    unsigned short* __restrict__ y, int chunk) {
  const int tid = threadIdx.x;
  const int nh = blockIdx.x & 3, b = blockIdx.x >> 2;
  const int g = tid >> 8;            // gate owned by this column
  __shared__ float hsh[256];
  __shared__ float raw[1024];
  // Rb[nh][d4][t][4]: this thread's column, one ushort4 per 4 d's, stride 1024 ushort4
  const ushort4* rp = (const ushort4*)Rb + (size_t)nh * 65536 + tid;
  const float bg = bgates[g * H_ + nh * HD_ + (tid & 255)];
  float creg = 0.f, nreg = 0.f, mreg = 0.f, hval = 0.f;
  size_t sb = (size_t)b * H_ + nh * HD_ + (tid & 255);
  if (tid < 256) {
    hval = state[sb];
    creg = state[65536 + sb];
    nreg = state[2 * 65536 + sb];
    mreg = state[3 * 65536 + sb];
    hsh[tid] = hval;
  }
  const unsigned short* gp = gxc + (size_t)b * 4096 + nh * 1024 + tid;
  unsigned short* yp = y + (size_t)chunk * TCH_ * 65536 + b * H_ + nh * HD_;
  unsigned short gcur = gp[0];
  __syncthreads();
  for (int t = 0; t < TCH_; ++t) {
    float acc = bf2f(gcur) + bg;
    if (t < TCH_ - 1) gcur = gp[(size_t)(t + 1) * 262144];  // prefetch under matvec
    const float4* h4 = (const float4*)hsh;
#pragma unroll
    for (int d4 = 0; d4 < 64; ++d4) {
      ushort4 u = rp[(size_t)d4 * 1024];   // L2-resident (2 MB distinct working set)
      float4 hv = h4[d4];                  // LDS broadcast (same addr across wave)
      acc = fmaf(hv.x, bf2f(u.x), acc);
      acc = fmaf(hv.y, bf2f(u.y), acc);
      acc = fmaf(hv.z, bf2f(u.z), acc);
      acc = fmaf(hv.w, bf2f(u.w), acc);
    }
    raw[tid] = acc;
    __syncthreads();
    if (tid < 256) {
      float iraw = raw[tid], fraw = raw[256 + tid];
      float zraw = raw[512 + tid], oraw = raw[768 + tid];
      float ls = -log1pf(expf(-fabsf(fraw)));
      if (fraw < 0.f) ls += fraw;                   // log_sigmoid(fraw)
      float lfm = mreg + ls;
      float mnew = fmaxf(iraw, lfm);
      float iv = expf(iraw - mnew);
      float fv = expf(lfm - mnew);
      creg = fv * creg + iv * tanhf(zraw);
      nreg = fv * nreg + iv;
      mreg = mnew;
      hval = creg / nreg / (1.f + expf(-oraw));
      hsh[tid] = hval;
      yp[(size_t)t * 65536 + tid] = f2bf(hval);     // y[s][b][h] bf16
    }
    __syncthreads();
  }
  if (tid < 256) {
    state[sb] = hval;
    state[65536 + sb] = creg;
    state[2 * 65536 + sb] = nreg;
    state[3 * 65536 + sb] = mreg;
  }
}

// ---------------- groupnorm + residual + post LN (bf16 in/out) ----------------
__global__ __launch_bounds__(256) void post_k(
    const unsigned short* __restrict__ y, const unsigned short* __restrict__ xp,
    const float* __restrict__ gnw, const float* __restrict__ lpw,
    unsigned short* __restrict__ outb) {
  const int r = blockIdx.x;            // r = b*512 + s
  const int b = r >> 9, s = r & 511;
  const int tid = threadIdx.x;
  const int lane = tid & 63, wave = tid >> 6;
  ushort4 yu = *(const ushort4*)(y + (size_t)(s * 64 + b) * H_ + tid * 4);
  float v[4] = {bf2f(yu.x), bf2f(yu.y), bf2f(yu.z), bf2f(yu.w)};
  float s1 = v[0] + v[1] + v[2] + v[3];
  float s2 = v[0] * v[0] + v[1] * v[1] + v[2] * v[2] + v[3] * v[3];
#pragma unroll
  for (int off = 32; off; off >>= 1) { s1 += __shfl_xor(s1, off); s2 += __shfl_xor(s2, off); }
  float mu = s1 * (1.f / HD_);
  float rstd = rsqrtf(s2 * (1.f / HD_) - mu * mu + 1e-5f);
  float4 g4 = *(const float4*)(gnw + tid * 4);
  ushort4 xu = *(const ushort4*)(xp + (size_t)r * H_ + tid * 4);
  float o[4];
  o[0] = fmaf((v[0] - mu) * rstd, g4.x, bf2f(xu.x));
  o[1] = fmaf((v[1] - mu) * rstd, g4.y, bf2f(xu.y));
  o[2] = fmaf((v[2] - mu) * rstd, g4.z, bf2f(xu.z));
  o[3] = fmaf((v[3] - mu) * rstd, g4.w, bf2f(xu.w));
  float t1 = o[0] + o[1] + o[2] + o[3];
  float t2 = o[0] * o[0] + o[1] * o[1] + o[2] * o[2] + o[3] * o[3];
#pragma unroll
  for (int off = 32; off; off >>= 1) { t1 += __shfl_xor(t1, off); t2 += __shfl_xor(t2, off); }
  __shared__ float a1[4], a2[4];
  if (lane == 0) { a1[wave] = t1; a2[wave] = t2; }
  __syncthreads();
  float T1 = a1[0] + a1[1] + a1[2] + a1[3];
  float T2 = a2[0] + a2[1] + a2[2] + a2[3];
  float MU = T1 * (1.f / H_);
  float RS = rsqrtf(T2 * (1.f / H_) - MU * MU + 1e-5f);
  float4 w4 = *(const float4*)(lpw + tid * 4);
  ushort4 res = {f2bf((o[0] - MU) * RS * w4.x), f2bf((o[1] - MU) * RS * w4.y),
                 f2bf((o[2] - MU) * RS * w4.z), f2bf((o[3] - MU) * RS * w4.w)};
  *(ushort4*)(outb + (size_t)r * H_ + tid * 4) = res;
}

// ---------------- logits + value heads (bf16 in, fp32 out) ----------------
__global__ __launch_bounds__(256) void heads_k(
    const unsigned short* __restrict__ hp, const unsigned short* __restrict__ hv,
    const float* __restrict__ Wact, const float* __restrict__ bact,
    const float* __restrict__ Wv, const float* __restrict__ bv,
    float* __restrict__ dout) {
  const int lane = threadIdx.x & 63, wave = threadIdx.x >> 6;
  const int r = blockIdx.x * 4 + wave;
  const unsigned short* hpr = hp + (size_t)r * HID_;
  const unsigned short* hvr = hv + (size_t)r * HID_;
  float acc[A_];
#pragma unroll
  for (int j = 0; j < A_; ++j) acc[j] = 0.f;
  float accv = 0.f;
  for (int i = 0; i < 16; ++i) {
    int k = i * 64 + lane;
    float hpv = bf2f(hpr[k]);
    float hvv = bf2f(hvr[k]);
#pragma unroll
    for (int j = 0; j < A_; ++j) acc[j] = fmaf(hpv, Wact[j * HID_ + k], acc[j]);
    accv = fmaf(hvv, Wv[k], accv);
  }
#pragma unroll
  for (int j = 0; j < A_; ++j)
#pragma unroll
    for (int off = 32; off; off >>= 1) acc[j] += __shfl_xor(acc[j], off);
#pragma unroll
  for (int off = 32; off; off >>= 1) accv += __shfl_xor(accv, off);
  if (lane == 0) {
#pragma unroll
    for (int j = 0; j < A_; ++j) dout[(size_t)r * A_ + j] = acc[j] + bact[j];
    dout[589824 + r] = accv + bv[0];
  }
}

// ---------------- launch ----------------
extern "C" void kernel_launch(void* const* d_in, const int* in_sizes, int n_in,
                              void* d_out, int out_size, void* d_ws, size_t ws_size,
                              hipStream_t stream) {
  const float* obs   = (const float*)d_in[0];
  const float* st    = (const float*)d_in[1];
  const float* W_in  = (const float*)d_in[2];
  const float* b_in  = (const float*)d_in[3];
  const float* ln1w  = (const float*)d_in[4];
  const float* wg    = (const float*)d_in[5];
  const float* R     = (const float*)d_in[6];
  const float* bgat  = (const float*)d_in[7];
  const float* gnw   = (const float*)d_in[8];
  const float* lpw   = (const float*)d_in[9];
  const float* W_hid = (const float*)d_in[10];
  const float* b_hid = (const float*)d_in[11];
  const float* W_pol = (const float*)d_in[12];
  const float* b_pol = (const float*)d_in[13];
  const float* W_val = (const float*)d_in[14];
  const float* b_val = (const float*)d_in[15];
  const float* W_act = (const float*)d_in[16];
  const float* b_act = (const float*)d_in[17];
  const float* W_v   = (const float*)d_in[18];
  const float* b_v   = (const float*)d_in[19];

  // Workspace layout (bf16 big buffers, heavy overlay):
  //  A [0,        67108864): xproj bf16  -> hh bf16
  //  B [67108864, 134217728): gx chunk bf16 (T=128) -> outb bf16 -> hv bf16
  //  C [134217728,201326592): y bf16 -> hp bf16
  //  ST[201326592,202375168): scan state fp32 (h,c,n,m) 4x64x1024
  //  RS[202375168,202899456): LN1 row stats
  //  RB[202899456,204996608): R bf16 transcoded [nh][d4][1024][4]
  const size_t NEEDED = 204996608;
  if (ws_size < NEEDED) return;  // diagnostic: clean absmax-fail => ws too small
  char* ws = (char*)d_ws;
  unsigned short* xproj = (unsigned short*)(ws + 0);
  unsigned short* gxc   = (unsigned short*)(ws + 67108864);
  unsigned short* ybuf  = (unsigned short*)(ws + 134217728);
  float* statebuf       = (float*)(ws + 201326592);
  float* rstat          = (float*)(ws + 202375168);
  unsigned short* Rb    = (unsigned short*)(ws + 202899456);
  unsigned short* outb  = gxc;    // after last scan chunk
  unsigned short* hh    = xproj;  // after post_k
  unsigned short* hp    = ybuf;   // y dead after post_k
  unsigned short* hv    = gxc;    // after MLP1 consumed outb
  float* dout = (float*)d_out;

  // 0. seed scan state + transcode R to bf16
  hipMemcpyAsync(statebuf, st, 4 * 65536 * sizeof(float), hipMemcpyDeviceToDevice, stream);
  rtrans_k<<<1024, 256, 0, stream>>>(R, Rb);
  // 1. x_proj = obs @ W_in^T + b_in   (M=32768,N=1024,K=512) -> bf16
  gemm_k<true, false, false, false, 0><<<dim3(256, 8), 256, 0, stream>>>(
      obs, W_in, b_in, nullptr, nullptr, xproj, 512, 512, 1024, 0);
  // 2. LN1 row stats
  rowstats_k<<<32768, 256, 0, stream>>>(xproj, rstat);
  // 3+4. per time-chunk: gate GEMM -> scan
  for (int c = 0; c < NCH_; ++c) {
    gemm_k<false, true, true, false, 1><<<dim3(64, 2, 16), 256, 0, stream>>>(
        xproj, wg, nullptr, rstat, ln1w, gxc, 256, 1024, 0, c);
    scan_k<<<256, 1024, 0, stream>>>(gxc, Rb, bgat, statebuf, ybuf, c);
  }
  // 5. groupnorm + residual + post LN
  post_k<<<32768, 256, 0, stream>>>(ybuf, xproj, gnw, lpw, outb);
  // 6-8. hidden / policy / value MLPs (relu)
  gemm_k<true, true, false, true, 0><<<dim3(256, 8), 256, 0, stream>>>(
      outb, W_hid, b_hid, nullptr, nullptr, hh, 1024, 1024, 1024, 0);
  gemm_k<true, true, false, true, 0><<<dim3(256, 8), 256, 0, stream>>>(
      hh, W_pol, b_pol, nullptr, nullptr, hp, 1024, 1024, 1024, 0);
  gemm_k<true, true, false, true, 0><<<dim3(256, 8), 256, 0, stream>>>(
      hh, W_val, b_val, nullptr, nullptr, hv, 1024, 1024, 1024, 0);
  // 9. logits + value
  heads_k<<<8192, 256, 0, stream>>>(hp, hv, W_act, b_act, W_v, b_v, dout);
}

// Round 4
// 11995.285 us; speedup vs baseline: 2.6082x; 2.6082x over previous
//
#include <hip/hip_runtime.h>
#include <cstdint>
#include <cstddef>

#define B_ 64
#define S_ 512
#define IN_ 512
#define H_ 1024
#define NH_ 4
#define HD_ 256
#define A_ 18
#define HID_ 1024
#define TCH_ 128            // scan time-chunk
#define NCH_ (S_ / TCH_)    // 4 chunks

// ---------------- helpers ----------------
__device__ __forceinline__ unsigned short f2bf(float f) {
  union { float f; unsigned u; } c; c.f = f;
  unsigned r = c.u + 0x7FFFu + ((c.u >> 16) & 1u);  // RNE
  return (unsigned short)(r >> 16);
}
__device__ __forceinline__ float bf2f(unsigned short h) {
  union { unsigned u; float f; } c; c.u = ((unsigned)h) << 16;
  return c.f;
}

// ---------------- R transcode: fp32 [nh][d][g][e] -> packed bf16 pairs ----------------
// Rbb[((nh*4+g)*256 + e)*128 + dp] = bf16(R[nh][2dp][g][e]) | bf16(R[nh][2dp+1][g][e])<<16
__global__ __launch_bounds__(256) void rtrans_k(const float* __restrict__ R,
                                                unsigned* __restrict__ Rbb) {
  const int i = blockIdx.x * 256 + threadIdx.x;   // [0, 524288)
  const int dp = i & 127;
  const int e = (i >> 7) & 255;
  const int g = (i >> 15) & 3;
  const int nh = i >> 17;
  const float* rp = R + (((size_t)nh * 256 + 2 * dp) * 4 + g) * 256 + e;  // d-stride 1024
  unsigned lo = f2bf(rp[0]), hi = f2bf(rp[1024]);
  Rbb[i] = lo | (hi << 16);
}

// ---------------- row stats for LN1 fusion (xproj is bf16) ----------------
__global__ __launch_bounds__(256) void rowstats_k(const unsigned short* __restrict__ x,
                                                  float* __restrict__ rs) {
  const int r = blockIdx.x, tid = threadIdx.x;
  const int lane = tid & 63, wave = tid >> 6;
  ushort4 u = *(const ushort4*)(x + (size_t)r * H_ + tid * 4);
  float v0 = bf2f(u.x), v1 = bf2f(u.y), v2 = bf2f(u.z), v3 = bf2f(u.w);
  float s1 = v0 + v1 + v2 + v3;
  float s2 = v0 * v0 + v1 * v1 + v2 * v2 + v3 * v3;
#pragma unroll
  for (int off = 32; off; off >>= 1) { s1 += __shfl_xor(s1, off); s2 += __shfl_xor(s2, off); }
  __shared__ float a1[4], a2[4];
  if (lane == 0) { a1[wave] = s1; a2[wave] = s2; }
  __syncthreads();
  if (tid == 0) {
    float S1 = a1[0] + a1[1] + a1[2] + a1[3];
    float S2 = a2[0] + a2[1] + a2[2] + a2[3];
    float mu = S1 * (1.f / H_);
    float var = S2 * (1.f / H_) - mu * mu;
    rs[r * 2] = mu;
    rs[r * 2 + 1] = rsqrtf(var + 1e-5f);
  }
}

// ---------------- generic tiled GEMM, fp32 math, bf16 out ----------------
template <bool TRANSB, bool ABF16, bool LNA, bool RELU, int OUTMODE>
__global__ __launch_bounds__(256) void gemm_k(
    const void* __restrict__ Av, const float* __restrict__ Wt,
    const float* __restrict__ bias, const float* __restrict__ rs,
    const float* __restrict__ lnw, unsigned short* __restrict__ Cb,
    int K, int lda, int ldc, int chunk) {
  __shared__ float As[16][132];
  __shared__ float Bs[16][132];
  const int tid = threadIdx.x;
  const int tx = tid & 15, ty = tid >> 4;
  const int col0 = blockIdx.y * 128;
  int aoff = 0, nh = 0, g = 0;
  const float* W = Wt;
  if constexpr (OUTMODE == 1) {
    int z = blockIdx.z; nh = z >> 2; g = z & 3;
    aoff = nh * HD_;
    W = Wt + (size_t)(g * NH_ + nh) * HD_ * HD_;
  }
  auto arow = [&](int mm) -> int {
    if constexpr (OUTMODE == 1) return (int)blockIdx.x * 512 + chunk * TCH_ + mm;
    else return (int)blockIdx.x * 128 + mm;
  };
  float acc[8][8];
#pragma unroll
  for (int i = 0; i < 8; ++i)
#pragma unroll
    for (int j = 0; j < 8; ++j) acc[i][j] = 0.f;

  for (int k0 = 0; k0 < K; k0 += 16) {
    {  // A tile: As[k][m]
      const int m = tid >> 2;
      const int kq = (tid & 3) * 4;
#pragma unroll
      for (int half = 0; half < 2; ++half) {
        int mm = m + half * 64;
        int rg = arow(mm);
        float av[4];
        if constexpr (ABF16) {
          ushort4 u = *(const ushort4*)((const unsigned short*)Av + (size_t)rg * lda + aoff + k0 + kq);
          av[0] = bf2f(u.x); av[1] = bf2f(u.y); av[2] = bf2f(u.z); av[3] = bf2f(u.w);
        } else {
          float4 f = *(const float4*)((const float*)Av + (size_t)rg * lda + aoff + k0 + kq);
          av[0] = f.x; av[1] = f.y; av[2] = f.z; av[3] = f.w;
        }
        if constexpr (LNA) {
          float mu = rs[rg * 2], rstd = rs[rg * 2 + 1];
#pragma unroll
          for (int j = 0; j < 4; ++j) av[j] = (av[j] - mu) * rstd * lnw[aoff + k0 + kq + j];
        }
#pragma unroll
        for (int j = 0; j < 4; ++j) As[kq + j][mm] = av[j];
      }
    }
    // B tile: Bs[k][n]
    if constexpr (TRANSB) {
      const int nn0 = tid >> 2;
      const int kq = (tid & 3) * 4;
#pragma unroll
      for (int half = 0; half < 2; ++half) {
        int nn = nn0 + half * 64;
        float4 wv = *(const float4*)(W + (size_t)(col0 + nn) * K + k0 + kq);
        Bs[kq + 0][nn] = wv.x; Bs[kq + 1][nn] = wv.y;
        Bs[kq + 2][nn] = wv.z; Bs[kq + 3][nn] = wv.w;
      }
    } else {
      const int kk = tid >> 4;
      const int nn = (tid & 15) * 8;
      const float* wp = W + (size_t)(k0 + kk) * 256 + col0 + nn;
      float4 w0 = *(const float4*)wp;
      float4 w1 = *(const float4*)(wp + 4);
      *(float4*)&Bs[kk][nn] = w0;
      *(float4*)&Bs[kk][nn + 4] = w1;
    }
    __syncthreads();
#pragma unroll
    for (int k = 0; k < 16; ++k) {
      float4 a0 = *(const float4*)&As[k][ty * 4];
      float4 a1 = *(const float4*)&As[k][ty * 4 + 64];
      float4 b0 = *(const float4*)&Bs[k][tx * 4];
      float4 b1 = *(const float4*)&Bs[k][tx * 4 + 64];
      float av[8] = {a0.x, a0.y, a0.z, a0.w, a1.x, a1.y, a1.z, a1.w};
      float bv[8] = {b0.x, b0.y, b0.z, b0.w, b1.x, b1.y, b1.z, b1.w};
#pragma unroll
      for (int i = 0; i < 8; ++i)
#pragma unroll
        for (int j = 0; j < 8; ++j) acc[i][j] = fmaf(av[i], bv[j], acc[i][j]);
    }
    __syncthreads();
  }
  if constexpr (OUTMODE == 0) {
    float4 bia0 = {0, 0, 0, 0}, bia1 = {0, 0, 0, 0};
    if (bias) {
      bia0 = *(const float4*)(bias + col0 + tx * 4);
      bia1 = *(const float4*)(bias + col0 + tx * 4 + 64);
    }
#pragma unroll
    for (int i = 0; i < 8; ++i) {
      int r = arow(ty * 4 + (i & 3) + (i >> 2) * 64);
      float v[8] = {acc[i][0] + bia0.x, acc[i][1] + bia0.y, acc[i][2] + bia0.z, acc[i][3] + bia0.w,
                    acc[i][4] + bia1.x, acc[i][5] + bia1.y, acc[i][6] + bia1.z, acc[i][7] + bia1.w};
      if constexpr (RELU) {
#pragma unroll
        for (int j = 0; j < 8; ++j) v[j] = fmaxf(v[j], 0.f);
      }
      ushort4 s0 = {f2bf(v[0]), f2bf(v[1]), f2bf(v[2]), f2bf(v[3])};
      ushort4 s1 = {f2bf(v[4]), f2bf(v[5]), f2bf(v[6]), f2bf(v[7])};
      *(ushort4*)(Cb + (size_t)r * ldc + col0 + tx * 4) = s0;
      *(ushort4*)(Cb + (size_t)r * ldc + col0 + tx * 4 + 64) = s1;
    }
  } else {
    // gx chunk: idx = ((sl*64+b)*4+nh)*1024 + g*256 + e ; sl = tile-local row
    const int b = blockIdx.x;
#pragma unroll
    for (int i = 0; i < 8; ++i) {
      int sl = ty * 4 + (i & 3) + (i >> 2) * 64;
      size_t base = (size_t)(sl * 64 + b) * 4096 + nh * 1024 + g * 256;
#pragma unroll
      for (int q = 0; q < 2; ++q) {
        int e = col0 + tx * 4 + q * 64;
        ushort4 pv = {f2bf(acc[i][q * 4 + 0]), f2bf(acc[i][q * 4 + 1]),
                      f2bf(acc[i][q * 4 + 2]), f2bf(acc[i][q * 4 + 3])};
        *(ushort4*)(Cb + base + e) = pv;
      }
    }
  }
}

// ---------------- sLSTM scan: 256 blocks = (nh, e-slice, batch-group), R in regs ----------------
// Block: 256 threads; thread owns gate-column (g = tid>>6, e = esl*64 + (tid&63)) for 4 batches.
// h exchanged across the 4 sibling blocks (same nh,bgrp; different esl) via agent atomics + flags.
__global__ __launch_bounds__(256, 1) void scan_k(
    const unsigned short* __restrict__ gxc, const unsigned* __restrict__ Rbb,
    const float* __restrict__ bgates, float* __restrict__ state,
    unsigned short* __restrict__ y, float* hx, int* flags, int chunk) {
  const int tid = threadIdx.x;
  const int bid = blockIdx.x;
  const int nh = bid >> 6, esl = (bid >> 4) & 3, bgrp = bid & 15;
  const int g = tid >> 6, eo = tid & 63;
  __shared__ float hsh[256][4];     // h[d][b], row = float4
  __shared__ float rawsh[64][17];   // raw[e][b*4+g], padded stride 17

  // R columns into registers: 256 bf16 packed into 128 uints
  unsigned rcol[128];
  {
    const unsigned* rp = Rbb + ((size_t)(nh * 4 + g) * 256 + esl * 64 + eo) * 128;
#pragma unroll
    for (int i = 0; i < 128; ++i) rcol[i] = rp[i];
  }
  const float bg = bgates[g * H_ + nh * HD_ + esl * 64 + eo];

  // owner mapping for pointwise/state: (ob, oe) -> d = esl*64+oe
  const int ob = tid >> 6, oe = tid & 63;
  const int od = esl * 64 + oe;
  const size_t sbase = (size_t)(bgrp * 4 + ob) * H_ + nh * HD_ + od;
  float c_ = state[65536 + sbase];
  float n_ = state[2 * 65536 + sbase];
  float m_ = state[3 * 65536 + sbase];
  float hlast = state[sbase];

  // init full h tile
#pragma unroll
  for (int r = 0; r < 4; ++r) {
    int idx = r * 256 + tid;
    int d = idx >> 2, b = idx & 3;
    hsh[d][b] = state[(size_t)(bgrp * 4 + b) * H_ + nh * HD_ + d];
  }
  __syncthreads();

  const int fbase = (nh * 16 + bgrp) * 4;
  float* hxc = hx + (size_t)(nh * 16 + bgrp) * 1024;  // [256 d][4 b]
  // gx: ((t*64 + bgrp*4+b)*4 + nh)*1024 + g*256 + esl*64 + eo ; b-stride 4096, t-stride 262144
  const unsigned short* gp = gxc + (size_t)(bgrp * 4) * 4096 + nh * 1024 + g * 256 + esl * 64 + eo;
  unsigned short* yp = y + ((size_t)(chunk * TCH_) * 64 + bgrp * 4) * H_ + nh * HD_;

  float g0 = bf2f(gp[0]), g1 = bf2f(gp[4096]), g2 = bf2f(gp[8192]), g3 = bf2f(gp[12288]);

  for (int t = 0; t < TCH_; ++t) {
    float acc0 = g0 + bg, acc1 = g1 + bg, acc2 = g2 + bg, acc3 = g3 + bg;
    if (t < TCH_ - 1) {  // prefetch next step's gx under the matvec
      const unsigned short* gn = gp + (size_t)(t + 1) * 262144;
      g0 = bf2f(gn[0]); g1 = bf2f(gn[4096]); g2 = bf2f(gn[8192]); g3 = bf2f(gn[12288]);
    }
#pragma unroll
    for (int dp = 0; dp < 128; ++dp) {
      unsigned u = rcol[dp];
      float rl = __uint_as_float(u << 16);
      float rh = __uint_as_float(u & 0xffff0000u);
      float4 ha = *(const float4*)&hsh[2 * dp][0];      // uniform addr -> LDS broadcast
      float4 hb = *(const float4*)&hsh[2 * dp + 1][0];
      acc0 = fmaf(rl, ha.x, acc0); acc1 = fmaf(rl, ha.y, acc1);
      acc2 = fmaf(rl, ha.z, acc2); acc3 = fmaf(rl, ha.w, acc3);
      acc0 = fmaf(rh, hb.x, acc0); acc1 = fmaf(rh, hb.y, acc1);
      acc2 = fmaf(rh, hb.z, acc2); acc3 = fmaf(rh, hb.w, acc3);
    }
    rawsh[eo][0 * 4 + g] = acc0;
    rawsh[eo][1 * 4 + g] = acc1;
    rawsh[eo][2 * 4 + g] = acc2;
    rawsh[eo][3 * 4 + g] = acc3;
    __syncthreads();
    // pointwise update for owned (ob, od)
    {
      float iraw = rawsh[oe][ob * 4 + 0];
      float fraw = rawsh[oe][ob * 4 + 1];
      float zraw = rawsh[oe][ob * 4 + 2];
      float oraw = rawsh[oe][ob * 4 + 3];
      float ls = -log1pf(expf(-fabsf(fraw)));
      if (fraw < 0.f) ls += fraw;                 // log_sigmoid(fraw)
      float lfm = m_ + ls;
      float mnew = fmaxf(iraw, lfm);
      float iv = expf(iraw - mnew);
      float fv = expf(lfm - mnew);
      c_ = fv * c_ + iv * tanhf(zraw);
      n_ = fv * n_ + iv;
      m_ = mnew;
      hlast = c_ / n_ / (1.f + expf(-oraw));
      hsh[od][ob] = hlast;
      __hip_atomic_store(&hxc[od * 4 + ob], hlast, __ATOMIC_RELAXED, __HIP_MEMORY_SCOPE_AGENT);
      yp[(size_t)(t * 64 + ob) * H_ + od] = f2bf(hlast);
    }
    __syncthreads();  // barrier drains vmcnt -> hx stores complete before flag
    if (tid == 0)
      __hip_atomic_fetch_add(&flags[fbase + esl], 1, __ATOMIC_RELEASE, __HIP_MEMORY_SCOPE_AGENT);
    const int tgt = chunk * TCH_ + t + 1;
    if (tid < 3) {
      int es = (tid >= esl) ? tid + 1 : tid;
      while (__hip_atomic_load(&flags[fbase + es], __ATOMIC_ACQUIRE, __HIP_MEMORY_SCOPE_AGENT) < tgt) {
        __builtin_amdgcn_s_sleep(1);
      }
    }
    __syncthreads();
    // fill the 3 sibling h-slices (192 d x 4 b = 768 values, 3 per thread)
#pragma unroll
    for (int r = 0; r < 3; ++r) {
      int idx = r * 256 + tid;
      int dof = idx >> 2, b = idx & 3;
      int d = (dof < esl * 64) ? dof : dof + 64;
      hsh[d][b] = __hip_atomic_load(&hxc[d * 4 + b], __ATOMIC_RELAXED, __HIP_MEMORY_SCOPE_AGENT);
    }
    __syncthreads();
  }
  state[sbase] = hlast;
  state[65536 + sbase] = c_;
  state[2 * 65536 + sbase] = n_;
  state[3 * 65536 + sbase] = m_;
}

// ---------------- groupnorm + residual + post LN (bf16 in/out) ----------------
__global__ __launch_bounds__(256) void post_k(
    const unsigned short* __restrict__ y, const unsigned short* __restrict__ xp,
    const float* __restrict__ gnw, const float* __restrict__ lpw,
    unsigned short* __restrict__ outb) {
  const int r = blockIdx.x;            // r = b*512 + s
  const int b = r >> 9, s = r & 511;
  const int tid = threadIdx.x;
  const int lane = tid & 63, wave = tid >> 6;
  ushort4 yu = *(const ushort4*)(y + (size_t)(s * 64 + b) * H_ + tid * 4);
  float v[4] = {bf2f(yu.x), bf2f(yu.y), bf2f(yu.z), bf2f(yu.w)};
  float s1 = v[0] + v[1] + v[2] + v[3];
  float s2 = v[0] * v[0] + v[1] * v[1] + v[2] * v[2] + v[3] * v[3];
#pragma unroll
  for (int off = 32; off; off >>= 1) { s1 += __shfl_xor(s1, off); s2 += __shfl_xor(s2, off); }
  float mu = s1 * (1.f / HD_);
  float rstd = rsqrtf(s2 * (1.f / HD_) - mu * mu + 1e-5f);
  float4 g4 = *(const float4*)(gnw + tid * 4);
  ushort4 xu = *(const ushort4*)(xp + (size_t)r * H_ + tid * 4);
  float o[4];
  o[0] = fmaf((v[0] - mu) * rstd, g4.x, bf2f(xu.x));
  o[1] = fmaf((v[1] - mu) * rstd, g4.y, bf2f(xu.y));
  o[2] = fmaf((v[2] - mu) * rstd, g4.z, bf2f(xu.z));
  o[3] = fmaf((v[3] - mu) * rstd, g4.w, bf2f(xu.w));
  float t1 = o[0] + o[1] + o[2] + o[3];
  float t2 = o[0] * o[0] + o[1] * o[1] + o[2] * o[2] + o[3] * o[3];
#pragma unroll
  for (int off = 32; off; off >>= 1) { t1 += __shfl_xor(t1, off); t2 += __shfl_xor(t2, off); }
  __shared__ float a1[4], a2[4];
  if (lane == 0) { a1[wave] = t1; a2[wave] = t2; }
  __syncthreads();
  float T1 = a1[0] + a1[1] + a1[2] + a1[3];
  float T2 = a2[0] + a2[1] + a2[2] + a2[3];
  float MU = T1 * (1.f / H_);
  float RS = rsqrtf(T2 * (1.f / H_) - MU * MU + 1e-5f);
  float4 w4 = *(const float4*)(lpw + tid * 4);
  ushort4 res = {f2bf((o[0] - MU) * RS * w4.x), f2bf((o[1] - MU) * RS * w4.y),
                 f2bf((o[2] - MU) * RS * w4.z), f2bf((o[3] - MU) * RS * w4.w)};
  *(ushort4*)(outb + (size_t)r * H_ + tid * 4) = res;
}

// ---------------- logits + value heads (bf16 in, fp32 out) ----------------
__global__ __launch_bounds__(256) void heads_k(
    const unsigned short* __restrict__ hp, const unsigned short* __restrict__ hv,
    const float* __restrict__ Wact, const float* __restrict__ bact,
    const float* __restrict__ Wv, const float* __restrict__ bv,
    float* __restrict__ dout) {
  const int lane = threadIdx.x & 63, wave = threadIdx.x >> 6;
  const int r = blockIdx.x * 4 + wave;
  const unsigned short* hpr = hp + (size_t)r * HID_;
  const unsigned short* hvr = hv + (size_t)r * HID_;
  float acc[A_];
#pragma unroll
  for (int j = 0; j < A_; ++j) acc[j] = 0.f;
  float accv = 0.f;
  for (int i = 0; i < 16; ++i) {
    int k = i * 64 + lane;
    float hpv = bf2f(hpr[k]);
    float hvv = bf2f(hvr[k]);
#pragma unroll
    for (int j = 0; j < A_; ++j) acc[j] = fmaf(hpv, Wact[j * HID_ + k], acc[j]);
    accv = fmaf(hvv, Wv[k], accv);
  }
#pragma unroll
  for (int j = 0; j < A_; ++j)
#pragma unroll
    for (int off = 32; off; off >>= 1) acc[j] += __shfl_xor(acc[j], off);
#pragma unroll
  for (int off = 32; off; off >>= 1) accv += __shfl_xor(accv, off);
  if (lane == 0) {
#pragma unroll
    for (int j = 0; j < A_; ++j) dout[(size_t)r * A_ + j] = acc[j] + bact[j];
    dout[589824 + r] = accv + bv[0];
  }
}

// ---------------- launch ----------------
extern "C" void kernel_launch(void* const* d_in, const int* in_sizes, int n_in,
                              void* d_out, int out_size, void* d_ws, size_t ws_size,
                              hipStream_t stream) {
  const float* obs   = (const float*)d_in[0];
  const float* st    = (const float*)d_in[1];
  const float* W_in  = (const float*)d_in[2];
  const float* b_in  = (const float*)d_in[3];
  const float* ln1w  = (const float*)d_in[4];
  const float* wg    = (const float*)d_in[5];
  const float* R     = (const float*)d_in[6];
  const float* bgat  = (const float*)d_in[7];
  const float* gnw   = (const float*)d_in[8];
  const float* lpw   = (const float*)d_in[9];
  const float* W_hid = (const float*)d_in[10];
  const float* b_hid = (const float*)d_in[11];
  const float* W_pol = (const float*)d_in[12];
  const float* b_pol = (const float*)d_in[13];
  const float* W_val = (const float*)d_in[14];
  const float* b_val = (const float*)d_in[15];
  const float* W_act = (const float*)d_in[16];
  const float* b_act = (const float*)d_in[17];
  const float* W_v   = (const float*)d_in[18];
  const float* b_v   = (const float*)d_in[19];

  // Workspace layout (same NEEDED as the round that passed):
  //  A [0,        67108864): xproj bf16  -> hh bf16
  //  B [67108864, 134217728): gx chunk bf16 (T=128) -> outb bf16 -> hv bf16
  //  C [134217728,201326592): y bf16 -> hp bf16
  //  ST[201326592,202375168): scan state fp32 (h,c,n,m) 4x64x1024
  //  RS[202375168,202899456): LN1 row stats
  //  RB[202899456,204996608): R packed bf16 pairs [nh][g][e][dpair]
  const size_t NEEDED = 204996608;
  if (ws_size < NEEDED) return;  // diagnostic: clean absmax-fail => ws too small
  char* ws = (char*)d_ws;
  unsigned short* xproj = (unsigned short*)(ws + 0);
  unsigned short* gxc   = (unsigned short*)(ws + 67108864);
  unsigned short* ybuf  = (unsigned short*)(ws + 134217728);
  float* statebuf       = (float*)(ws + 201326592);
  float* rstat          = (float*)(ws + 202375168);
  unsigned* Rbb         = (unsigned*)(ws + 202899456);
  unsigned short* outb  = gxc;    // after last scan chunk
  unsigned short* hh    = xproj;  // after post_k
  unsigned short* hp    = ybuf;   // y dead after post_k
  unsigned short* hv    = gxc;    // after MLP1 consumed outb
  float* dout = (float*)d_out;
  // scan exchange buffers live in d_out's tail-unused space (fully rewritten by heads_k later)
  float* hx  = (float*)d_out;                       // 65536 floats = 256 KB
  int* flags = (int*)((char*)d_out + 262144);       // 256 ints

  // 0. seed scan state, zero cluster flags, transcode R
  hipMemcpyAsync(statebuf, st, 4 * 65536 * sizeof(float), hipMemcpyDeviceToDevice, stream);
  hipMemsetAsync(flags, 0, 256 * sizeof(int), stream);
  rtrans_k<<<2048, 256, 0, stream>>>(R, Rbb);
  // 1. x_proj = obs @ W_in^T + b_in   (M=32768,N=1024,K=512) -> bf16
  gemm_k<true, false, false, false, 0><<<dim3(256, 8), 256, 0, stream>>>(
      obs, W_in, b_in, nullptr, nullptr, xproj, 512, 512, 1024, 0);
  // 2. LN1 row stats
  rowstats_k<<<32768, 256, 0, stream>>>(xproj, rstat);
  // 3+4. per time-chunk: gate GEMM -> scan
  for (int c = 0; c < NCH_; ++c) {
    gemm_k<false, true, true, false, 1><<<dim3(64, 2, 16), 256, 0, stream>>>(
        xproj, wg, nullptr, rstat, ln1w, gxc, 256, 1024, 0, c);
    scan_k<<<256, 256, 0, stream>>>(gxc, Rbb, bgat, statebuf, ybuf, hx, flags, c);
  }
  // 5. groupnorm + residual + post LN
  post_k<<<32768, 256, 0, stream>>>(ybuf, xproj, gnw, lpw, outb);
  // 6-8. hidden / policy / value MLPs (relu)
  gemm_k<true, true, false, true, 0><<<dim3(256, 8), 256, 0, stream>>>(
      outb, W_hid, b_hid, nullptr, nullptr, hh, 1024, 1024, 1024, 0);
  gemm_k<true, true, false, true, 0><<<dim3(256, 8), 256, 0, stream>>>(
      hh, W_pol, b_pol, nullptr, nullptr, hp, 1024, 1024, 1024, 0);
  gemm_k<true, true, false, true, 0><<<dim3(256, 8), 256, 0, stream>>>(
      hh, W_val, b_val, nullptr, nullptr, hv, 1024, 1024, 1024, 0);
  // 9. logits + value
  heads_k<<<8192, 256, 0, stream>>>(hp, hv, W_act, b_act, W_v, b_v, dout);
}

// Round 5
// 10000.000 us; speedup vs baseline: 3.1286x; 1.1995x over previous
//
#include <hip/hip_runtime.h>
#include <cstdint>
#include <cstddef>

#define B_ 64
#define S_ 512
#define IN_ 512
#define H_ 1024
#define NH_ 4
#define HD_ 256
#define A_ 18
#define HID_ 1024
#define TCH_ 128            // scan time-chunk
#define NCH_ (S_ / TCH_)    // 4 chunks

// ---------------- helpers ----------------
__device__ __forceinline__ unsigned short f2bf(float f) {
  union { float f; unsigned u; } c; c.f = f;
  unsigned r = c.u + 0x7FFFu + ((c.u >> 16) & 1u);  // RNE
  return (unsigned short)(r >> 16);
}
__device__ __forceinline__ float bf2f(unsigned short h) {
  union { unsigned u; float f; } c; c.u = ((unsigned)h) << 16;
  return c.f;
}

// ---------------- R transcode: fp32 [nh][d][g][e] -> packed bf16 pairs ----------------
// Rbb[((nh*4+g)*256 + e)*128 + dp] = bf16(R[nh][2dp][g][e]) | bf16(R[nh][2dp+1][g][e])<<16
__global__ __launch_bounds__(256) void rtrans_k(const float* __restrict__ R,
                                                unsigned* __restrict__ Rbb) {
  const int i = blockIdx.x * 256 + threadIdx.x;   // [0, 524288)
  const int dp = i & 127;
  const int e = (i >> 7) & 255;
  const int g = (i >> 15) & 3;
  const int nh = i >> 17;
  const float* rp = R + (((size_t)nh * 256 + 2 * dp) * 4 + g) * 256 + e;  // d-stride 1024
  unsigned lo = f2bf(rp[0]), hi = f2bf(rp[1024]);
  Rbb[i] = lo | (hi << 16);
}

// ---------------- row stats for LN1 fusion (xproj is bf16) ----------------
__global__ __launch_bounds__(256) void rowstats_k(const unsigned short* __restrict__ x,
                                                  float* __restrict__ rs) {
  const int r = blockIdx.x, tid = threadIdx.x;
  const int lane = tid & 63, wave = tid >> 6;
  ushort4 u = *(const ushort4*)(x + (size_t)r * H_ + tid * 4);
  float v0 = bf2f(u.x), v1 = bf2f(u.y), v2 = bf2f(u.z), v3 = bf2f(u.w);
  float s1 = v0 + v1 + v2 + v3;
  float s2 = v0 * v0 + v1 * v1 + v2 * v2 + v3 * v3;
#pragma unroll
  for (int off = 32; off; off >>= 1) { s1 += __shfl_xor(s1, off); s2 += __shfl_xor(s2, off); }
  __shared__ float a1[4], a2[4];
  if (lane == 0) { a1[wave] = s1; a2[wave] = s2; }
  __syncthreads();
  if (tid == 0) {
    float S1 = a1[0] + a1[1] + a1[2] + a1[3];
    float S2 = a2[0] + a2[1] + a2[2] + a2[3];
    float mu = S1 * (1.f / H_);
    float var = S2 * (1.f / H_) - mu * mu;
    rs[r * 2] = mu;
    rs[r * 2 + 1] = rsqrtf(var + 1e-5f);
  }
}

// ---------------- generic tiled GEMM, fp32 math, bf16 out ----------------
template <bool TRANSB, bool ABF16, bool LNA, bool RELU, int OUTMODE>
__global__ __launch_bounds__(256) void gemm_k(
    const void* __restrict__ Av, const float* __restrict__ Wt,
    const float* __restrict__ bias, const float* __restrict__ rs,
    const float* __restrict__ lnw, unsigned short* __restrict__ Cb,
    int K, int lda, int ldc, int chunk) {
  __shared__ float As[16][132];
  __shared__ float Bs[16][132];
  const int tid = threadIdx.x;
  const int tx = tid & 15, ty = tid >> 4;
  const int col0 = blockIdx.y * 128;
  int aoff = 0, nh = 0, g = 0;
  const float* W = Wt;
  if constexpr (OUTMODE == 1) {
    int z = blockIdx.z; nh = z >> 2; g = z & 3;
    aoff = nh * HD_;
    W = Wt + (size_t)(g * NH_ + nh) * HD_ * HD_;
  }
  auto arow = [&](int mm) -> int {
    if constexpr (OUTMODE == 1) return (int)blockIdx.x * 512 + chunk * TCH_ + mm;
    else return (int)blockIdx.x * 128 + mm;
  };
  float acc[8][8];
#pragma unroll
  for (int i = 0; i < 8; ++i)
#pragma unroll
    for (int j = 0; j < 8; ++j) acc[i][j] = 0.f;

  for (int k0 = 0; k0 < K; k0 += 16) {
    {  // A tile: As[k][m]
      const int m = tid >> 2;
      const int kq = (tid & 3) * 4;
#pragma unroll
      for (int half = 0; half < 2; ++half) {
        int mm = m + half * 64;
        int rg = arow(mm);
        float av[4];
        if constexpr (ABF16) {
          ushort4 u = *(const ushort4*)((const unsigned short*)Av + (size_t)rg * lda + aoff + k0 + kq);
          av[0] = bf2f(u.x); av[1] = bf2f(u.y); av[2] = bf2f(u.z); av[3] = bf2f(u.w);
        } else {
          float4 f = *(const float4*)((const float*)Av + (size_t)rg * lda + aoff + k0 + kq);
          av[0] = f.x; av[1] = f.y; av[2] = f.z; av[3] = f.w;
        }
        if constexpr (LNA) {
          float mu = rs[rg * 2], rstd = rs[rg * 2 + 1];
#pragma unroll
          for (int j = 0; j < 4; ++j) av[j] = (av[j] - mu) * rstd * lnw[aoff + k0 + kq + j];
        }
#pragma unroll
        for (int j = 0; j < 4; ++j) As[kq + j][mm] = av[j];
      }
    }
    // B tile: Bs[k][n]
    if constexpr (TRANSB) {
      const int nn0 = tid >> 2;
      const int kq = (tid & 3) * 4;
#pragma unroll
      for (int half = 0; half < 2; ++half) {
        int nn = nn0 + half * 64;
        float4 wv = *(const float4*)(W + (size_t)(col0 + nn) * K + k0 + kq);
        Bs[kq + 0][nn] = wv.x; Bs[kq + 1][nn] = wv.y;
        Bs[kq + 2][nn] = wv.z; Bs[kq + 3][nn] = wv.w;
      }
    } else {
      const int kk = tid >> 4;
      const int nn = (tid & 15) * 8;
      const float* wp = W + (size_t)(k0 + kk) * 256 + col0 + nn;
      float4 w0 = *(const float4*)wp;
      float4 w1 = *(const float4*)(wp + 4);
      *(float4*)&Bs[kk][nn] = w0;
      *(float4*)&Bs[kk][nn + 4] = w1;
    }
    __syncthreads();
#pragma unroll
    for (int k = 0; k < 16; ++k) {
      float4 a0 = *(const float4*)&As[k][ty * 4];
      float4 a1 = *(const float4*)&As[k][ty * 4 + 64];
      float4 b0 = *(const float4*)&Bs[k][tx * 4];
      float4 b1 = *(const float4*)&Bs[k][tx * 4 + 64];
      float av[8] = {a0.x, a0.y, a0.z, a0.w, a1.x, a1.y, a1.z, a1.w};
      float bv[8] = {b0.x, b0.y, b0.z, b0.w, b1.x, b1.y, b1.z, b1.w};
#pragma unroll
      for (int i = 0; i < 8; ++i)
#pragma unroll
        for (int j = 0; j < 8; ++j) acc[i][j] = fmaf(av[i], bv[j], acc[i][j]);
    }
    __syncthreads();
  }
  if constexpr (OUTMODE == 0) {
    float4 bia0 = {0, 0, 0, 0}, bia1 = {0, 0, 0, 0};
    if (bias) {
      bia0 = *(const float4*)(bias + col0 + tx * 4);
      bia1 = *(const float4*)(bias + col0 + tx * 4 + 64);
    }
#pragma unroll
    for (int i = 0; i < 8; ++i) {
      int r = arow(ty * 4 + (i & 3) + (i >> 2) * 64);
      float v[8] = {acc[i][0] + bia0.x, acc[i][1] + bia0.y, acc[i][2] + bia0.z, acc[i][3] + bia0.w,
                    acc[i][4] + bia1.x, acc[i][5] + bia1.y, acc[i][6] + bia1.z, acc[i][7] + bia1.w};
      if constexpr (RELU) {
#pragma unroll
        for (int j = 0; j < 8; ++j) v[j] = fmaxf(v[j], 0.f);
      }
      ushort4 s0 = {f2bf(v[0]), f2bf(v[1]), f2bf(v[2]), f2bf(v[3])};
      ushort4 s1 = {f2bf(v[4]), f2bf(v[5]), f2bf(v[6]), f2bf(v[7])};
      *(ushort4*)(Cb + (size_t)r * ldc + col0 + tx * 4) = s0;
      *(ushort4*)(Cb + (size_t)r * ldc + col0 + tx * 4 + 64) = s1;
    }
  } else {
    // gx chunk: idx = ((sl*64+b)*4+nh)*1024 + g*256 + e ; sl = tile-local row
    const int b = blockIdx.x;
#pragma unroll
    for (int i = 0; i < 8; ++i) {
      int sl = ty * 4 + (i & 3) + (i >> 2) * 64;
      size_t base = (size_t)(sl * 64 + b) * 4096 + nh * 1024 + g * 256;
#pragma unroll
      for (int q = 0; q < 2; ++q) {
        int e = col0 + tx * 4 + q * 64;
        ushort4 pv = {f2bf(acc[i][q * 4 + 0]), f2bf(acc[i][q * 4 + 1]),
                      f2bf(acc[i][q * 4 + 2]), f2bf(acc[i][q * 4 + 3])};
        *(ushort4*)(Cb + base + e) = pv;
      }
    }
  }
}

// ---------------- sLSTM scan: 256 blocks = (nh, e-slice, batch-group), R in regs ----------------
// Cross-block h exchange: RELAXED agent atomics only (no acquire/release fences — those
// emit L2 writeback/invalidate per step and were ~14us/step in round 4). Ordering is
// physical: __syncthreads drains vmcnt(0), so hx stores are complete at the coherence
// point before the flag RMW issues. hx is double-buffered by step parity (kills the
// 1-step-skew WAR race); one shared flag per 4-block group (each adds 1 per step).
__global__ __launch_bounds__(256, 1) void scan_k(
    const unsigned short* __restrict__ gxc, const unsigned* __restrict__ Rbb,
    const float* __restrict__ bgates, float* __restrict__ state,
    unsigned short* __restrict__ y, float* hx, int* flags, int chunk) {
  const int tid = threadIdx.x;
  const int bid = blockIdx.x;
  const int nh = bid >> 6, esl = (bid >> 4) & 3, bgrp = bid & 15;
  const int g = tid >> 6, eo = tid & 63;
  __shared__ float hsh[256][4];     // h[d][b], row = float4
  __shared__ float rawsh[64][17];   // raw[e][b*4+g], padded stride 17

  // R columns into registers: 256 bf16 packed into 128 uints
  unsigned rcol[128];
  {
    const unsigned* rp = Rbb + ((size_t)(nh * 4 + g) * 256 + esl * 64 + eo) * 128;
#pragma unroll
    for (int i = 0; i < 128; ++i) rcol[i] = rp[i];
  }
  const float bg = bgates[g * H_ + nh * HD_ + esl * 64 + eo];

  // owner mapping for pointwise/state: (ob, oe) -> d = esl*64+oe
  const int ob = tid >> 6, oe = tid & 63;
  const int od = esl * 64 + oe;
  const size_t sbase = (size_t)(bgrp * 4 + ob) * H_ + nh * HD_ + od;
  float c_ = state[65536 + sbase];
  float n_ = state[2 * 65536 + sbase];
  float m_ = state[3 * 65536 + sbase];
  float hlast = state[sbase];

  // init full h tile
#pragma unroll
  for (int r = 0; r < 4; ++r) {
    int idx = r * 256 + tid;
    int d = idx >> 2, b = idx & 3;
    hsh[d][b] = state[(size_t)(bgrp * 4 + b) * H_ + nh * HD_ + d];
  }
  __syncthreads();

  const int grp = nh * 16 + bgrp;
  float* hx0 = hx + (size_t)grp * 1024;            // parity 0: [256 d][4 b]
  float* hx1 = hx + 65536 + (size_t)grp * 1024;    // parity 1
  int* flagp = flags + grp;
  // gx: ((t*64 + bgrp*4+b)*4 + nh)*1024 + g*256 + esl*64 + eo ; b-stride 4096, t-stride 262144
  const unsigned short* gp = gxc + (size_t)(bgrp * 4) * 4096 + nh * 1024 + g * 256 + esl * 64 + eo;
  unsigned short* yp = y + ((size_t)(chunk * TCH_) * 64 + bgrp * 4) * H_ + nh * HD_;

  float g0 = bf2f(gp[0]), g1 = bf2f(gp[4096]), g2 = bf2f(gp[8192]), g3 = bf2f(gp[12288]);

  for (int t = 0; t < TCH_; ++t) {
    const int tg = chunk * TCH_ + t;
    float* hxc = (tg & 1) ? hx1 : hx0;
    float acc0 = g0 + bg, acc1 = g1 + bg, acc2 = g2 + bg, acc3 = g3 + bg;
    if (t < TCH_ - 1) {  // prefetch next step's gx under the matvec
      const unsigned short* gn = gp + (size_t)(t + 1) * 262144;
      g0 = bf2f(gn[0]); g1 = bf2f(gn[4096]); g2 = bf2f(gn[8192]); g3 = bf2f(gn[12288]);
    }
#pragma unroll
    for (int dp = 0; dp < 128; ++dp) {
      unsigned u = rcol[dp];
      float rl = __uint_as_float(u << 16);
      float rh = __uint_as_float(u & 0xffff0000u);
      float4 ha = *(const float4*)&hsh[2 * dp][0];      // uniform addr -> LDS broadcast
      float4 hb = *(const float4*)&hsh[2 * dp + 1][0];
      acc0 = fmaf(rl, ha.x, acc0); acc1 = fmaf(rl, ha.y, acc1);
      acc2 = fmaf(rl, ha.z, acc2); acc3 = fmaf(rl, ha.w, acc3);
      acc0 = fmaf(rh, hb.x, acc0); acc1 = fmaf(rh, hb.y, acc1);
      acc2 = fmaf(rh, hb.z, acc2); acc3 = fmaf(rh, hb.w, acc3);
    }
    rawsh[eo][0 * 4 + g] = acc0;
    rawsh[eo][1 * 4 + g] = acc1;
    rawsh[eo][2 * 4 + g] = acc2;
    rawsh[eo][3 * 4 + g] = acc3;
    __syncthreads();
    // pointwise update for owned (ob, od)
    {
      float iraw = rawsh[oe][ob * 4 + 0];
      float fraw = rawsh[oe][ob * 4 + 1];
      float zraw = rawsh[oe][ob * 4 + 2];
      float oraw = rawsh[oe][ob * 4 + 3];
      float ls = -log1pf(expf(-fabsf(fraw)));
      if (fraw < 0.f) ls += fraw;                 // log_sigmoid(fraw)
      float lfm = m_ + ls;
      float mnew = fmaxf(iraw, lfm);
      float iv = expf(iraw - mnew);
      float fv = expf(lfm - mnew);
      c_ = fv * c_ + iv * tanhf(zraw);
      n_ = fv * n_ + iv;
      m_ = mnew;
      hlast = c_ / n_ / (1.f + expf(-oraw));
      hsh[od][ob] = hlast;
      __hip_atomic_store(&hxc[od * 4 + ob], hlast, __ATOMIC_RELAXED, __HIP_MEMORY_SCOPE_AGENT);
      yp[(size_t)(t * 64 + ob) * H_ + od] = f2bf(hlast);
    }
    __syncthreads();  // drains vmcnt(0): hx stores complete at coherence point
    if (tid == 0) {
      __hip_atomic_fetch_add(flagp, 1, __ATOMIC_RELAXED, __HIP_MEMORY_SCOPE_AGENT);
      const int tgt = 4 * (tg + 1);
      while (__hip_atomic_load(flagp, __ATOMIC_RELAXED, __HIP_MEMORY_SCOPE_AGENT) < tgt) {
        __builtin_amdgcn_s_sleep(1);
      }
    }
    __syncthreads();
    // fill the 3 sibling h-slices (192 d x 4 b = 768 values, 3 per thread)
#pragma unroll
    for (int r = 0; r < 3; ++r) {
      int idx = r * 256 + tid;
      int dof = idx >> 2, b = idx & 3;
      int d = (dof < esl * 64) ? dof : dof + 64;
      hsh[d][b] = __hip_atomic_load(&hxc[d * 4 + b], __ATOMIC_RELAXED, __HIP_MEMORY_SCOPE_AGENT);
    }
    __syncthreads();
  }
  state[sbase] = hlast;
  state[65536 + sbase] = c_;
  state[2 * 65536 + sbase] = n_;
  state[3 * 65536 + sbase] = m_;
}

// ---------------- groupnorm + residual + post LN (bf16 in/out) ----------------
__global__ __launch_bounds__(256) void post_k(
    const unsigned short* __restrict__ y, const unsigned short* __restrict__ xp,
    const float* __restrict__ gnw, const float* __restrict__ lpw,
    unsigned short* __restrict__ outb) {
  const int r = blockIdx.x;            // r = b*512 + s
  const int b = r >> 9, s = r & 511;
  const int tid = threadIdx.x;
  const int lane = tid & 63, wave = tid >> 6;
  ushort4 yu = *(const ushort4*)(y + (size_t)(s * 64 + b) * H_ + tid * 4);
  float v[4] = {bf2f(yu.x), bf2f(yu.y), bf2f(yu.z), bf2f(yu.w)};
  float s1 = v[0] + v[1] + v[2] + v[3];
  float s2 = v[0] * v[0] + v[1] * v[1] + v[2] * v[2] + v[3] * v[3];
#pragma unroll
  for (int off = 32; off; off >>= 1) { s1 += __shfl_xor(s1, off); s2 += __shfl_xor(s2, off); }
  float mu = s1 * (1.f / HD_);
  float rstd = rsqrtf(s2 * (1.f / HD_) - mu * mu + 1e-5f);
  float4 g4 = *(const float4*)(gnw + tid * 4);
  ushort4 xu = *(const ushort4*)(xp + (size_t)r * H_ + tid * 4);
  float o[4];
  o[0] = fmaf((v[0] - mu) * rstd, g4.x, bf2f(xu.x));
  o[1] = fmaf((v[1] - mu) * rstd, g4.y, bf2f(xu.y));
  o[2] = fmaf((v[2] - mu) * rstd, g4.z, bf2f(xu.z));
  o[3] = fmaf((v[3] - mu) * rstd, g4.w, bf2f(xu.w));
  float t1 = o[0] + o[1] + o[2] + o[3];
  float t2 = o[0] * o[0] + o[1] * o[1] + o[2] * o[2] + o[3] * o[3];
#pragma unroll
  for (int off = 32; off; off >>= 1) { t1 += __shfl_xor(t1, off); t2 += __shfl_xor(t2, off); }
  __shared__ float a1[4], a2[4];
  if (lane == 0) { a1[wave] = t1; a2[wave] = t2; }
  __syncthreads();
  float T1 = a1[0] + a1[1] + a1[2] + a1[3];
  float T2 = a2[0] + a2[1] + a2[2] + a2[3];
  float MU = T1 * (1.f / H_);
  float RS = rsqrtf(T2 * (1.f / H_) - MU * MU + 1e-5f);
  float4 w4 = *(const float4*)(lpw + tid * 4);
  ushort4 res = {f2bf((o[0] - MU) * RS * w4.x), f2bf((o[1] - MU) * RS * w4.y),
                 f2bf((o[2] - MU) * RS * w4.z), f2bf((o[3] - MU) * RS * w4.w)};
  *(ushort4*)(outb + (size_t)r * H_ + tid * 4) = res;
}

// ---------------- logits + value heads (bf16 in, fp32 out) ----------------
__global__ __launch_bounds__(256) void heads_k(
    const unsigned short* __restrict__ hp, const unsigned short* __restrict__ hv,
    const float* __restrict__ Wact, const float* __restrict__ bact,
    const float* __restrict__ Wv, const float* __restrict__ bv,
    float* __restrict__ dout) {
  const int lane = threadIdx.x & 63, wave = threadIdx.x >> 6;
  const int r = blockIdx.x * 4 + wave;
  const unsigned short* hpr = hp + (size_t)r * HID_;
  const unsigned short* hvr = hv + (size_t)r * HID_;
  float acc[A_];
#pragma unroll
  for (int j = 0; j < A_; ++j) acc[j] = 0.f;
  float accv = 0.f;
  for (int i = 0; i < 16; ++i) {
    int k = i * 64 + lane;
    float hpv = bf2f(hpr[k]);
    float hvv = bf2f(hvr[k]);
#pragma unroll
    for (int j = 0; j < A_; ++j) acc[j] = fmaf(hpv, Wact[j * HID_ + k], acc[j]);
    accv = fmaf(hvv, Wv[k], accv);
  }
#pragma unroll
  for (int j = 0; j < A_; ++j)
#pragma unroll
    for (int off = 32; off; off >>= 1) acc[j] += __shfl_xor(acc[j], off);
#pragma unroll
  for (int off = 32; off; off >>= 1) accv += __shfl_xor(accv, off);
  if (lane == 0) {
#pragma unroll
    for (int j = 0; j < A_; ++j) dout[(size_t)r * A_ + j] = acc[j] + bact[j];
    dout[589824 + r] = accv + bv[0];
  }
}

// ---------------- launch ----------------
extern "C" void kernel_launch(void* const* d_in, const int* in_sizes, int n_in,
                              void* d_out, int out_size, void* d_ws, size_t ws_size,
                              hipStream_t stream) {
  const float* obs   = (const float*)d_in[0];
  const float* st    = (const float*)d_in[1];
  const float* W_in  = (const float*)d_in[2];
  const float* b_in  = (const float*)d_in[3];
  const float* ln1w  = (const float*)d_in[4];
  const float* wg    = (const float*)d_in[5];
  const float* R     = (const float*)d_in[6];
  const float* bgat  = (const float*)d_in[7];
  const float* gnw   = (const float*)d_in[8];
  const float* lpw   = (const float*)d_in[9];
  const float* W_hid = (const float*)d_in[10];
  const float* b_hid = (const float*)d_in[11];
  const float* W_pol = (const float*)d_in[12];
  const float* b_pol = (const float*)d_in[13];
  const float* W_val = (const float*)d_in[14];
  const float* b_val = (const float*)d_in[15];
  const float* W_act = (const float*)d_in[16];
  const float* b_act = (const float*)d_in[17];
  const float* W_v   = (const float*)d_in[18];
  const float* b_v   = (const float*)d_in[19];

  // Workspace layout (same NEEDED as the round that passed):
  //  A [0,        67108864): xproj bf16  -> hh bf16
  //  B [67108864, 134217728): gx chunk bf16 (T=128) -> outb bf16 -> hv bf16
  //  C [134217728,201326592): y bf16 -> hp bf16
  //  ST[201326592,202375168): scan state fp32 (h,c,n,m) 4x64x1024
  //  RS[202375168,202899456): LN1 row stats
  //  RB[202899456,204996608): R packed bf16 pairs [nh][g][e][dpair]
  const size_t NEEDED = 204996608;
  if (ws_size < NEEDED) return;  // diagnostic: clean absmax-fail => ws too small
  char* ws = (char*)d_ws;
  unsigned short* xproj = (unsigned short*)(ws + 0);
  unsigned short* gxc   = (unsigned short*)(ws + 67108864);
  unsigned short* ybuf  = (unsigned short*)(ws + 134217728);
  float* statebuf       = (float*)(ws + 201326592);
  float* rstat          = (float*)(ws + 202375168);
  unsigned* Rbb         = (unsigned*)(ws + 202899456);
  unsigned short* outb  = gxc;    // after last scan chunk
  unsigned short* hh    = xproj;  // after post_k
  unsigned short* hp    = ybuf;   // y dead after post_k
  unsigned short* hv    = gxc;    // after MLP1 consumed outb
  float* dout = (float*)d_out;
  // scan exchange buffers live in d_out's head (fully rewritten by heads_k later):
  //   hx double-buffer [2][64 grp][1024] = 524288 B, flags 64 ints at +524288
  float* hx  = (float*)d_out;
  int* flags = (int*)((char*)d_out + 524288);

  // 0. seed scan state, zero group flags, transcode R
  hipMemcpyAsync(statebuf, st, 4 * 65536 * sizeof(float), hipMemcpyDeviceToDevice, stream);
  hipMemsetAsync(flags, 0, 64 * sizeof(int), stream);
  rtrans_k<<<2048, 256, 0, stream>>>(R, Rbb);
  // 1. x_proj = obs @ W_in^T + b_in   (M=32768,N=1024,K=512) -> bf16
  gemm_k<true, false, false, false, 0><<<dim3(256, 8), 256, 0, stream>>>(
      obs, W_in, b_in, nullptr, nullptr, xproj, 512, 512, 1024, 0);
  // 2. LN1 row stats
  rowstats_k<<<32768, 256, 0, stream>>>(xproj, rstat);
  // 3+4. per time-chunk: gate GEMM -> scan
  for (int c = 0; c < NCH_; ++c) {
    gemm_k<false, true, true, false, 1><<<dim3(64, 2, 16), 256, 0, stream>>>(
        xproj, wg, nullptr, rstat, ln1w, gxc, 256, 1024, 0, c);
    scan_k<<<256, 256, 0, stream>>>(gxc, Rbb, bgat, statebuf, ybuf, hx, flags, c);
  }
  // 5. groupnorm + residual + post LN
  post_k<<<32768, 256, 0, stream>>>(ybuf, xproj, gnw, lpw, outb);
  // 6-8. hidden / policy / value MLPs (relu)
  gemm_k<true, true, false, true, 0><<<dim3(256, 8), 256, 0, stream>>>(
      outb, W_hid, b_hid, nullptr, nullptr, hh, 1024, 1024, 1024, 0);
  gemm_k<true, true, false, true, 0><<<dim3(256, 8), 256, 0, stream>>>(
      hh, W_pol, b_pol, nullptr, nullptr, hp, 1024, 1024, 1024, 0);
  gemm_k<true, true, false, true, 0><<<dim3(256, 8), 256, 0, stream>>>(
      hh, W_val, b_val, nullptr, nullptr, hv, 1024, 1024, 1024, 0);
  // 9. logits + value
  heads_k<<<8192, 256, 0, stream>>>(hp, hv, W_act, b_act, W_v, b_v, dout);
}

// Round 6
// 9690.506 us; speedup vs baseline: 3.2285x; 1.0319x over previous
//
#include <hip/hip_runtime.h>
#include <cstdint>
#include <cstddef>

#define B_ 64
#define S_ 512
#define IN_ 512
#define H_ 1024
#define NH_ 4
#define HD_ 256
#define A_ 18
#define HID_ 1024
#define TCH_ 128            // scan time-chunk
#define NCH_ (S_ / TCH_)    // 4 chunks

// ---------------- helpers ----------------
__device__ __forceinline__ unsigned short f2bf(float f) {
  union { float f; unsigned u; } c; c.f = f;
  unsigned r = c.u + 0x7FFFu + ((c.u >> 16) & 1u);  // RNE
  return (unsigned short)(r >> 16);
}
__device__ __forceinline__ float bf2f(unsigned short h) {
  union { unsigned u; float f; } c; c.u = ((unsigned)h) << 16;
  return c.f;
}

// ---------------- R transcode: fp32 [nh][d][g][e] -> packed bf16 pairs ----------------
// Rbb[((nh*4+g)*256 + e)*128 + dp] = bf16(R[nh][2dp][g][e]) | bf16(R[nh][2dp+1][g][e])<<16
__global__ __launch_bounds__(256) void rtrans_k(const float* __restrict__ R,
                                                unsigned* __restrict__ Rbb) {
  const int i = blockIdx.x * 256 + threadIdx.x;   // [0, 524288)
  const int dp = i & 127;
  const int e = (i >> 7) & 255;
  const int g = (i >> 15) & 3;
  const int nh = i >> 17;
  const float* rp = R + (((size_t)nh * 256 + 2 * dp) * 4 + g) * 256 + e;  // d-stride 1024
  unsigned lo = f2bf(rp[0]), hi = f2bf(rp[1024]);
  Rbb[i] = lo | (hi << 16);
}

// ---------------- row stats for LN1 fusion (xproj is bf16) ----------------
__global__ __launch_bounds__(256) void rowstats_k(const unsigned short* __restrict__ x,
                                                  float* __restrict__ rs) {
  const int r = blockIdx.x, tid = threadIdx.x;
  const int lane = tid & 63, wave = tid >> 6;
  ushort4 u = *(const ushort4*)(x + (size_t)r * H_ + tid * 4);
  float v0 = bf2f(u.x), v1 = bf2f(u.y), v2 = bf2f(u.z), v3 = bf2f(u.w);
  float s1 = v0 + v1 + v2 + v3;
  float s2 = v0 * v0 + v1 * v1 + v2 * v2 + v3 * v3;
#pragma unroll
  for (int off = 32; off; off >>= 1) { s1 += __shfl_xor(s1, off); s2 += __shfl_xor(s2, off); }
  __shared__ float a1[4], a2[4];
  if (lane == 0) { a1[wave] = s1; a2[wave] = s2; }
  __syncthreads();
  if (tid == 0) {
    float S1 = a1[0] + a1[1] + a1[2] + a1[3];
    float S2 = a2[0] + a2[1] + a2[2] + a2[3];
    float mu = S1 * (1.f / H_);
    float var = S2 * (1.f / H_) - mu * mu;
    rs[r * 2] = mu;
    rs[r * 2 + 1] = rsqrtf(var + 1e-5f);
  }
}

// ---------------- generic tiled GEMM, fp32 math, bf16 out ----------------
template <bool TRANSB, bool ABF16, bool LNA, bool RELU, int OUTMODE>
__global__ __launch_bounds__(256) void gemm_k(
    const void* __restrict__ Av, const float* __restrict__ Wt,
    const float* __restrict__ bias, const float* __restrict__ rs,
    const float* __restrict__ lnw, unsigned short* __restrict__ Cb,
    int K, int lda, int ldc, int chunk) {
  __shared__ float As[16][132];
  __shared__ float Bs[16][132];
  const int tid = threadIdx.x;
  const int tx = tid & 15, ty = tid >> 4;
  const int col0 = blockIdx.y * 128;
  int aoff = 0, nh = 0, g = 0;
  const float* W = Wt;
  if constexpr (OUTMODE == 1) {
    int z = blockIdx.z; nh = z >> 2; g = z & 3;
    aoff = nh * HD_;
    W = Wt + (size_t)(g * NH_ + nh) * HD_ * HD_;
  }
  auto arow = [&](int mm) -> int {
    if constexpr (OUTMODE == 1) return (int)blockIdx.x * 512 + chunk * TCH_ + mm;
    else return (int)blockIdx.x * 128 + mm;
  };
  float acc[8][8];
#pragma unroll
  for (int i = 0; i < 8; ++i)
#pragma unroll
    for (int j = 0; j < 8; ++j) acc[i][j] = 0.f;

  for (int k0 = 0; k0 < K; k0 += 16) {
    {  // A tile: As[k][m]
      const int m = tid >> 2;
      const int kq = (tid & 3) * 4;
#pragma unroll
      for (int half = 0; half < 2; ++half) {
        int mm = m + half * 64;
        int rg = arow(mm);
        float av[4];
        if constexpr (ABF16) {
          ushort4 u = *(const ushort4*)((const unsigned short*)Av + (size_t)rg * lda + aoff + k0 + kq);
          av[0] = bf2f(u.x); av[1] = bf2f(u.y); av[2] = bf2f(u.z); av[3] = bf2f(u.w);
        } else {
          float4 f = *(const float4*)((const float*)Av + (size_t)rg * lda + aoff + k0 + kq);
          av[0] = f.x; av[1] = f.y; av[2] = f.z; av[3] = f.w;
        }
        if constexpr (LNA) {
          float mu = rs[rg * 2], rstd = rs[rg * 2 + 1];
#pragma unroll
          for (int j = 0; j < 4; ++j) av[j] = (av[j] - mu) * rstd * lnw[aoff + k0 + kq + j];
        }
#pragma unroll
        for (int j = 0; j < 4; ++j) As[kq + j][mm] = av[j];
      }
    }
    // B tile: Bs[k][n]
    if constexpr (TRANSB) {
      const int nn0 = tid >> 2;
      const int kq = (tid & 3) * 4;
#pragma unroll
      for (int half = 0; half < 2; ++half) {
        int nn = nn0 + half * 64;
        float4 wv = *(const float4*)(W + (size_t)(col0 + nn) * K + k0 + kq);
        Bs[kq + 0][nn] = wv.x; Bs[kq + 1][nn] = wv.y;
        Bs[kq + 2][nn] = wv.z; Bs[kq + 3][nn] = wv.w;
      }
    } else {
      const int kk = tid >> 4;
      const int nn = (tid & 15) * 8;
      const float* wp = W + (size_t)(k0 + kk) * 256 + col0 + nn;
      float4 w0 = *(const float4*)wp;
      float4 w1 = *(const float4*)(wp + 4);
      *(float4*)&Bs[kk][nn] = w0;
      *(float4*)&Bs[kk][nn + 4] = w1;
    }
    __syncthreads();
#pragma unroll
    for (int k = 0; k < 16; ++k) {
      float4 a0 = *(const float4*)&As[k][ty * 4];
      float4 a1 = *(const float4*)&As[k][ty * 4 + 64];
      float4 b0 = *(const float4*)&Bs[k][tx * 4];
      float4 b1 = *(const float4*)&Bs[k][tx * 4 + 64];
      float av[8] = {a0.x, a0.y, a0.z, a0.w, a1.x, a1.y, a1.z, a1.w};
      float bv[8] = {b0.x, b0.y, b0.z, b0.w, b1.x, b1.y, b1.z, b1.w};
#pragma unroll
      for (int i = 0; i < 8; ++i)
#pragma unroll
        for (int j = 0; j < 8; ++j) acc[i][j] = fmaf(av[i], bv[j], acc[i][j]);
    }
    __syncthreads();
  }
  if constexpr (OUTMODE == 0) {
    float4 bia0 = {0, 0, 0, 0}, bia1 = {0, 0, 0, 0};
    if (bias) {
      bia0 = *(const float4*)(bias + col0 + tx * 4);
      bia1 = *(const float4*)(bias + col0 + tx * 4 + 64);
    }
#pragma unroll
    for (int i = 0; i < 8; ++i) {
      int r = arow(ty * 4 + (i & 3) + (i >> 2) * 64);
      float v[8] = {acc[i][0] + bia0.x, acc[i][1] + bia0.y, acc[i][2] + bia0.z, acc[i][3] + bia0.w,
                    acc[i][4] + bia1.x, acc[i][5] + bia1.y, acc[i][6] + bia1.z, acc[i][7] + bia1.w};
      if constexpr (RELU) {
#pragma unroll
        for (int j = 0; j < 8; ++j) v[j] = fmaxf(v[j], 0.f);
      }
      ushort4 s0 = {f2bf(v[0]), f2bf(v[1]), f2bf(v[2]), f2bf(v[3])};
      ushort4 s1 = {f2bf(v[4]), f2bf(v[5]), f2bf(v[6]), f2bf(v[7])};
      *(ushort4*)(Cb + (size_t)r * ldc + col0 + tx * 4) = s0;
      *(ushort4*)(Cb + (size_t)r * ldc + col0 + tx * 4 + 64) = s1;
    }
  } else {
    // gx chunk: idx = ((sl*64+b)*4+nh)*1024 + g*256 + e ; sl = tile-local row
    const int b = blockIdx.x;
#pragma unroll
    for (int i = 0; i < 8; ++i) {
      int sl = ty * 4 + (i & 3) + (i >> 2) * 64;
      size_t base = (size_t)(sl * 64 + b) * 4096 + nh * 1024 + g * 256;
#pragma unroll
      for (int q = 0; q < 2; ++q) {
        int e = col0 + tx * 4 + q * 64;
        ushort4 pv = {f2bf(acc[i][q * 4 + 0]), f2bf(acc[i][q * 4 + 1]),
                      f2bf(acc[i][q * 4 + 2]), f2bf(acc[i][q * 4 + 3])};
        *(ushort4*)(Cb + base + e) = pv;
      }
    }
  }
}

// ---------------- sLSTM scan: 256 blocks = (nh, e-slice, batch-group), R in regs ----------------
// Cross-block h exchange: ONE 32-bit word per value = bf16(h)<<16 | (step+1) tag.
// Data and readiness flag are the same atomic word -> no fences, no flag round-trip,
// no store-drain barrier. Double-buffered by step parity (WAR-safe, dep chain <= 2).
// Tag = step+1 so zeroed (tag 0) / 0xAA-poisoned (tag 0xAAAA) memory never matches.
// Layout hx[parity][grp][b*256+d]: a wave stores 256 consecutive bytes (no partial-line
// write amplification -- round 5's [d][b] layout caused 4x WRITE_SIZE inflation).
__global__ __launch_bounds__(256, 1) void scan_k(
    const unsigned short* __restrict__ gxc, const unsigned* __restrict__ Rbb,
    const float* __restrict__ bgates, float* __restrict__ state,
    unsigned short* __restrict__ y, unsigned* hx, int chunk) {
  const int tid = threadIdx.x;
  const int bid = blockIdx.x;
  const int nh = bid >> 6, esl = (bid >> 4) & 3, bgrp = bid & 15;
  const int g = tid >> 6, eo = tid & 63;
  __shared__ float hsh[256][4];     // h[d][b], row = float4
  __shared__ float rawsh[64][17];   // raw[e][b*4+g], padded stride 17

  // R columns into registers: 256 bf16 packed into 128 uints
  unsigned rcol[128];
  {
    const unsigned* rp = Rbb + ((size_t)(nh * 4 + g) * 256 + esl * 64 + eo) * 128;
#pragma unroll
    for (int i = 0; i < 128; ++i) rcol[i] = rp[i];
  }
  const float bg = bgates[g * H_ + nh * HD_ + esl * 64 + eo];

  // owner mapping for pointwise/state: (ob, oe) -> d = esl*64+oe
  const int ob = tid >> 6, oe = tid & 63;
  const int od = esl * 64 + oe;
  const size_t sbase = (size_t)(bgrp * 4 + ob) * H_ + nh * HD_ + od;
  float c_ = state[65536 + sbase];
  float n_ = state[2 * 65536 + sbase];
  float m_ = state[3 * 65536 + sbase];
  float hlast = state[sbase];

  // init full h tile
#pragma unroll
  for (int r = 0; r < 4; ++r) {
    int idx = r * 256 + tid;
    int d = idx >> 2, b = idx & 3;
    hsh[d][b] = state[(size_t)(bgrp * 4 + b) * H_ + nh * HD_ + d];
  }
  __syncthreads();

  const int grp = nh * 16 + bgrp;
  unsigned* hx0 = hx + (size_t)grp * 1024;            // parity 0: [4 b][256 d]
  unsigned* hx1 = hx + 65536 + (size_t)grp * 1024;    // parity 1
  const int ownoff = ob * 256 + od;
  // sibling word offsets + hsh targets (3 per thread, static-indexed)
  int soff0, soff1, soff2;
  float *st0, *st1, *st2;
  {
    int idx, b, dof, d;
    idx = tid;        b = idx & 3; dof = idx >> 2; d = (dof < esl * 64) ? dof : dof + 64;
    soff0 = b * 256 + d; st0 = &hsh[d][b];
    idx = 256 + tid;  b = idx & 3; dof = idx >> 2; d = (dof < esl * 64) ? dof : dof + 64;
    soff1 = b * 256 + d; st1 = &hsh[d][b];
    idx = 512 + tid;  b = idx & 3; dof = idx >> 2; d = (dof < esl * 64) ? dof : dof + 64;
    soff2 = b * 256 + d; st2 = &hsh[d][b];
  }
  // gx: ((t*64 + bgrp*4+b)*4 + nh)*1024 + g*256 + esl*64 + eo ; b-stride 4096, t-stride 262144
  const unsigned short* gp = gxc + (size_t)(bgrp * 4) * 4096 + nh * 1024 + g * 256 + esl * 64 + eo;
  unsigned short* yp = y + ((size_t)(chunk * TCH_) * 64 + bgrp * 4) * H_ + nh * HD_;

  float g0 = bf2f(gp[0]), g1 = bf2f(gp[4096]), g2 = bf2f(gp[8192]), g3 = bf2f(gp[12288]);

  for (int t = 0; t < TCH_; ++t) {
    const int tg = chunk * TCH_ + t;
    unsigned* hxc = (tg & 1) ? hx1 : hx0;
    const unsigned tagv = (unsigned)(tg + 1) & 0xffffu;
    float acc0 = g0 + bg, acc1 = g1 + bg, acc2 = g2 + bg, acc3 = g3 + bg;
    if (t < TCH_ - 1) {  // prefetch next step's gx under the matvec
      const unsigned short* gn = gp + (size_t)(t + 1) * 262144;
      g0 = bf2f(gn[0]); g1 = bf2f(gn[4096]); g2 = bf2f(gn[8192]); g3 = bf2f(gn[12288]);
    }
#pragma unroll
    for (int dp = 0; dp < 128; ++dp) {
      unsigned u = rcol[dp];
      float rl = __uint_as_float(u << 16);
      float rh = __uint_as_float(u & 0xffff0000u);
      float4 ha = *(const float4*)&hsh[2 * dp][0];      // uniform addr -> LDS broadcast
      float4 hb = *(const float4*)&hsh[2 * dp + 1][0];
      acc0 = fmaf(rl, ha.x, acc0); acc1 = fmaf(rl, ha.y, acc1);
      acc2 = fmaf(rl, ha.z, acc2); acc3 = fmaf(rl, ha.w, acc3);
      acc0 = fmaf(rh, hb.x, acc0); acc1 = fmaf(rh, hb.y, acc1);
      acc2 = fmaf(rh, hb.z, acc2); acc3 = fmaf(rh, hb.w, acc3);
    }
    rawsh[eo][0 * 4 + g] = acc0;
    rawsh[eo][1 * 4 + g] = acc1;
    rawsh[eo][2 * 4 + g] = acc2;
    rawsh[eo][3 * 4 + g] = acc3;
    __syncthreads();
    // pointwise update for owned (ob, od) + publish packed word
    {
      float iraw = rawsh[oe][ob * 4 + 0];
      float fraw = rawsh[oe][ob * 4 + 1];
      float zraw = rawsh[oe][ob * 4 + 2];
      float oraw = rawsh[oe][ob * 4 + 3];
      float ls = -log1pf(expf(-fabsf(fraw)));
      if (fraw < 0.f) ls += fraw;                 // log_sigmoid(fraw)
      float lfm = m_ + ls;
      float mnew = fmaxf(iraw, lfm);
      float iv = expf(iraw - mnew);
      float fv = expf(lfm - mnew);
      c_ = fv * c_ + iv * tanhf(zraw);
      n_ = fv * n_ + iv;
      m_ = mnew;
      hlast = c_ / n_ / (1.f + expf(-oraw));
      hsh[od][ob] = hlast;
      unsigned hw = ((unsigned)f2bf(hlast) << 16) | tagv;
      __hip_atomic_store(&hxc[ownoff], hw, __ATOMIC_RELAXED, __HIP_MEMORY_SCOPE_AGENT);
      yp[(size_t)(t * 64 + ob) * H_ + od] = f2bf(hlast);
    }
    // poll sibling words (data+tag in one word; all 256 threads in parallel)
    unsigned w0, w1, w2;
    bool d0 = false, d1 = false, d2 = false;
    for (;;) {
      if (!d0) { unsigned v = __hip_atomic_load(&hxc[soff0], __ATOMIC_RELAXED, __HIP_MEMORY_SCOPE_AGENT);
                 if ((v & 0xffffu) == tagv) { w0 = v; d0 = true; } }
      if (!d1) { unsigned v = __hip_atomic_load(&hxc[soff1], __ATOMIC_RELAXED, __HIP_MEMORY_SCOPE_AGENT);
                 if ((v & 0xffffu) == tagv) { w1 = v; d1 = true; } }
      if (!d2) { unsigned v = __hip_atomic_load(&hxc[soff2], __ATOMIC_RELAXED, __HIP_MEMORY_SCOPE_AGENT);
                 if ((v & 0xffffu) == tagv) { w2 = v; d2 = true; } }
      if (d0 && d1 && d2) break;
      __builtin_amdgcn_s_sleep(1);
    }
    *st0 = bf2f((unsigned short)(w0 >> 16));
    *st1 = bf2f((unsigned short)(w1 >> 16));
    *st2 = bf2f((unsigned short)(w2 >> 16));
    __syncthreads();
  }
  state[sbase] = hlast;
  state[65536 + sbase] = c_;
  state[2 * 65536 + sbase] = n_;
  state[3 * 65536 + sbase] = m_;
}

// ---------------- groupnorm + residual + post LN (bf16 in/out) ----------------
__global__ __launch_bounds__(256) void post_k(
    const unsigned short* __restrict__ y, const unsigned short* __restrict__ xp,
    const float* __restrict__ gnw, const float* __restrict__ lpw,
    unsigned short* __restrict__ outb) {
  const int r = blockIdx.x;            // r = b*512 + s
  const int b = r >> 9, s = r & 511;
  const int tid = threadIdx.x;
  const int lane = tid & 63, wave = tid >> 6;
  ushort4 yu = *(const ushort4*)(y + (size_t)(s * 64 + b) * H_ + tid * 4);
  float v[4] = {bf2f(yu.x), bf2f(yu.y), bf2f(yu.z), bf2f(yu.w)};
  float s1 = v[0] + v[1] + v[2] + v[3];
  float s2 = v[0] * v[0] + v[1] * v[1] + v[2] * v[2] + v[3] * v[3];
#pragma unroll
  for (int off = 32; off; off >>= 1) { s1 += __shfl_xor(s1, off); s2 += __shfl_xor(s2, off); }
  float mu = s1 * (1.f / HD_);
  float rstd = rsqrtf(s2 * (1.f / HD_) - mu * mu + 1e-5f);
  float4 g4 = *(const float4*)(gnw + tid * 4);
  ushort4 xu = *(const ushort4*)(xp + (size_t)r * H_ + tid * 4);
  float o[4];
  o[0] = fmaf((v[0] - mu) * rstd, g4.x, bf2f(xu.x));
  o[1] = fmaf((v[1] - mu) * rstd, g4.y, bf2f(xu.y));
  o[2] = fmaf((v[2] - mu) * rstd, g4.z, bf2f(xu.z));
  o[3] = fmaf((v[3] - mu) * rstd, g4.w, bf2f(xu.w));
  float t1 = o[0] + o[1] + o[2] + o[3];
  float t2 = o[0] * o[0] + o[1] * o[1] + o[2] * o[2] + o[3] * o[3];
#pragma unroll
  for (int off = 32; off; off >>= 1) { t1 += __shfl_xor(t1, off); t2 += __shfl_xor(t2, off); }
  __shared__ float a1[4], a2[4];
  if (lane == 0) { a1[wave] = t1; a2[wave] = t2; }
  __syncthreads();
  float T1 = a1[0] + a1[1] + a1[2] + a1[3];
  float T2 = a2[0] + a2[1] + a2[2] + a2[3];
  float MU = T1 * (1.f / H_);
  float RS = rsqrtf(T2 * (1.f / H_) - MU * MU + 1e-5f);
  float4 w4 = *(const float4*)(lpw + tid * 4);
  ushort4 res = {f2bf((o[0] - MU) * RS * w4.x), f2bf((o[1] - MU) * RS * w4.y),
                 f2bf((o[2] - MU) * RS * w4.z), f2bf((o[3] - MU) * RS * w4.w)};
  *(ushort4*)(outb + (size_t)r * H_ + tid * 4) = res;
}

// ---------------- logits + value heads (bf16 in, fp32 out) ----------------
__global__ __launch_bounds__(256) void heads_k(
    const unsigned short* __restrict__ hp, const unsigned short* __restrict__ hv,
    const float* __restrict__ Wact, const float* __restrict__ bact,
    const float* __restrict__ Wv, const float* __restrict__ bv,
    float* __restrict__ dout) {
  const int lane = threadIdx.x & 63, wave = threadIdx.x >> 6;
  const int r = blockIdx.x * 4 + wave;
  const unsigned short* hpr = hp + (size_t)r * HID_;
  const unsigned short* hvr = hv + (size_t)r * HID_;
  float acc[A_];
#pragma unroll
  for (int j = 0; j < A_; ++j) acc[j] = 0.f;
  float accv = 0.f;
  for (int i = 0; i < 16; ++i) {
    int k = i * 64 + lane;
    float hpv = bf2f(hpr[k]);
    float hvv = bf2f(hvr[k]);
#pragma unroll
    for (int j = 0; j < A_; ++j) acc[j] = fmaf(hpv, Wact[j * HID_ + k], acc[j]);
    accv = fmaf(hvv, Wv[k], accv);
  }
#pragma unroll
  for (int j = 0; j < A_; ++j)
#pragma unroll
    for (int off = 32; off; off >>= 1) acc[j] += __shfl_xor(acc[j], off);
#pragma unroll
  for (int off = 32; off; off >>= 1) accv += __shfl_xor(accv, off);
  if (lane == 0) {
#pragma unroll
    for (int j = 0; j < A_; ++j) dout[(size_t)r * A_ + j] = acc[j] + bact[j];
    dout[589824 + r] = accv + bv[0];
  }
}

// ---------------- launch ----------------
extern "C" void kernel_launch(void* const* d_in, const int* in_sizes, int n_in,
                              void* d_out, int out_size, void* d_ws, size_t ws_size,
                              hipStream_t stream) {
  const float* obs   = (const float*)d_in[0];
  const float* st    = (const float*)d_in[1];
  const float* W_in  = (const float*)d_in[2];
  const float* b_in  = (const float*)d_in[3];
  const float* ln1w  = (const float*)d_in[4];
  const float* wg    = (const float*)d_in[5];
  const float* R     = (const float*)d_in[6];
  const float* bgat  = (const float*)d_in[7];
  const float* gnw   = (const float*)d_in[8];
  const float* lpw   = (const float*)d_in[9];
  const float* W_hid = (const float*)d_in[10];
  const float* b_hid = (const float*)d_in[11];
  const float* W_pol = (const float*)d_in[12];
  const float* b_pol = (const float*)d_in[13];
  const float* W_val = (const float*)d_in[14];
  const float* b_val = (const float*)d_in[15];
  const float* W_act = (const float*)d_in[16];
  const float* b_act = (const float*)d_in[17];
  const float* W_v   = (const float*)d_in[18];
  const float* b_v   = (const float*)d_in[19];

  // Workspace layout (same NEEDED as the round that passed):
  //  A [0,        67108864): xproj bf16  -> hh bf16
  //  B [67108864, 134217728): gx chunk bf16 (T=128) -> outb bf16 -> hv bf16
  //  C [134217728,201326592): y bf16 -> hp bf16
  //  ST[201326592,202375168): scan state fp32 (h,c,n,m) 4x64x1024
  //  RS[202375168,202899456): LN1 row stats
  //  RB[202899456,204996608): R packed bf16 pairs [nh][g][e][dpair]
  const size_t NEEDED = 204996608;
  if (ws_size < NEEDED) return;  // diagnostic: clean absmax-fail => ws too small
  char* ws = (char*)d_ws;
  unsigned short* xproj = (unsigned short*)(ws + 0);
  unsigned short* gxc   = (unsigned short*)(ws + 67108864);
  unsigned short* ybuf  = (unsigned short*)(ws + 134217728);
  float* statebuf       = (float*)(ws + 201326592);
  float* rstat          = (float*)(ws + 202375168);
  unsigned* Rbb         = (unsigned*)(ws + 202899456);
  unsigned short* outb  = gxc;    // after last scan chunk
  unsigned short* hh    = xproj;  // after post_k
  unsigned short* hp    = ybuf;   // y dead after post_k
  unsigned short* hv    = gxc;    // after MLP1 consumed outb
  float* dout = (float*)d_out;
  // scan exchange words live in d_out's head (fully rewritten by heads_k later):
  //   hx double-buffer [2][64 grp][4 b][256 d] u32 = 524288 B (tag-in-word, no init needed)
  unsigned* hx = (unsigned*)d_out;

  // 0. seed scan state + transcode R
  hipMemcpyAsync(statebuf, st, 4 * 65536 * sizeof(float), hipMemcpyDeviceToDevice, stream);
  rtrans_k<<<2048, 256, 0, stream>>>(R, Rbb);
  // 1. x_proj = obs @ W_in^T + b_in   (M=32768,N=1024,K=512) -> bf16
  gemm_k<true, false, false, false, 0><<<dim3(256, 8), 256, 0, stream>>>(
      obs, W_in, b_in, nullptr, nullptr, xproj, 512, 512, 1024, 0);
  // 2. LN1 row stats
  rowstats_k<<<32768, 256, 0, stream>>>(xproj, rstat);
  // 3+4. per time-chunk: gate GEMM -> scan
  for (int c = 0; c < NCH_; ++c) {
    gemm_k<false, true, true, false, 1><<<dim3(64, 2, 16), 256, 0, stream>>>(
        xproj, wg, nullptr, rstat, ln1w, gxc, 256, 1024, 0, c);
    scan_k<<<256, 256, 0, stream>>>(gxc, Rbb, bgat, statebuf, ybuf, hx, c);
  }
  // 5. groupnorm + residual + post LN
  post_k<<<32768, 256, 0, stream>>>(ybuf, xproj, gnw, lpw, outb);
  // 6-8. hidden / policy / value MLPs (relu)
  gemm_k<true, true, false, true, 0><<<dim3(256, 8), 256, 0, stream>>>(
      outb, W_hid, b_hid, nullptr, nullptr, hh, 1024, 1024, 1024, 0);
  gemm_k<true, true, false, true, 0><<<dim3(256, 8), 256, 0, stream>>>(
      hh, W_pol, b_pol, nullptr, nullptr, hp, 1024, 1024, 1024, 0);
  gemm_k<true, true, false, true, 0><<<dim3(256, 8), 256, 0, stream>>>(
      hh, W_val, b_val, nullptr, nullptr, hv, 1024, 1024, 1024, 0);
  // 9. logits + value
  heads_k<<<8192, 256, 0, stream>>>(hp, hv, W_act, b_act, W_v, b_v, dout);
}

// Round 7
// 6702.779 us; speedup vs baseline: 4.6676x; 1.4457x over previous
//
#include <hip/hip_runtime.h>
#include <cstdint>
#include <cstddef>

#define B_ 64
#define S_ 512
#define IN_ 512
#define H_ 1024
#define NH_ 4
#define HD_ 256
#define A_ 18
#define HID_ 1024
#define TCH_ 128            // scan time-chunk
#define NCH_ (S_ / TCH_)    // 4 chunks

using short8 = __attribute__((ext_vector_type(8))) short;
using f32x4  = __attribute__((ext_vector_type(4))) float;

// ---------------- helpers ----------------
__device__ __forceinline__ unsigned short f2bf(float f) {
  union { float f; unsigned u; } c; c.f = f;
  unsigned r = c.u + 0x7FFFu + ((c.u >> 16) & 1u);  // RNE
  return (unsigned short)(r >> 16);
}
__device__ __forceinline__ float bf2f(unsigned short h) {
  union { unsigned u; float f; } c; c.u = ((unsigned)h) << 16;
  return c.f;
}
__device__ __forceinline__ unsigned pk2(float a, float b) {
  return (unsigned)f2bf(a) | ((unsigned)f2bf(b) << 16);
}

// ---------------- R transcode: fp32 [nh][d][g][e] -> packed bf16 pairs ----------------
__global__ __launch_bounds__(256) void rtrans_k(const float* __restrict__ R,
                                                unsigned* __restrict__ Rbb) {
  const int i = blockIdx.x * 256 + threadIdx.x;   // [0, 524288)
  const int dp = i & 127;
  const int e = (i >> 7) & 255;
  const int g = (i >> 15) & 3;
  const int nh = i >> 17;
  const float* rp = R + (((size_t)nh * 256 + 2 * dp) * 4 + g) * 256 + e;  // d-stride 1024
  unsigned lo = f2bf(rp[0]), hi = f2bf(rp[1024]);
  Rbb[i] = lo | (hi << 16);
}

// ---------------- w_gates transcode: fp32 [g][nh][d][e] -> bf16 [nh][g][e][d] ----------------
__global__ __launch_bounds__(256) void wgt_k(const float* __restrict__ wg,
                                             unsigned short* __restrict__ wgb) {
  const int i = blockIdx.x * 256 + threadIdx.x;   // [0, 1048576)
  const int k = i & 255;
  const int e = (i >> 8) & 255;
  const int g = (i >> 16) & 3;
  const int nh = i >> 18;
  wgb[i] = f2bf(wg[(((size_t)(g * 4 + nh) * 256 + k) * 256) + e]);
}

// ---------------- row stats for LN1 fusion (xproj is bf16) ----------------
__global__ __launch_bounds__(256) void rowstats_k(const unsigned short* __restrict__ x,
                                                  float* __restrict__ rs) {
  const int r = blockIdx.x, tid = threadIdx.x;
  const int lane = tid & 63, wave = tid >> 6;
  ushort4 u = *(const ushort4*)(x + (size_t)r * H_ + tid * 4);
  float v0 = bf2f(u.x), v1 = bf2f(u.y), v2 = bf2f(u.z), v3 = bf2f(u.w);
  float s1 = v0 + v1 + v2 + v3;
  float s2 = v0 * v0 + v1 * v1 + v2 * v2 + v3 * v3;
#pragma unroll
  for (int off = 32; off; off >>= 1) { s1 += __shfl_xor(s1, off); s2 += __shfl_xor(s2, off); }
  __shared__ float a1[4], a2[4];
  if (lane == 0) { a1[wave] = s1; a2[wave] = s2; }
  __syncthreads();
  if (tid == 0) {
    float S1 = a1[0] + a1[1] + a1[2] + a1[3];
    float S2 = a2[0] + a2[1] + a2[2] + a2[3];
    float mu = S1 * (1.f / H_);
    float var = S2 * (1.f / H_) - mu * mu;
    rs[r * 2] = mu;
    rs[r * 2 + 1] = rsqrtf(var + 1e-5f);
  }
}

// ---------------- MFMA bf16 GEMM, 128x128 tile, BK=32, 4 waves of 64x64 ----------------
// AMODE: 0 = A fp32 (cvt on stage), 1 = A bf16, 2 = A bf16 + fused LN(rs,lnw)
// BMODE: 0 = W fp32 (N,K) row-major (cvt on stage), 1 = W bf16 pre-laid [row=col][k]
// OUTMODE 0: bf16 row-major [r][1024] (+bias,+relu).  OUTMODE 1: gx chunk layout.
// LDS layout: [k-unit p(4)][row(128)] of 16B units -> ds_read_b128 2-way-free;
// A-frag: row=lane&15, k=(lane>>4)*8+j ; B-frag: col=lane&15, same k-map (k-order
// consistency between A and B is all that matters for the sum). C/D per m89:
// col=lane&15, row=(lane>>4)*4+reg.
template <int AMODE, int BMODE, bool RELU, int OUTMODE>
__global__ __launch_bounds__(256) void mgemm_k(
    const void* __restrict__ Av, const void* __restrict__ Wv,
    const float* __restrict__ bias, const float* __restrict__ rs,
    const float* __restrict__ lnw, unsigned short* __restrict__ Cb,
    int K, int lda, int chunk) {
  __shared__ uint4 As4[4][128];
  __shared__ uint4 Bs4[4][128];
  const int tid = threadIdx.x;
  const int lane = tid & 63, wave = tid >> 6;
  const int wr = wave >> 1, wc = wave & 1;
  const int col0 = blockIdx.y * 128;
  int nh = 0, g = 0, aoff = 0, bb = 0;
  size_t wbase = 0;
  if constexpr (OUTMODE == 1) {
    int z = blockIdx.z; nh = z >> 2; g = z & 3;
    aoff = nh * HD_;
    bb = blockIdx.x;
    wbase = (size_t)(nh * 4 + g) * 256 * 256;
  }
  auto arow = [&](int mm) -> int {
    if constexpr (OUTMODE == 1) return bb * 512 + chunk * TCH_ + mm;
    else return (int)blockIdx.x * 128 + mm;
  };
  f32x4 acc[4][4];
#pragma unroll
  for (int m = 0; m < 4; ++m)
#pragma unroll
    for (int n = 0; n < 4; ++n) acc[m][n] = 0.f;

  const int sm = tid >> 1;   // staging row
  const int sh = tid & 1;    // k half (16 elems)

  for (int k0 = 0; k0 < K; k0 += 32) {
    // ---- stage A row sm, k [k0+sh*16, +16) ----
    {
      int rg = arow(sm);
      unsigned pk[8];
      if constexpr (AMODE == 0) {
        const float* ap = (const float*)Av + (size_t)rg * lda + k0 + sh * 16;
#pragma unroll
        for (int q = 0; q < 4; ++q) {
          float4 f = ((const float4*)ap)[q];
          pk[2 * q] = pk2(f.x, f.y); pk[2 * q + 1] = pk2(f.z, f.w);
        }
      } else if constexpr (AMODE == 1) {
        const uint4* ap = (const uint4*)((const unsigned short*)Av + (size_t)rg * lda + aoff + k0 + sh * 16);
        uint4 u0 = ap[0], u1 = ap[1];
        pk[0] = u0.x; pk[1] = u0.y; pk[2] = u0.z; pk[3] = u0.w;
        pk[4] = u1.x; pk[5] = u1.y; pk[6] = u1.z; pk[7] = u1.w;
      } else {
        const uint4* ap = (const uint4*)((const unsigned short*)Av + (size_t)rg * lda + aoff + k0 + sh * 16);
        uint4 u0 = ap[0], u1 = ap[1];
        unsigned w8[8] = {u0.x, u0.y, u0.z, u0.w, u1.x, u1.y, u1.z, u1.w};
        float mu = rs[rg * 2], rstd = rs[rg * 2 + 1];
        const float* lw = lnw + aoff + k0 + sh * 16;
#pragma unroll
        for (int q = 0; q < 8; ++q) {
          float lo = (bf2f((unsigned short)w8[q]) - mu) * rstd * lw[2 * q];
          float hi = (bf2f((unsigned short)(w8[q] >> 16)) - mu) * rstd * lw[2 * q + 1];
          pk[q] = pk2(lo, hi);
        }
      }
      As4[2 * sh][sm]     = uint4{pk[0], pk[1], pk[2], pk[3]};
      As4[2 * sh + 1][sm] = uint4{pk[4], pk[5], pk[6], pk[7]};
    }
    // ---- stage B row (col) sm ----
    {
      unsigned pk[8];
      if constexpr (BMODE == 0) {
        const float* wp = (const float*)Wv + (size_t)(col0 + sm) * K + k0 + sh * 16;
#pragma unroll
        for (int q = 0; q < 4; ++q) {
          float4 f = ((const float4*)wp)[q];
          pk[2 * q] = pk2(f.x, f.y); pk[2 * q + 1] = pk2(f.z, f.w);
        }
      } else {
        const uint4* wp = (const uint4*)((const unsigned short*)Wv + wbase + (size_t)(col0 + sm) * 256 + k0 + sh * 16);
        uint4 u0 = wp[0], u1 = wp[1];
        pk[0] = u0.x; pk[1] = u0.y; pk[2] = u0.z; pk[3] = u0.w;
        pk[4] = u1.x; pk[5] = u1.y; pk[6] = u1.z; pk[7] = u1.w;
      }
      Bs4[2 * sh][sm]     = uint4{pk[0], pk[1], pk[2], pk[3]};
      Bs4[2 * sh + 1][sm] = uint4{pk[4], pk[5], pk[6], pk[7]};
    }
    __syncthreads();
    short8 af[4], bfv[4];
#pragma unroll
    for (int m = 0; m < 4; ++m)
      af[m] = *(const short8*)&As4[lane >> 4][wr * 64 + m * 16 + (lane & 15)];
#pragma unroll
    for (int n = 0; n < 4; ++n)
      bfv[n] = *(const short8*)&Bs4[lane >> 4][wc * 64 + n * 16 + (lane & 15)];
#pragma unroll
    for (int m = 0; m < 4; ++m)
#pragma unroll
      for (int n = 0; n < 4; ++n)
        acc[m][n] = __builtin_amdgcn_mfma_f32_16x16x32_bf16(af[m], bfv[n], acc[m][n], 0, 0, 0);
    __syncthreads();
  }
  // ---- epilogue ----
  if constexpr (OUTMODE == 0) {
#pragma unroll
    for (int n = 0; n < 4; ++n) {
      int c = col0 + wc * 64 + n * 16 + (lane & 15);
      float bc = bias ? bias[c] : 0.f;
#pragma unroll
      for (int m = 0; m < 4; ++m) {
        int r0 = arow(wr * 64 + m * 16 + ((lane >> 4) << 2));
#pragma unroll
        for (int i = 0; i < 4; ++i) {
          float v = acc[m][n][i] + bc;
          if constexpr (RELU) v = fmaxf(v, 0.f);
          Cb[(size_t)(r0 + i) * 1024 + c] = f2bf(v);
        }
      }
    }
  } else {
#pragma unroll
    for (int n = 0; n < 4; ++n) {
      int e = col0 + wc * 64 + n * 16 + (lane & 15);
#pragma unroll
      for (int m = 0; m < 4; ++m) {
        int sl0 = wr * 64 + m * 16 + ((lane >> 4) << 2);
#pragma unroll
        for (int i = 0; i < 4; ++i) {
          int sl = sl0 + i;
          size_t base = (size_t)(sl * 64 + bb) * 4096 + nh * 1024 + g * 256;
          Cb[base + e] = f2bf(acc[m][n][i]);
        }
      }
    }
  }
}

// ---------------- sLSTM scan: 256 blocks = (nh, e-slice, batch-group), R in regs ----------------
// Exchange word = bf16(h)<<16 | (step+1) tag (data+flag fused, relaxed agent atomics).
// Round-7 reorder: poll loads are batched (3 in flight, one wait) and the y-store +
// gx prefetch are issued AFTER the poll so the poll's vmcnt drain never waits on
// HBM traffic; their latency hides under the next step's matvec.
__global__ __launch_bounds__(256, 1) void scan_k(
    const unsigned short* __restrict__ gxc, const unsigned* __restrict__ Rbb,
    const float* __restrict__ bgates, float* __restrict__ state,
    unsigned short* __restrict__ y, unsigned* hx, int chunk) {
  const int tid = threadIdx.x;
  const int bid = blockIdx.x;
  const int nh = bid >> 6, esl = (bid >> 4) & 3, bgrp = bid & 15;
  const int g = tid >> 6, eo = tid & 63;
  __shared__ float hsh[256][4];     // h[d][b]
  __shared__ float rawsh[64][17];   // raw[e][b*4+g]

  unsigned rcol[128];
  {
    const unsigned* rp = Rbb + ((size_t)(nh * 4 + g) * 256 + esl * 64 + eo) * 128;
#pragma unroll
    for (int i = 0; i < 128; ++i) rcol[i] = rp[i];
  }
  const float bg = bgates[g * H_ + nh * HD_ + esl * 64 + eo];

  const int ob = tid >> 6, oe = tid & 63;
  const int od = esl * 64 + oe;
  const size_t sbase = (size_t)(bgrp * 4 + ob) * H_ + nh * HD_ + od;
  float c_ = state[65536 + sbase];
  float n_ = state[2 * 65536 + sbase];
  float m_ = state[3 * 65536 + sbase];
  float hlast = state[sbase];

#pragma unroll
  for (int r = 0; r < 4; ++r) {
    int idx = r * 256 + tid;
    int d = idx >> 2, b = idx & 3;
    hsh[d][b] = state[(size_t)(bgrp * 4 + b) * H_ + nh * HD_ + d];
  }
  __syncthreads();

  const int grp = nh * 16 + bgrp;
  unsigned* hx0 = hx + (size_t)grp * 1024;
  unsigned* hx1 = hx + 65536 + (size_t)grp * 1024;
  const int ownoff = ob * 256 + od;
  int soff0, soff1, soff2;
  float *st0, *st1, *st2;
  {
    int idx, b, dof, d;
    idx = tid;        b = idx & 3; dof = idx >> 2; d = (dof < esl * 64) ? dof : dof + 64;
    soff0 = b * 256 + d; st0 = &hsh[d][b];
    idx = 256 + tid;  b = idx & 3; dof = idx >> 2; d = (dof < esl * 64) ? dof : dof + 64;
    soff1 = b * 256 + d; st1 = &hsh[d][b];
    idx = 512 + tid;  b = idx & 3; dof = idx >> 2; d = (dof < esl * 64) ? dof : dof + 64;
    soff2 = b * 256 + d; st2 = &hsh[d][b];
  }
  const unsigned short* gp = gxc + (size_t)(bgrp * 4) * 4096 + nh * 1024 + g * 256 + esl * 64 + eo;
  unsigned short* yp = y + ((size_t)(chunk * TCH_) * 64 + bgrp * 4) * H_ + nh * HD_;

  float g0 = bf2f(gp[0]), g1 = bf2f(gp[4096]), g2 = bf2f(gp[8192]), g3 = bf2f(gp[12288]);

  for (int t = 0; t < TCH_; ++t) {
    const int tg = chunk * TCH_ + t;
    unsigned* hxc = (tg & 1) ? hx1 : hx0;
    const unsigned tagv = (unsigned)(tg + 1) & 0xffffu;
    float acc0 = g0 + bg, acc1 = g1 + bg, acc2 = g2 + bg, acc3 = g3 + bg;
#pragma unroll
    for (int dp = 0; dp < 128; ++dp) {
      unsigned u = rcol[dp];
      float rl = __uint_as_float(u << 16);
      float rh = __uint_as_float(u & 0xffff0000u);
      float4 ha = *(const float4*)&hsh[2 * dp][0];
      float4 hb = *(const float4*)&hsh[2 * dp + 1][0];
      acc0 = fmaf(rl, ha.x, acc0); acc1 = fmaf(rl, ha.y, acc1);
      acc2 = fmaf(rl, ha.z, acc2); acc3 = fmaf(rl, ha.w, acc3);
      acc0 = fmaf(rh, hb.x, acc0); acc1 = fmaf(rh, hb.y, acc1);
      acc2 = fmaf(rh, hb.z, acc2); acc3 = fmaf(rh, hb.w, acc3);
    }
    rawsh[eo][0 * 4 + g] = acc0;
    rawsh[eo][1 * 4 + g] = acc1;
    rawsh[eo][2 * 4 + g] = acc2;
    rawsh[eo][3 * 4 + g] = acc3;
    __syncthreads();
    // pointwise + publish (only vm op before the poll -> minimal vmcnt drain)
    {
      float iraw = rawsh[oe][ob * 4 + 0];
      float fraw = rawsh[oe][ob * 4 + 1];
      float zraw = rawsh[oe][ob * 4 + 2];
      float oraw = rawsh[oe][ob * 4 + 3];
      float ls = -log1pf(expf(-fabsf(fraw)));
      if (fraw < 0.f) ls += fraw;                 // log_sigmoid(fraw)
      float lfm = m_ + ls;
      float mnew = fmaxf(iraw, lfm);
      float iv = expf(iraw - mnew);
      float fv = expf(lfm - mnew);
      c_ = fv * c_ + iv * tanhf(zraw);
      n_ = fv * n_ + iv;
      m_ = mnew;
      hlast = c_ / n_ / (1.f + expf(-oraw));
      hsh[od][ob] = hlast;
      unsigned hw = ((unsigned)f2bf(hlast) << 16) | tagv;
      __hip_atomic_store(&hxc[ownoff], hw, __ATOMIC_RELAXED, __HIP_MEMORY_SCOPE_AGENT);
    }
    // batched poll: 3 loads in flight, single wait per iteration
    unsigned w0, w1, w2;
    for (;;) {
      unsigned v0 = __hip_atomic_load(&hxc[soff0], __ATOMIC_RELAXED, __HIP_MEMORY_SCOPE_AGENT);
      unsigned v1 = __hip_atomic_load(&hxc[soff1], __ATOMIC_RELAXED, __HIP_MEMORY_SCOPE_AGENT);
      unsigned v2 = __hip_atomic_load(&hxc[soff2], __ATOMIC_RELAXED, __HIP_MEMORY_SCOPE_AGENT);
      unsigned bad = (((v0 & 0xffffu) ^ tagv) | ((v1 & 0xffffu) ^ tagv) | ((v2 & 0xffffu) ^ tagv));
      if (bad == 0u) { w0 = v0; w1 = v1; w2 = v2; break; }
      __builtin_amdgcn_s_sleep(1);
    }
    *st0 = bf2f((unsigned short)(w0 >> 16));
    *st1 = bf2f((unsigned short)(w1 >> 16));
    *st2 = bf2f((unsigned short)(w2 >> 16));
    // deferred HBM traffic: y-store + next-step gx prefetch (hide under next matvec)
    yp[(size_t)(t * 64 + ob) * H_ + od] = f2bf(hlast);
    if (t < TCH_ - 1) {
      const unsigned short* gn = gp + (size_t)(t + 1) * 262144;
      g0 = bf2f(gn[0]); g1 = bf2f(gn[4096]); g2 = bf2f(gn[8192]); g3 = bf2f(gn[12288]);
    }
    __syncthreads();
  }
  state[sbase] = hlast;
  state[65536 + sbase] = c_;
  state[2 * 65536 + sbase] = n_;
  state[3 * 65536 + sbase] = m_;
}

// ---------------- groupnorm + residual + post LN (bf16 in/out) ----------------
__global__ __launch_bounds__(256) void post_k(
    const unsigned short* __restrict__ y, const unsigned short* __restrict__ xp,
    const float* __restrict__ gnw, const float* __restrict__ lpw,
    unsigned short* __restrict__ outb) {
  const int r = blockIdx.x;            // r = b*512 + s
  const int b = r >> 9, s = r & 511;
  const int tid = threadIdx.x;
  const int lane = tid & 63, wave = tid >> 6;
  ushort4 yu = *(const ushort4*)(y + (size_t)(s * 64 + b) * H_ + tid * 4);
  float v[4] = {bf2f(yu.x), bf2f(yu.y), bf2f(yu.z), bf2f(yu.w)};
  float s1 = v[0] + v[1] + v[2] + v[3];
  float s2 = v[0] * v[0] + v[1] * v[1] + v[2] * v[2] + v[3] * v[3];
#pragma unroll
  for (int off = 32; off; off >>= 1) { s1 += __shfl_xor(s1, off); s2 += __shfl_xor(s2, off); }
  float mu = s1 * (1.f / HD_);
  float rstd = rsqrtf(s2 * (1.f / HD_) - mu * mu + 1e-5f);
  float4 g4 = *(const float4*)(gnw + tid * 4);
  ushort4 xu = *(const ushort4*)(xp + (size_t)r * H_ + tid * 4);
  float o[4];
  o[0] = fmaf((v[0] - mu) * rstd, g4.x, bf2f(xu.x));
  o[1] = fmaf((v[1] - mu) * rstd, g4.y, bf2f(xu.y));
  o[2] = fmaf((v[2] - mu) * rstd, g4.z, bf2f(xu.z));
  o[3] = fmaf((v[3] - mu) * rstd, g4.w, bf2f(xu.w));
  float t1 = o[0] + o[1] + o[2] + o[3];
  float t2 = o[0] * o[0] + o[1] * o[1] + o[2] * o[2] + o[3] * o[3];
#pragma unroll
  for (int off = 32; off; off >>= 1) { t1 += __shfl_xor(t1, off); t2 += __shfl_xor(t2, off); }
  __shared__ float a1[4], a2[4];
  if (lane == 0) { a1[wave] = t1; a2[wave] = t2; }
  __syncthreads();
  float T1 = a1[0] + a1[1] + a1[2] + a1[3];
  float T2 = a2[0] + a2[1] + a2[2] + a2[3];
  float MU = T1 * (1.f / H_);
  float RS = rsqrtf(T2 * (1.f / H_) - MU * MU + 1e-5f);
  float4 w4 = *(const float4*)(lpw + tid * 4);
  ushort4 res = {f2bf((o[0] - MU) * RS * w4.x), f2bf((o[1] - MU) * RS * w4.y),
                 f2bf((o[2] - MU) * RS * w4.z), f2bf((o[3] - MU) * RS * w4.w)};
  *(ushort4*)(outb + (size_t)r * H_ + tid * 4) = res;
}

// ---------------- logits + value heads (bf16 in, fp32 out) ----------------
__global__ __launch_bounds__(256) void heads_k(
    const unsigned short* __restrict__ hp, const unsigned short* __restrict__ hv,
    const float* __restrict__ Wact, const float* __restrict__ bact,
    const float* __restrict__ Wv, const float* __restrict__ bv,
    float* __restrict__ dout) {
  const int lane = threadIdx.x & 63, wave = threadIdx.x >> 6;
  const int r = blockIdx.x * 4 + wave;
  const unsigned short* hpr = hp + (size_t)r * HID_;
  const unsigned short* hvr = hv + (size_t)r * HID_;
  float acc[A_];
#pragma unroll
  for (int j = 0; j < A_; ++j) acc[j] = 0.f;
  float accv = 0.f;
  for (int i = 0; i < 16; ++i) {
    int k = i * 64 + lane;
    float hpv = bf2f(hpr[k]);
    float hvv = bf2f(hvr[k]);
#pragma unroll
    for (int j = 0; j < A_; ++j) acc[j] = fmaf(hpv, Wact[j * HID_ + k], acc[j]);
    accv = fmaf(hvv, Wv[k], accv);
  }
#pragma unroll
  for (int j = 0; j < A_; ++j)
#pragma unroll
    for (int off = 32; off; off >>= 1) acc[j] += __shfl_xor(acc[j], off);
#pragma unroll
  for (int off = 32; off; off >>= 1) accv += __shfl_xor(accv, off);
  if (lane == 0) {
#pragma unroll
    for (int j = 0; j < A_; ++j) dout[(size_t)r * A_ + j] = acc[j] + bact[j];
    dout[589824 + r] = accv + bv[0];
  }
}

// ---------------- launch ----------------
extern "C" void kernel_launch(void* const* d_in, const int* in_sizes, int n_in,
                              void* d_out, int out_size, void* d_ws, size_t ws_size,
                              hipStream_t stream) {
  const float* obs   = (const float*)d_in[0];
  const float* st    = (const float*)d_in[1];
  const float* W_in  = (const float*)d_in[2];
  const float* b_in  = (const float*)d_in[3];
  const float* ln1w  = (const float*)d_in[4];
  const float* wg    = (const float*)d_in[5];
  const float* R     = (const float*)d_in[6];
  const float* bgat  = (const float*)d_in[7];
  const float* gnw   = (const float*)d_in[8];
  const float* lpw   = (const float*)d_in[9];
  const float* W_hid = (const float*)d_in[10];
  const float* b_hid = (const float*)d_in[11];
  const float* W_pol = (const float*)d_in[12];
  const float* b_pol = (const float*)d_in[13];
  const float* W_val = (const float*)d_in[14];
  const float* b_val = (const float*)d_in[15];
  const float* W_act = (const float*)d_in[16];
  const float* b_act = (const float*)d_in[17];
  const float* W_v   = (const float*)d_in[18];
  const float* b_v   = (const float*)d_in[19];

  // Workspace layout:
  //  A [0,        67108864): xproj bf16  -> hh bf16
  //  B [67108864, 134217728): gx chunk bf16 (T=128) -> outb bf16 -> hv bf16
  //  C [134217728,201326592): y bf16 -> hp bf16
  //  ST[201326592,202375168): scan state fp32 (h,c,n,m) 4x64x1024
  //  RS[202375168,202899456): LN1 row stats
  //  RB[202899456,204996608): R packed bf16 pairs [nh][g][e][dpair]
  //  WG[204996608,207093760): w_gates bf16 [nh][g][e][k]
  const size_t NEEDED = 207093760;
  if (ws_size < NEEDED) return;  // diagnostic: clean absmax-fail => ws too small
  char* ws = (char*)d_ws;
  unsigned short* xproj = (unsigned short*)(ws + 0);
  unsigned short* gxc   = (unsigned short*)(ws + 67108864);
  unsigned short* ybuf  = (unsigned short*)(ws + 134217728);
  float* statebuf       = (float*)(ws + 201326592);
  float* rstat          = (float*)(ws + 202375168);
  unsigned* Rbb         = (unsigned*)(ws + 202899456);
  unsigned short* wgb   = (unsigned short*)(ws + 204996608);
  unsigned short* outb  = gxc;    // after last scan chunk
  unsigned short* hh    = xproj;  // after post_k
  unsigned short* hp    = ybuf;   // y dead after post_k
  unsigned short* hv    = gxc;    // after MLP1 consumed outb
  float* dout = (float*)d_out;
  // scan exchange words live in d_out's head (rewritten by heads_k later):
  unsigned* hx = (unsigned*)d_out;   // [2][64 grp][4 b][256 d] u32 = 524288 B

  // 0. seed scan state + transcode R and w_gates
  hipMemcpyAsync(statebuf, st, 4 * 65536 * sizeof(float), hipMemcpyDeviceToDevice, stream);
  rtrans_k<<<2048, 256, 0, stream>>>(R, Rbb);
  wgt_k<<<4096, 256, 0, stream>>>(wg, wgb);
  // 1. x_proj = obs @ W_in^T + b_in   (MFMA, A fp32 cvt)
  mgemm_k<0, 0, false, 0><<<dim3(256, 8), 256, 0, stream>>>(
      obs, W_in, b_in, nullptr, nullptr, xproj, 512, 512, 0);
  // 2. LN1 row stats
  rowstats_k<<<32768, 256, 0, stream>>>(xproj, rstat);
  // 3+4. per time-chunk: gate GEMM (MFMA, fused LN) -> scan
  for (int c = 0; c < NCH_; ++c) {
    mgemm_k<2, 1, false, 1><<<dim3(64, 2, 16), 256, 0, stream>>>(
        xproj, wgb, nullptr, rstat, ln1w, gxc, 256, 1024, c);
    scan_k<<<256, 256, 0, stream>>>(gxc, Rbb, bgat, statebuf, ybuf, hx, c);
  }
  // 5. groupnorm + residual + post LN
  post_k<<<32768, 256, 0, stream>>>(ybuf, xproj, gnw, lpw, outb);
  // 6-8. hidden / policy / value MLPs (MFMA, relu)
  mgemm_k<1, 0, true, 0><<<dim3(256, 8), 256, 0, stream>>>(
      outb, W_hid, b_hid, nullptr, nullptr, hh, 1024, 1024, 0);
  mgemm_k<1, 0, true, 0><<<dim3(256, 8), 256, 0, stream>>>(
      hh, W_pol, b_pol, nullptr, nullptr, hp, 1024, 1024, 0);
  mgemm_k<1, 0, true, 0><<<dim3(256, 8), 256, 0, stream>>>(
      hh, W_val, b_val, nullptr, nullptr, hv, 1024, 1024, 0);
  // 9. logits + value
  heads_k<<<8192, 256, 0, stream>>>(hp, hv, W_act, b_act, W_v, b_v, dout);
}

// Round 9
// 6687.068 us; speedup vs baseline: 4.6786x; 1.0023x over previous
//
#include <hip/hip_runtime.h>
#include <cstdint>
#include <cstddef>

#define B_ 64
#define S_ 512
#define IN_ 512
#define H_ 1024
#define NH_ 4
#define HD_ 256
#define A_ 18
#define HID_ 1024
#define TCH_ 128            // scan time-chunk
#define NCH_ (S_ / TCH_)    // 4 chunks

using short8 = __attribute__((ext_vector_type(8))) short;
using f32x4  = __attribute__((ext_vector_type(4))) float;

// ---------------- helpers ----------------
__device__ __forceinline__ unsigned short f2bf(float f) {
  union { float f; unsigned u; } c; c.f = f;
  unsigned r = c.u + 0x7FFFu + ((c.u >> 16) & 1u);  // RNE
  return (unsigned short)(r >> 16);
}
__device__ __forceinline__ float bf2f(unsigned short h) {
  union { unsigned u; float f; } c; c.u = ((unsigned)h) << 16;
  return c.f;
}
__device__ __forceinline__ unsigned pk2(float a, float b) {
  return (unsigned)f2bf(a) | ((unsigned)f2bf(b) << 16);
}

// ---------------- R transcode: fp32 [nh][d][g][e] -> packed bf16 pairs ----------------
__global__ __launch_bounds__(256) void rtrans_k(const float* __restrict__ R,
                                                unsigned* __restrict__ Rbb) {
  const int i = blockIdx.x * 256 + threadIdx.x;   // [0, 524288)
  const int dp = i & 127;
  const int e = (i >> 7) & 255;
  const int g = (i >> 15) & 3;
  const int nh = i >> 17;
  const float* rp = R + (((size_t)nh * 256 + 2 * dp) * 4 + g) * 256 + e;  // d-stride 1024
  unsigned lo = f2bf(rp[0]), hi = f2bf(rp[1024]);
  Rbb[i] = lo | (hi << 16);
}

// ---------------- w_gates transcode: fp32 [g][nh][d][e] -> bf16 [nh][g][e][d] ----------------
__global__ __launch_bounds__(256) void wgt_k(const float* __restrict__ wg,
                                             unsigned short* __restrict__ wgb) {
  const int i = blockIdx.x * 256 + threadIdx.x;   // [0, 1048576)
  const int k = i & 255;
  const int e = (i >> 8) & 255;
  const int g = (i >> 16) & 3;
  const int nh = i >> 18;
  wgb[i] = f2bf(wg[(((size_t)(g * 4 + nh) * 256 + k) * 256) + e]);
}

// ---------------- row stats for LN1 fusion (xproj is bf16) ----------------
__global__ __launch_bounds__(256) void rowstats_k(const unsigned short* __restrict__ x,
                                                  float* __restrict__ rs) {
  const int r = blockIdx.x, tid = threadIdx.x;
  const int lane = tid & 63, wave = tid >> 6;
  ushort4 u = *(const ushort4*)(x + (size_t)r * H_ + tid * 4);
  float v0 = bf2f(u.x), v1 = bf2f(u.y), v2 = bf2f(u.z), v3 = bf2f(u.w);
  float s1 = v0 + v1 + v2 + v3;
  float s2 = v0 * v0 + v1 * v1 + v2 * v2 + v3 * v3;
#pragma unroll
  for (int off = 32; off; off >>= 1) { s1 += __shfl_xor(s1, off); s2 += __shfl_xor(s2, off); }
  __shared__ float a1[4], a2[4];
  if (lane == 0) { a1[wave] = s1; a2[wave] = s2; }
  __syncthreads();
  if (tid == 0) {
    float S1 = a1[0] + a1[1] + a1[2] + a1[3];
    float S2 = a2[0] + a2[1] + a2[2] + a2[3];
    float mu = S1 * (1.f / H_);
    float var = S2 * (1.f / H_) - mu * mu;
    rs[r * 2] = mu;
    rs[r * 2 + 1] = rsqrtf(var + 1e-5f);
  }
}

// ---------------- MFMA bf16 GEMM, 128x128 tile, BK=32, 4 waves of 64x64 ----------------
template <int AMODE, int BMODE, bool RELU, int OUTMODE>
__global__ __launch_bounds__(256) void mgemm_k(
    const void* __restrict__ Av, const void* __restrict__ Wv,
    const float* __restrict__ bias, const float* __restrict__ rs,
    const float* __restrict__ lnw, unsigned short* __restrict__ Cb,
    int K, int lda, int chunk) {
  __shared__ uint4 As4[4][128];
  __shared__ uint4 Bs4[4][128];
  const int tid = threadIdx.x;
  const int lane = tid & 63, wave = tid >> 6;
  const int wr = wave >> 1, wc = wave & 1;
  const int col0 = blockIdx.y * 128;
  int nh = 0, g = 0, aoff = 0, bb = 0;
  size_t wbase = 0;
  if constexpr (OUTMODE == 1) {
    int z = blockIdx.z; nh = z >> 2; g = z & 3;
    aoff = nh * HD_;
    bb = blockIdx.x;
    wbase = (size_t)(nh * 4 + g) * 256 * 256;
  }
  auto arow = [&](int mm) -> int {
    if constexpr (OUTMODE == 1) return bb * 512 + chunk * TCH_ + mm;
    else return (int)blockIdx.x * 128 + mm;
  };
  f32x4 acc[4][4];
#pragma unroll
  for (int m = 0; m < 4; ++m)
#pragma unroll
    for (int n = 0; n < 4; ++n) acc[m][n] = 0.f;

  const int sm = tid >> 1;   // staging row
  const int sh = tid & 1;    // k half (16 elems)

  for (int k0 = 0; k0 < K; k0 += 32) {
    {
      int rg = arow(sm);
      unsigned pk[8];
      if constexpr (AMODE == 0) {
        const float* ap = (const float*)Av + (size_t)rg * lda + k0 + sh * 16;
#pragma unroll
        for (int q = 0; q < 4; ++q) {
          float4 f = ((const float4*)ap)[q];
          pk[2 * q] = pk2(f.x, f.y); pk[2 * q + 1] = pk2(f.z, f.w);
        }
      } else if constexpr (AMODE == 1) {
        const uint4* ap = (const uint4*)((const unsigned short*)Av + (size_t)rg * lda + aoff + k0 + sh * 16);
        uint4 u0 = ap[0], u1 = ap[1];
        pk[0] = u0.x; pk[1] = u0.y; pk[2] = u0.z; pk[3] = u0.w;
        pk[4] = u1.x; pk[5] = u1.y; pk[6] = u1.z; pk[7] = u1.w;
      } else {
        const uint4* ap = (const uint4*)((const unsigned short*)Av + (size_t)rg * lda + aoff + k0 + sh * 16);
        uint4 u0 = ap[0], u1 = ap[1];
        unsigned w8[8] = {u0.x, u0.y, u0.z, u0.w, u1.x, u1.y, u1.z, u1.w};
        float mu = rs[rg * 2], rstd = rs[rg * 2 + 1];
        const float* lw = lnw + aoff + k0 + sh * 16;
#pragma unroll
        for (int q = 0; q < 8; ++q) {
          float lo = (bf2f((unsigned short)w8[q]) - mu) * rstd * lw[2 * q];
          float hi = (bf2f((unsigned short)(w8[q] >> 16)) - mu) * rstd * lw[2 * q + 1];
          pk[q] = pk2(lo, hi);
        }
      }
      As4[2 * sh][sm]     = uint4{pk[0], pk[1], pk[2], pk[3]};
      As4[2 * sh + 1][sm] = uint4{pk[4], pk[5], pk[6], pk[7]};
    }
    {
      unsigned pk[8];
      if constexpr (BMODE == 0) {
        const float* wp = (const float*)Wv + (size_t)(col0 + sm) * K + k0 + sh * 16;
#pragma unroll
        for (int q = 0; q < 4; ++q) {
          float4 f = ((const float4*)wp)[q];
          pk[2 * q] = pk2(f.x, f.y); pk[2 * q + 1] = pk2(f.z, f.w);
        }
      } else {
        const uint4* wp = (const uint4*)((const unsigned short*)Wv + wbase + (size_t)(col0 + sm) * 256 + k0 + sh * 16);
        uint4 u0 = wp[0], u1 = wp[1];
        pk[0] = u0.x; pk[1] = u0.y; pk[2] = u0.z; pk[3] = u0.w;
        pk[4] = u1.x; pk[5] = u1.y; pk[6] = u1.z; pk[7] = u1.w;
      }
      Bs4[2 * sh][sm]     = uint4{pk[0], pk[1], pk[2], pk[3]};
      Bs4[2 * sh + 1][sm] = uint4{pk[4], pk[5], pk[6], pk[7]};
    }
    __syncthreads();
    short8 af[4], bfv[4];
#pragma unroll
    for (int m = 0; m < 4; ++m)
      af[m] = *(const short8*)&As4[lane >> 4][wr * 64 + m * 16 + (lane & 15)];
#pragma unroll
    for (int n = 0; n < 4; ++n)
      bfv[n] = *(const short8*)&Bs4[lane >> 4][wc * 64 + n * 16 + (lane & 15)];
#pragma unroll
    for (int m = 0; m < 4; ++m)
#pragma unroll
      for (int n = 0; n < 4; ++n)
        acc[m][n] = __builtin_amdgcn_mfma_f32_16x16x32_bf16(af[m], bfv[n], acc[m][n], 0, 0, 0);
    __syncthreads();
  }
  if constexpr (OUTMODE == 0) {
#pragma unroll
    for (int n = 0; n < 4; ++n) {
      int c = col0 + wc * 64 + n * 16 + (lane & 15);
      float bc = bias ? bias[c] : 0.f;
#pragma unroll
      for (int m = 0; m < 4; ++m) {
        int r0 = arow(wr * 64 + m * 16 + ((lane >> 4) << 2));
#pragma unroll
        for (int i = 0; i < 4; ++i) {
          float v = acc[m][n][i] + bc;
          if constexpr (RELU) v = fmaxf(v, 0.f);
          Cb[(size_t)(r0 + i) * 1024 + c] = f2bf(v);
        }
      }
    }
  } else {
#pragma unroll
    for (int n = 0; n < 4; ++n) {
      int e = col0 + wc * 64 + n * 16 + (lane & 15);
#pragma unroll
      for (int m = 0; m < 4; ++m) {
        int sl0 = wr * 64 + m * 16 + ((lane >> 4) << 2);
#pragma unroll
        for (int i = 0; i < 4; ++i) {
          int sl = sl0 + i;
          size_t base = (size_t)(sl * 64 + bb) * 4096 + nh * 1024 + g * 256;
          Cb[base + e] = f2bf(acc[m][n][i]);
        }
      }
    }
  }
}

// ---------------- sLSTM scan: 256 blocks = (nh, e-slice, batch-group), R in regs ----------------
// Exchange word = bf16(h)<<16 | (step+1) tag, relaxed agent atomics (round-7 protocol,
// known-correct). Round-9: hx moved from d_out to d_ws — d_out may be host-visible
// memory (PCIe latency would explain the transport-invariant ~9us/step exchange cost).
__global__ __launch_bounds__(256, 1) void scan_k(
    const unsigned short* __restrict__ gxc, const unsigned* __restrict__ Rbb,
    const float* __restrict__ bgates, float* __restrict__ state,
    unsigned short* __restrict__ y, unsigned* hx, int chunk) {
  const int tid = threadIdx.x;
  const int bid = blockIdx.x;
  const int nh = bid >> 6, esl = (bid >> 4) & 3, bgrp = bid & 15;
  const int g = tid >> 6, eo = tid & 63;
  __shared__ float hsh[256][4];     // h[d][b]
  __shared__ float rawsh[64][17];   // raw[e][b*4+g]

  unsigned rcol[128];
  {
    const unsigned* rp = Rbb + ((size_t)(nh * 4 + g) * 256 + esl * 64 + eo) * 128;
#pragma unroll
    for (int i = 0; i < 128; ++i) rcol[i] = rp[i];
  }
  const float bg = bgates[g * H_ + nh * HD_ + esl * 64 + eo];

  const int ob = tid >> 6, oe = tid & 63;
  const int od = esl * 64 + oe;
  const size_t sbase = (size_t)(bgrp * 4 + ob) * H_ + nh * HD_ + od;
  float c_ = state[65536 + sbase];
  float n_ = state[2 * 65536 + sbase];
  float m_ = state[3 * 65536 + sbase];
  float hlast = state[sbase];

#pragma unroll
  for (int r = 0; r < 4; ++r) {
    int idx = r * 256 + tid;
    int d = idx >> 2, b = idx & 3;
    hsh[d][b] = state[(size_t)(bgrp * 4 + b) * H_ + nh * HD_ + d];
  }
  __syncthreads();

  const int grp = nh * 16 + bgrp;
  unsigned* hx0 = hx + (size_t)grp * 1024;
  unsigned* hx1 = hx + 65536 + (size_t)grp * 1024;
  const int ownoff = ob * 256 + od;
  int soff0, soff1, soff2;
  float *st0, *st1, *st2;
  {
    int idx, b, dof, d;
    idx = tid;        b = idx & 3; dof = idx >> 2; d = (dof < esl * 64) ? dof : dof + 64;
    soff0 = b * 256 + d; st0 = &hsh[d][b];
    idx = 256 + tid;  b = idx & 3; dof = idx >> 2; d = (dof < esl * 64) ? dof : dof + 64;
    soff1 = b * 256 + d; st1 = &hsh[d][b];
    idx = 512 + tid;  b = idx & 3; dof = idx >> 2; d = (dof < esl * 64) ? dof : dof + 64;
    soff2 = b * 256 + d; st2 = &hsh[d][b];
  }
  const unsigned short* gp = gxc + (size_t)(bgrp * 4) * 4096 + nh * 1024 + g * 256 + esl * 64 + eo;
  unsigned short* yp = y + ((size_t)(chunk * TCH_) * 64 + bgrp * 4) * H_ + nh * HD_;

  float g0 = bf2f(gp[0]), g1 = bf2f(gp[4096]), g2 = bf2f(gp[8192]), g3 = bf2f(gp[12288]);

  for (int t = 0; t < TCH_; ++t) {
    const int tg = chunk * TCH_ + t;
    unsigned* hxc = (tg & 1) ? hx1 : hx0;
    const unsigned tagv = (unsigned)(tg + 1) & 0xffffu;
    float acc0 = g0 + bg, acc1 = g1 + bg, acc2 = g2 + bg, acc3 = g3 + bg;
#pragma unroll
    for (int dp = 0; dp < 128; ++dp) {
      unsigned u = rcol[dp];
      float rl = __uint_as_float(u << 16);
      float rh = __uint_as_float(u & 0xffff0000u);
      float4 ha = *(const float4*)&hsh[2 * dp][0];
      float4 hb = *(const float4*)&hsh[2 * dp + 1][0];
      acc0 = fmaf(rl, ha.x, acc0); acc1 = fmaf(rl, ha.y, acc1);
      acc2 = fmaf(rl, ha.z, acc2); acc3 = fmaf(rl, ha.w, acc3);
      acc0 = fmaf(rh, hb.x, acc0); acc1 = fmaf(rh, hb.y, acc1);
      acc2 = fmaf(rh, hb.z, acc2); acc3 = fmaf(rh, hb.w, acc3);
    }
    rawsh[eo][0 * 4 + g] = acc0;
    rawsh[eo][1 * 4 + g] = acc1;
    rawsh[eo][2 * 4 + g] = acc2;
    rawsh[eo][3 * 4 + g] = acc3;
    __syncthreads();
    // pointwise + publish (only vm op before the poll)
    {
      float iraw = rawsh[oe][ob * 4 + 0];
      float fraw = rawsh[oe][ob * 4 + 1];
      float zraw = rawsh[oe][ob * 4 + 2];
      float oraw = rawsh[oe][ob * 4 + 3];
      float ls = -log1pf(expf(-fabsf(fraw)));
      if (fraw < 0.f) ls += fraw;                 // log_sigmoid(fraw)
      float lfm = m_ + ls;
      float mnew = fmaxf(iraw, lfm);
      float iv = expf(iraw - mnew);
      float fv = expf(lfm - mnew);
      c_ = fv * c_ + iv * tanhf(zraw);
      n_ = fv * n_ + iv;
      m_ = mnew;
      hlast = c_ / n_ / (1.f + expf(-oraw));
      hsh[od][ob] = hlast;
      unsigned hw = ((unsigned)f2bf(hlast) << 16) | tagv;
      __hip_atomic_store(&hxc[ownoff], hw, __ATOMIC_RELAXED, __HIP_MEMORY_SCOPE_AGENT);
    }
    // batched poll: 3 loads in flight, single wait per iteration
    unsigned w0, w1, w2;
    for (;;) {
      unsigned v0 = __hip_atomic_load(&hxc[soff0], __ATOMIC_RELAXED, __HIP_MEMORY_SCOPE_AGENT);
      unsigned v1 = __hip_atomic_load(&hxc[soff1], __ATOMIC_RELAXED, __HIP_MEMORY_SCOPE_AGENT);
      unsigned v2 = __hip_atomic_load(&hxc[soff2], __ATOMIC_RELAXED, __HIP_MEMORY_SCOPE_AGENT);
      unsigned bad = (((v0 & 0xffffu) ^ tagv) | ((v1 & 0xffffu) ^ tagv) | ((v2 & 0xffffu) ^ tagv));
      if (bad == 0u) { w0 = v0; w1 = v1; w2 = v2; break; }
      __builtin_amdgcn_s_sleep(1);
    }
    *st0 = bf2f((unsigned short)(w0 >> 16));
    *st1 = bf2f((unsigned short)(w1 >> 16));
    *st2 = bf2f((unsigned short)(w2 >> 16));
    // deferred HBM traffic: y-store + next-step gx prefetch
    yp[(size_t)(t * 64 + ob) * H_ + od] = f2bf(hlast);
    if (t < TCH_ - 1) {
      const unsigned short* gn = gp + (size_t)(t + 1) * 262144;
      g0 = bf2f(gn[0]); g1 = bf2f(gn[4096]); g2 = bf2f(gn[8192]); g3 = bf2f(gn[12288]);
    }
    __syncthreads();
  }
  state[sbase] = hlast;
  state[65536 + sbase] = c_;
  state[2 * 65536 + sbase] = n_;
  state[3 * 65536 + sbase] = m_;
}

// ---------------- groupnorm + residual + post LN (bf16 in/out) ----------------
__global__ __launch_bounds__(256) void post_k(
    const unsigned short* __restrict__ y, const unsigned short* __restrict__ xp,
    const float* __restrict__ gnw, const float* __restrict__ lpw,
    unsigned short* __restrict__ outb) {
  const int r = blockIdx.x;            // r = b*512 + s
  const int b = r >> 9, s = r & 511;
  const int tid = threadIdx.x;
  const int lane = tid & 63, wave = tid >> 6;
  ushort4 yu = *(const ushort4*)(y + (size_t)(s * 64 + b) * H_ + tid * 4);
  float v[4] = {bf2f(yu.x), bf2f(yu.y), bf2f(yu.z), bf2f(yu.w)};
  float s1 = v[0] + v[1] + v[2] + v[3];
  float s2 = v[0] * v[0] + v[1] * v[1] + v[2] * v[2] + v[3] * v[3];
#pragma unroll
  for (int off = 32; off; off >>= 1) { s1 += __shfl_xor(s1, off); s2 += __shfl_xor(s2, off); }
  float mu = s1 * (1.f / HD_);
  float rstd = rsqrtf(s2 * (1.f / HD_) - mu * mu + 1e-5f);
  float4 g4 = *(const float4*)(gnw + tid * 4);
  ushort4 xu = *(const ushort4*)(xp + (size_t)r * H_ + tid * 4);
  float o[4];
  o[0] = fmaf((v[0] - mu) * rstd, g4.x, bf2f(xu.x));
  o[1] = fmaf((v[1] - mu) * rstd, g4.y, bf2f(xu.y));
  o[2] = fmaf((v[2] - mu) * rstd, g4.z, bf2f(xu.z));
  o[3] = fmaf((v[3] - mu) * rstd, g4.w, bf2f(xu.w));
  float t1 = o[0] + o[1] + o[2] + o[3];
  float t2 = o[0] * o[0] + o[1] * o[1] + o[2] * o[2] + o[3] * o[3];
#pragma unroll
  for (int off = 32; off; off >>= 1) { t1 += __shfl_xor(t1, off); t2 += __shfl_xor(t2, off); }
  __shared__ float a1[4], a2[4];
  if (lane == 0) { a1[wave] = t1; a2[wave] = t2; }
  __syncthreads();
  float T1 = a1[0] + a1[1] + a1[2] + a1[3];
  float T2 = a2[0] + a2[1] + a2[2] + a2[3];
  float MU = T1 * (1.f / H_);
  float RS = rsqrtf(T2 * (1.f / H_) - MU * MU + 1e-5f);
  float4 w4 = *(const float4*)(lpw + tid * 4);
  ushort4 res = {f2bf((o[0] - MU) * RS * w4.x), f2bf((o[1] - MU) * RS * w4.y),
                 f2bf((o[2] - MU) * RS * w4.z), f2bf((o[3] - MU) * RS * w4.w)};
  *(ushort4*)(outb + (size_t)r * H_ + tid * 4) = res;
}

// ---------------- logits + value heads (bf16 in, fp32 out) ----------------
__global__ __launch_bounds__(256) void heads_k(
    const unsigned short* __restrict__ hp, const unsigned short* __restrict__ hv,
    const float* __restrict__ Wact, const float* __restrict__ bact,
    const float* __restrict__ Wv, const float* __restrict__ bv,
    float* __restrict__ dout) {
  const int lane = threadIdx.x & 63, wave = threadIdx.x >> 6;
  const int r = blockIdx.x * 4 + wave;
  const unsigned short* hpr = hp + (size_t)r * HID_;
  const unsigned short* hvr = hv + (size_t)r * HID_;
  float acc[A_];
#pragma unroll
  for (int j = 0; j < A_; ++j) acc[j] = 0.f;
  float accv = 0.f;
  for (int i = 0; i < 16; ++i) {
    int k = i * 64 + lane;
    float hpv = bf2f(hpr[k]);
    float hvv = bf2f(hvr[k]);
#pragma unroll
    for (int j = 0; j < A_; ++j) acc[j] = fmaf(hpv, Wact[j * HID_ + k], acc[j]);
    accv = fmaf(hvv, Wv[k], accv);
  }
#pragma unroll
  for (int j = 0; j < A_; ++j)
#pragma unroll
    for (int off = 32; off; off >>= 1) acc[j] += __shfl_xor(acc[j], off);
#pragma unroll
  for (int off = 32; off; off >>= 1) accv += __shfl_xor(accv, off);
  if (lane == 0) {
#pragma unroll
    for (int j = 0; j < A_; ++j) dout[(size_t)r * A_ + j] = acc[j] + bact[j];
    dout[589824 + r] = accv + bv[0];
  }
}

// ---------------- launch ----------------
extern "C" void kernel_launch(void* const* d_in, const int* in_sizes, int n_in,
                              void* d_out, int out_size, void* d_ws, size_t ws_size,
                              hipStream_t stream) {
  const float* obs   = (const float*)d_in[0];
  const float* st    = (const float*)d_in[1];
  const float* W_in  = (const float*)d_in[2];
  const float* b_in  = (const float*)d_in[3];
  const float* ln1w  = (const float*)d_in[4];
  const float* wg    = (const float*)d_in[5];
  const float* R     = (const float*)d_in[6];
  const float* bgat  = (const float*)d_in[7];
  const float* gnw   = (const float*)d_in[8];
  const float* lpw   = (const float*)d_in[9];
  const float* W_hid = (const float*)d_in[10];
  const float* b_hid = (const float*)d_in[11];
  const float* W_pol = (const float*)d_in[12];
  const float* b_pol = (const float*)d_in[13];
  const float* W_val = (const float*)d_in[14];
  const float* b_val = (const float*)d_in[15];
  const float* W_act = (const float*)d_in[16];
  const float* b_act = (const float*)d_in[17];
  const float* W_v   = (const float*)d_in[18];
  const float* b_v   = (const float*)d_in[19];

  // Workspace layout:
  //  A [0,        67108864): xproj bf16  -> hh bf16
  //  B [67108864, 134217728): gx chunk bf16 (T=128) -> outb bf16 -> hv bf16
  //  C [134217728,201326592): y bf16 -> hp bf16
  //  ST[201326592,202375168): scan state fp32 (h,c,n,m) 4x64x1024
  //  RS[202375168,202899456): LN1 row stats
  //  RB[202899456,204996608): R packed bf16 pairs
  //  WG[204996608,207093760): w_gates bf16 [nh][g][e][k]
  //  HX[207093760,207618048): scan exchange words [2][64 grp][4 b][256 d] u32
  const size_t NEEDED = 207618048;
  if (ws_size < NEEDED) return;
  char* ws = (char*)d_ws;
  unsigned short* xproj = (unsigned short*)(ws + 0);
  unsigned short* gxc   = (unsigned short*)(ws + 67108864);
  unsigned short* ybuf  = (unsigned short*)(ws + 134217728);
  float* statebuf       = (float*)(ws + 201326592);
  float* rstat          = (float*)(ws + 202375168);
  unsigned* Rbb         = (unsigned*)(ws + 202899456);
  unsigned short* wgb   = (unsigned short*)(ws + 204996608);
  unsigned* hx          = (unsigned*)(ws + 207093760);   // DEVICE HBM (not d_out!)
  unsigned short* outb  = gxc;
  unsigned short* hh    = xproj;
  unsigned short* hp    = ybuf;
  unsigned short* hv    = gxc;
  float* dout = (float*)d_out;

  hipMemcpyAsync(statebuf, st, 4 * 65536 * sizeof(float), hipMemcpyDeviceToDevice, stream);
  rtrans_k<<<2048, 256, 0, stream>>>(R, Rbb);
  wgt_k<<<4096, 256, 0, stream>>>(wg, wgb);
  mgemm_k<0, 0, false, 0><<<dim3(256, 8), 256, 0, stream>>>(
      obs, W_in, b_in, nullptr, nullptr, xproj, 512, 512, 0);
  rowstats_k<<<32768, 256, 0, stream>>>(xproj, rstat);
  for (int c = 0; c < NCH_; ++c) {
    mgemm_k<2, 1, false, 1><<<dim3(64, 2, 16), 256, 0, stream>>>(
        xproj, wgb, nullptr, rstat, ln1w, gxc, 256, 1024, c);
    scan_k<<<256, 256, 0, stream>>>(gxc, Rbb, bgat, statebuf, ybuf, hx, c);
  }
  post_k<<<32768, 256, 0, stream>>>(ybuf, xproj, gnw, lpw, outb);
  mgemm_k<1, 0, true, 0><<<dim3(256, 8), 256, 0, stream>>>(
      outb, W_hid, b_hid, nullptr, nullptr, hh, 1024, 1024, 0);
  mgemm_k<1, 0, true, 0><<<dim3(256, 8), 256, 0, stream>>>(
      hh, W_pol, b_pol, nullptr, nullptr, hp, 1024, 1024, 0);
  mgemm_k<1, 0, true, 0><<<dim3(256, 8), 256, 0, stream>>>(
      hh, W_val, b_val, nullptr, nullptr, hv, 1024, 1024, 0);
  heads_k<<<8192, 256, 0, stream>>>(hp, hv, W_act, b_act, W_v, b_v, dout);
}

// Round 10
// 2231.530 us; speedup vs baseline: 14.0200x; 2.9966x over previous
//
#include <hip/hip_runtime.h>
#include <cstdint>
#include <cstddef>

#define B_ 64
#define S_ 512
#define IN_ 512
#define H_ 1024
#define NH_ 4
#define HD_ 256
#define A_ 18
#define HID_ 1024
#define TCH_ 128            // scan time-chunk
#define NCH_ (S_ / TCH_)    // 4 chunks

using short8 = __attribute__((ext_vector_type(8))) short;
using f32x4  = __attribute__((ext_vector_type(4))) float;
typedef __attribute__((ext_vector_type(2))) __bf16 bf16x2;

// ---------------- helpers ----------------
__device__ __forceinline__ unsigned short f2bf(float f) {
  union { float f; unsigned u; } c; c.f = f;
  unsigned r = c.u + 0x7FFFu + ((c.u >> 16) & 1u);  // RNE
  return (unsigned short)(r >> 16);
}
__device__ __forceinline__ float bf2f(unsigned short h) {
  union { unsigned u; float f; } c; c.u = ((unsigned)h) << 16;
  return c.f;
}
__device__ __forceinline__ unsigned pk2(float a, float b) {
  return (unsigned)f2bf(a) | ((unsigned)f2bf(b) << 16);
}
// packed-bf16 dual-MAC: acc += a.lo*b.lo + a.hi*b.hi
__device__ __forceinline__ float dot2(unsigned a, unsigned b, float c) {
#if __has_builtin(__builtin_amdgcn_fdot2_f32_bf16)
  return __builtin_amdgcn_fdot2_f32_bf16(__builtin_bit_cast(bf16x2, a),
                                         __builtin_bit_cast(bf16x2, b), c, false);
#else
  float al = __uint_as_float(a << 16), ah = __uint_as_float(a & 0xffff0000u);
  float bl = __uint_as_float(b << 16), bh = __uint_as_float(b & 0xffff0000u);
  return fmaf(ah, bh, fmaf(al, bl, c));
#endif
}

// ---------------- R transcode: fp32 [nh][d][g][e] -> packed bf16 pairs ----------------
// Rbb[((nh*4+g)*256+e)*128 + dp] = pack(R[2dp], R[2dp+1])   (registers part, dp<96)
// Rl[((j*4+nh)*1024 + col)*2 + p] = same value for dp = 96+2j+p  (LDS part, coalesced fill)
__global__ __launch_bounds__(256) void rtrans_k(const float* __restrict__ R,
                                                unsigned* __restrict__ Rbb,
                                                unsigned* __restrict__ Rl) {
  const int i = blockIdx.x * 256 + threadIdx.x;   // [0, 524288)
  const int dp = i & 127;
  const int e = (i >> 7) & 255;
  const int g = (i >> 15) & 3;
  const int nh = i >> 17;
  const float* rp = R + (((size_t)nh * 256 + 2 * dp) * 4 + g) * 256 + e;  // d-stride 1024
  unsigned lo = f2bf(rp[0]), hi = f2bf(rp[1024]);
  unsigned v = lo | (hi << 16);
  Rbb[i] = v;
  if (dp >= 96) {
    int j = (dp - 96) >> 1, p = (dp - 96) & 1;
    int col = g * 256 + e;
    Rl[((size_t)(j * 4 + nh) * 1024 + col) * 2 + p] = v;
  }
}

// ---------------- w_gates transcode: fp32 [g][nh][d][e] -> bf16 [nh][g][e][d] ----------------
__global__ __launch_bounds__(256) void wgt_k(const float* __restrict__ wg,
                                             unsigned short* __restrict__ wgb) {
  const int i = blockIdx.x * 256 + threadIdx.x;   // [0, 1048576)
  const int k = i & 255;
  const int e = (i >> 8) & 255;
  const int g = (i >> 16) & 3;
  const int nh = i >> 18;
  wgb[i] = f2bf(wg[(((size_t)(g * 4 + nh) * 256 + k) * 256) + e]);
}

// ---------------- row stats for LN1 fusion (xproj is bf16) ----------------
__global__ __launch_bounds__(256) void rowstats_k(const unsigned short* __restrict__ x,
                                                  float* __restrict__ rs) {
  const int r = blockIdx.x, tid = threadIdx.x;
  const int lane = tid & 63, wave = tid >> 6;
  ushort4 u = *(const ushort4*)(x + (size_t)r * H_ + tid * 4);
  float v0 = bf2f(u.x), v1 = bf2f(u.y), v2 = bf2f(u.z), v3 = bf2f(u.w);
  float s1 = v0 + v1 + v2 + v3;
  float s2 = v0 * v0 + v1 * v1 + v2 * v2 + v3 * v3;
#pragma unroll
  for (int off = 32; off; off >>= 1) { s1 += __shfl_xor(s1, off); s2 += __shfl_xor(s2, off); }
  __shared__ float a1[4], a2[4];
  if (lane == 0) { a1[wave] = s1; a2[wave] = s2; }
  __syncthreads();
  if (tid == 0) {
    float S1 = a1[0] + a1[1] + a1[2] + a1[3];
    float S2 = a2[0] + a2[1] + a2[2] + a2[3];
    float mu = S1 * (1.f / H_);
    float var = S2 * (1.f / H_) - mu * mu;
    rs[r * 2] = mu;
    rs[r * 2 + 1] = rsqrtf(var + 1e-5f);
  }
}

// ---------------- MFMA bf16 GEMM, 128x128 tile, BK=32, 4 waves of 64x64 ----------------
template <int AMODE, int BMODE, bool RELU, int OUTMODE>
__global__ __launch_bounds__(256) void mgemm_k(
    const void* __restrict__ Av, const void* __restrict__ Wv,
    const float* __restrict__ bias, const float* __restrict__ rs,
    const float* __restrict__ lnw, unsigned short* __restrict__ Cb,
    int K, int lda, int chunk) {
  __shared__ uint4 As4[4][128];
  __shared__ uint4 Bs4[4][128];
  const int tid = threadIdx.x;
  const int lane = tid & 63, wave = tid >> 6;
  const int wr = wave >> 1, wc = wave & 1;
  const int col0 = blockIdx.y * 128;
  int nh = 0, g = 0, aoff = 0, bb = 0;
  size_t wbase = 0;
  if constexpr (OUTMODE == 1) {
    int z = blockIdx.z; nh = z >> 2; g = z & 3;
    aoff = nh * HD_;
    bb = blockIdx.x;
    wbase = (size_t)(nh * 4 + g) * 256 * 256;
  }
  auto arow = [&](int mm) -> int {
    if constexpr (OUTMODE == 1) return bb * 512 + chunk * TCH_ + mm;
    else return (int)blockIdx.x * 128 + mm;
  };
  f32x4 acc[4][4];
#pragma unroll
  for (int m = 0; m < 4; ++m)
#pragma unroll
    for (int n = 0; n < 4; ++n) acc[m][n] = 0.f;

  const int sm = tid >> 1;   // staging row
  const int sh = tid & 1;    // k half (16 elems)

  for (int k0 = 0; k0 < K; k0 += 32) {
    {
      int rg = arow(sm);
      unsigned pk[8];
      if constexpr (AMODE == 0) {
        const float* ap = (const float*)Av + (size_t)rg * lda + k0 + sh * 16;
#pragma unroll
        for (int q = 0; q < 4; ++q) {
          float4 f = ((const float4*)ap)[q];
          pk[2 * q] = pk2(f.x, f.y); pk[2 * q + 1] = pk2(f.z, f.w);
        }
      } else if constexpr (AMODE == 1) {
        const uint4* ap = (const uint4*)((const unsigned short*)Av + (size_t)rg * lda + aoff + k0 + sh * 16);
        uint4 u0 = ap[0], u1 = ap[1];
        pk[0] = u0.x; pk[1] = u0.y; pk[2] = u0.z; pk[3] = u0.w;
        pk[4] = u1.x; pk[5] = u1.y; pk[6] = u1.z; pk[7] = u1.w;
      } else {
        const uint4* ap = (const uint4*)((const unsigned short*)Av + (size_t)rg * lda + aoff + k0 + sh * 16);
        uint4 u0 = ap[0], u1 = ap[1];
        unsigned w8[8] = {u0.x, u0.y, u0.z, u0.w, u1.x, u1.y, u1.z, u1.w};
        float mu = rs[rg * 2], rstd = rs[rg * 2 + 1];
        const float* lw = lnw + aoff + k0 + sh * 16;
#pragma unroll
        for (int q = 0; q < 8; ++q) {
          float lo = (bf2f((unsigned short)w8[q]) - mu) * rstd * lw[2 * q];
          float hi = (bf2f((unsigned short)(w8[q] >> 16)) - mu) * rstd * lw[2 * q + 1];
          pk[q] = pk2(lo, hi);
        }
      }
      As4[2 * sh][sm]     = uint4{pk[0], pk[1], pk[2], pk[3]};
      As4[2 * sh + 1][sm] = uint4{pk[4], pk[5], pk[6], pk[7]};
    }
    {
      unsigned pk[8];
      if constexpr (BMODE == 0) {
        const float* wp = (const float*)Wv + (size_t)(col0 + sm) * K + k0 + sh * 16;
#pragma unroll
        for (int q = 0; q < 4; ++q) {
          float4 f = ((const float4*)wp)[q];
          pk[2 * q] = pk2(f.x, f.y); pk[2 * q + 1] = pk2(f.z, f.w);
        }
      } else {
        const uint4* wp = (const uint4*)((const unsigned short*)Wv + wbase + (size_t)(col0 + sm) * 256 + k0 + sh * 16);
        uint4 u0 = wp[0], u1 = wp[1];
        pk[0] = u0.x; pk[1] = u0.y; pk[2] = u0.z; pk[3] = u0.w;
        pk[4] = u1.x; pk[5] = u1.y; pk[6] = u1.z; pk[7] = u1.w;
      }
      Bs4[2 * sh][sm]     = uint4{pk[0], pk[1], pk[2], pk[3]};
      Bs4[2 * sh + 1][sm] = uint4{pk[4], pk[5], pk[6], pk[7]};
    }
    __syncthreads();
    short8 af[4], bfv[4];
#pragma unroll
    for (int m = 0; m < 4; ++m)
      af[m] = *(const short8*)&As4[lane >> 4][wr * 64 + m * 16 + (lane & 15)];
#pragma unroll
    for (int n = 0; n < 4; ++n)
      bfv[n] = *(const short8*)&Bs4[lane >> 4][wc * 64 + n * 16 + (lane & 15)];
#pragma unroll
    for (int m = 0; m < 4; ++m)
#pragma unroll
      for (int n = 0; n < 4; ++n)
        acc[m][n] = __builtin_amdgcn_mfma_f32_16x16x32_bf16(af[m], bfv[n], acc[m][n], 0, 0, 0);
    __syncthreads();
  }
  if constexpr (OUTMODE == 0) {
#pragma unroll
    for (int n = 0; n < 4; ++n) {
      int c = col0 + wc * 64 + n * 16 + (lane & 15);
      float bc = bias ? bias[c] : 0.f;
#pragma unroll
      for (int m = 0; m < 4; ++m) {
        int r0 = arow(wr * 64 + m * 16 + ((lane >> 4) << 2));
#pragma unroll
        for (int i = 0; i < 4; ++i) {
          float v = acc[m][n][i] + bc;
          if constexpr (RELU) v = fmaxf(v, 0.f);
          Cb[(size_t)(r0 + i) * 1024 + c] = f2bf(v);
        }
      }
    }
  } else {
#pragma unroll
    for (int n = 0; n < 4; ++n) {
      int e = col0 + wc * 64 + n * 16 + (lane & 15);
#pragma unroll
      for (int m = 0; m < 4; ++m) {
        int sl0 = wr * 64 + m * 16 + ((lane >> 4) << 2);
#pragma unroll
        for (int i = 0; i < 4; ++i) {
          int sl = sl0 + i;
          size_t base = (size_t)(sl * 64 + bb) * 4096 + nh * 1024 + g * 256;
          Cb[base + e] = f2bf(acc[m][n][i]);
        }
      }
    }
  }
}

// ---------------- sLSTM scan: ZERO-EXCHANGE. 256 blocks = (nh, batch), 1024 thr ----------------
// Thread = one gate-column (g=tid>>8, e=tid&255) for ONE batch. Full h update closes
// in-block via LDS: no cross-block traffic at all (rounds 4-9's invariant ~7us/step
// exchange eliminated). Column R: d 0..191 in registers (96 packed bf16 pairs),
// d 192..255 in LDS (128KB Rlds). h kept as packed bf16 (512B, broadcast b128 reads).
__global__ __launch_bounds__(1024, 1) void scan_k(
    const unsigned short* __restrict__ gxc, const unsigned* __restrict__ Rbb,
    const unsigned* __restrict__ Rl, const float* __restrict__ bgates,
    float* __restrict__ state, unsigned short* __restrict__ y, int chunk) {
  const int tid = threadIdx.x;
  const int bid = blockIdx.x;
  const int nh = bid >> 6, b = bid & 63;
  __shared__ uint2 Rlds[16][1024];                 // 128KB: R d=192..255, [j][col]
  __shared__ float rawf[1024];                     // raw[g*256+e]
  __shared__ alignas(16) unsigned short hsu[256];  // h packed bf16

  // fill Rlds cooperatively (coalesced global reads, conflict-free LDS writes)
#pragma unroll
  for (int j = 0; j < 16; ++j) {
    const uint2* src = (const uint2*)Rl + (size_t)(j * 4 + nh) * 1024 + tid;
    Rlds[j][tid] = *src;
  }
  // register R: this column's d 0..191
  unsigned rcol[96];
  {
    const unsigned* rp = Rbb + ((size_t)nh * 1024 + tid) * 128;
#pragma unroll
    for (int i = 0; i < 96; ++i) rcol[i] = rp[i];
  }
  const float bg = bgates[(tid >> 8) * H_ + nh * HD_ + (tid & 255)];

  // state ownership: thread d = tid (<256) for this (nh, b)
  const size_t sbase = (size_t)b * H_ + nh * HD_ + tid;
  float c_ = 0.f, n_ = 0.f, m_ = 0.f, hlast = 0.f;
  if (tid < 256) {
    hlast = state[sbase];
    c_ = state[65536 + sbase];
    n_ = state[2 * 65536 + sbase];
    m_ = state[3 * 65536 + sbase];
    hsu[tid] = f2bf(hlast);
  }
  __syncthreads();

  // gx: ((t*64+b)*4+nh)*1024 + tid ; t-stride 262144
  const unsigned short* gp = gxc + ((size_t)b * 4 + nh) * 1024 + tid;
  unsigned short* yp = y + ((size_t)(chunk * TCH_) * 64 + b) * H_ + nh * HD_;

  unsigned short gcur = gp[0];

  for (int t = 0; t < TCH_; ++t) {
    float acc = bf2f(gcur) + bg;
    if (t < TCH_ - 1) gcur = gp[(size_t)(t + 1) * 262144];  // prefetch under matvec
    const uint4* h4 = (const uint4*)hsu;
    // register part: d 0..191 (24 x uniform b128 h reads, 96 dot2)
#pragma unroll
    for (int q = 0; q < 24; ++q) {
      uint4 hu = h4[q];
      acc = dot2(rcol[4 * q + 0], hu.x, acc);
      acc = dot2(rcol[4 * q + 1], hu.y, acc);
      acc = dot2(rcol[4 * q + 2], hu.z, acc);
      acc = dot2(rcol[4 * q + 3], hu.w, acc);
    }
    // LDS part: d 192..255 (8 x b128 h + 16 x b64 R, 32 dot2)
#pragma unroll
    for (int s = 0; s < 8; ++s) {
      uint4 hu = h4[24 + s];
      uint2 r0 = Rlds[2 * s][tid];
      uint2 r1 = Rlds[2 * s + 1][tid];
      acc = dot2(r0.x, hu.x, acc);
      acc = dot2(r0.y, hu.y, acc);
      acc = dot2(r1.x, hu.z, acc);
      acc = dot2(r1.y, hu.w, acc);
    }
    rawf[tid] = acc;
    __syncthreads();
    if (tid < 256) {   // pointwise for d = tid
      float iraw = rawf[tid];
      float fraw = rawf[256 + tid];
      float zraw = rawf[512 + tid];
      float oraw = rawf[768 + tid];
      float ls = -log1pf(expf(-fabsf(fraw)));
      if (fraw < 0.f) ls += fraw;                 // log_sigmoid(fraw)
      float lfm = m_ + ls;
      float mnew = fmaxf(iraw, lfm);
      float iv = expf(iraw - mnew);
      float fv = expf(lfm - mnew);
      c_ = fv * c_ + iv * tanhf(zraw);
      n_ = fv * n_ + iv;
      m_ = mnew;
      hlast = c_ / n_ / (1.f + expf(-oraw));
      unsigned short hb = f2bf(hlast);
      hsu[tid] = hb;
      yp[(size_t)t * 65536 + tid] = hb;           // y[s][b][h] bf16
    }
    __syncthreads();
  }
  if (tid < 256) {
    state[sbase] = hlast;
    state[65536 + sbase] = c_;
    state[2 * 65536 + sbase] = n_;
    state[3 * 65536 + sbase] = m_;
  }
}

// ---------------- groupnorm + residual + post LN (bf16 in/out) ----------------
__global__ __launch_bounds__(256) void post_k(
    const unsigned short* __restrict__ y, const unsigned short* __restrict__ xp,
    const float* __restrict__ gnw, const float* __restrict__ lpw,
    unsigned short* __restrict__ outb) {
  const int r = blockIdx.x;            // r = b*512 + s
  const int b = r >> 9, s = r & 511;
  const int tid = threadIdx.x;
  const int lane = tid & 63, wave = tid >> 6;
  ushort4 yu = *(const ushort4*)(y + (size_t)(s * 64 + b) * H_ + tid * 4);
  float v[4] = {bf2f(yu.x), bf2f(yu.y), bf2f(yu.z), bf2f(yu.w)};
  float s1 = v[0] + v[1] + v[2] + v[3];
  float s2 = v[0] * v[0] + v[1] * v[1] + v[2] * v[2] + v[3] * v[3];
#pragma unroll
  for (int off = 32; off; off >>= 1) { s1 += __shfl_xor(s1, off); s2 += __shfl_xor(s2, off); }
  float mu = s1 * (1.f / HD_);
  float rstd = rsqrtf(s2 * (1.f / HD_) - mu * mu + 1e-5f);
  float4 g4 = *(const float4*)(gnw + tid * 4);
  ushort4 xu = *(const ushort4*)(xp + (size_t)r * H_ + tid * 4);
  float o[4];
  o[0] = fmaf((v[0] - mu) * rstd, g4.x, bf2f(xu.x));
  o[1] = fmaf((v[1] - mu) * rstd, g4.y, bf2f(xu.y));
  o[2] = fmaf((v[2] - mu) * rstd, g4.z, bf2f(xu.z));
  o[3] = fmaf((v[3] - mu) * rstd, g4.w, bf2f(xu.w));
  float t1 = o[0] + o[1] + o[2] + o[3];
  float t2 = o[0] * o[0] + o[1] * o[1] + o[2] * o[2] + o[3] * o[3];
#pragma unroll
  for (int off = 32; off; off >>= 1) { t1 += __shfl_xor(t1, off); t2 += __shfl_xor(t2, off); }
  __shared__ float a1[4], a2[4];
  if (lane == 0) { a1[wave] = t1; a2[wave] = t2; }
  __syncthreads();
  float T1 = a1[0] + a1[1] + a1[2] + a1[3];
  float T2 = a2[0] + a2[1] + a2[2] + a2[3];
  float MU = T1 * (1.f / H_);
  float RS = rsqrtf(T2 * (1.f / H_) - MU * MU + 1e-5f);
  float4 w4 = *(const float4*)(lpw + tid * 4);
  ushort4 res = {f2bf((o[0] - MU) * RS * w4.x), f2bf((o[1] - MU) * RS * w4.y),
                 f2bf((o[2] - MU) * RS * w4.z), f2bf((o[3] - MU) * RS * w4.w)};
  *(ushort4*)(outb + (size_t)r * H_ + tid * 4) = res;
}

// ---------------- logits + value heads (bf16 in, fp32 out) ----------------
__global__ __launch_bounds__(256) void heads_k(
    const unsigned short* __restrict__ hp, const unsigned short* __restrict__ hv,
    const float* __restrict__ Wact, const float* __restrict__ bact,
    const float* __restrict__ Wv, const float* __restrict__ bv,
    float* __restrict__ dout) {
  const int lane = threadIdx.x & 63, wave = threadIdx.x >> 6;
  const int r = blockIdx.x * 4 + wave;
  const unsigned short* hpr = hp + (size_t)r * HID_;
  const unsigned short* hvr = hv + (size_t)r * HID_;
  float acc[A_];
#pragma unroll
  for (int j = 0; j < A_; ++j) acc[j] = 0.f;
  float accv = 0.f;
  for (int i = 0; i < 16; ++i) {
    int k = i * 64 + lane;
    float hpv = bf2f(hpr[k]);
    float hvv = bf2f(hvr[k]);
#pragma unroll
    for (int j = 0; j < A_; ++j) acc[j] = fmaf(hpv, Wact[j * HID_ + k], acc[j]);
    accv = fmaf(hvv, Wv[k], accv);
  }
#pragma unroll
  for (int j = 0; j < A_; ++j)
#pragma unroll
    for (int off = 32; off; off >>= 1) acc[j] += __shfl_xor(acc[j], off);
#pragma unroll
  for (int off = 32; off; off >>= 1) accv += __shfl_xor(accv, off);
  if (lane == 0) {
#pragma unroll
    for (int j = 0; j < A_; ++j) dout[(size_t)r * A_ + j] = acc[j] + bact[j];
    dout[589824 + r] = accv + bv[0];
  }
}

// ---------------- launch ----------------
extern "C" void kernel_launch(void* const* d_in, const int* in_sizes, int n_in,
                              void* d_out, int out_size, void* d_ws, size_t ws_size,
                              hipStream_t stream) {
  const float* obs   = (const float*)d_in[0];
  const float* st    = (const float*)d_in[1];
  const float* W_in  = (const float*)d_in[2];
  const float* b_in  = (const float*)d_in[3];
  const float* ln1w  = (const float*)d_in[4];
  const float* wg    = (const float*)d_in[5];
  const float* R     = (const float*)d_in[6];
  const float* bgat  = (const float*)d_in[7];
  const float* gnw   = (const float*)d_in[8];
  const float* lpw   = (const float*)d_in[9];
  const float* W_hid = (const float*)d_in[10];
  const float* b_hid = (const float*)d_in[11];
  const float* W_pol = (const float*)d_in[12];
  const float* b_pol = (const float*)d_in[13];
  const float* W_val = (const float*)d_in[14];
  const float* b_val = (const float*)d_in[15];
  const float* W_act = (const float*)d_in[16];
  const float* b_act = (const float*)d_in[17];
  const float* W_v   = (const float*)d_in[18];
  const float* b_v   = (const float*)d_in[19];

  // Workspace layout (NEEDED identical to round 9, which fit):
  //  A [0,        67108864): xproj bf16  -> hh bf16
  //  B [67108864, 134217728): gx chunk bf16 (T=128) -> outb bf16 -> hv bf16
  //  C [134217728,201326592): y bf16 -> hp bf16
  //  ST[201326592,202375168): scan state fp32 (h,c,n,m) 4x64x1024
  //  RS[202375168,202899456): LN1 row stats
  //  RB[202899456,204996608): R packed bf16 pairs (register part source)
  //  WG[204996608,207093760): w_gates bf16 [nh][g][e][k]
  //  RL[207093760,207618048): R LDS-part [16 j][4 nh][1024 col][2] packed bf16 pairs
  const size_t NEEDED = 207618048;
  if (ws_size < NEEDED) return;
  char* ws = (char*)d_ws;
  unsigned short* xproj = (unsigned short*)(ws + 0);
  unsigned short* gxc   = (unsigned short*)(ws + 67108864);
  unsigned short* ybuf  = (unsigned short*)(ws + 134217728);
  float* statebuf       = (float*)(ws + 201326592);
  float* rstat          = (float*)(ws + 202375168);
  unsigned* Rbb         = (unsigned*)(ws + 202899456);
  unsigned short* wgb   = (unsigned short*)(ws + 204996608);
  unsigned* Rl          = (unsigned*)(ws + 207093760);
  unsigned short* outb  = gxc;
  unsigned short* hh    = xproj;
  unsigned short* hp    = ybuf;
  unsigned short* hv    = gxc;
  float* dout = (float*)d_out;

  hipMemcpyAsync(statebuf, st, 4 * 65536 * sizeof(float), hipMemcpyDeviceToDevice, stream);
  rtrans_k<<<2048, 256, 0, stream>>>(R, Rbb, Rl);
  wgt_k<<<4096, 256, 0, stream>>>(wg, wgb);
  mgemm_k<0, 0, false, 0><<<dim3(256, 8), 256, 0, stream>>>(
      obs, W_in, b_in, nullptr, nullptr, xproj, 512, 512, 0);
  rowstats_k<<<32768, 256, 0, stream>>>(xproj, rstat);
  for (int c = 0; c < NCH_; ++c) {
    mgemm_k<2, 1, false, 1><<<dim3(64, 2, 16), 256, 0, stream>>>(
        xproj, wgb, nullptr, rstat, ln1w, gxc, 256, 1024, c);
    scan_k<<<256, 1024, 0, stream>>>(gxc, Rbb, Rl, bgat, statebuf, ybuf, c);
  }
  post_k<<<32768, 256, 0, stream>>>(ybuf, xproj, gnw, lpw, outb);
  mgemm_k<1, 0, true, 0><<<dim3(256, 8), 256, 0, stream>>>(
      outb, W_hid, b_hid, nullptr, nullptr, hh, 1024, 1024, 0);
  mgemm_k<1, 0, true, 0><<<dim3(256, 8), 256, 0, stream>>>(
      hh, W_pol, b_pol, nullptr, nullptr, hp, 1024, 1024, 0);
  mgemm_k<1, 0, true, 0><<<dim3(256, 8), 256, 0, stream>>>(
      hh, W_val, b_val, nullptr, nullptr, hv, 1024, 1024, 0);
  heads_k<<<8192, 256, 0, stream>>>(hp, hv, W_act, b_act, W_v, b_v, dout);
}

// Round 11
// 2177.796 us; speedup vs baseline: 14.3660x; 1.0247x over previous
//
#include <hip/hip_runtime.h>
#include <cstdint>
#include <cstddef>

#define B_ 64
#define S_ 512
#define IN_ 512
#define H_ 1024
#define NH_ 4
#define HD_ 256
#define A_ 18
#define HID_ 1024
#define TCH_ 128            // scan time-chunk
#define NCH_ (S_ / TCH_)    // 4 chunks

using short8 = __attribute__((ext_vector_type(8))) short;
using f32x4  = __attribute__((ext_vector_type(4))) float;

// ---------------- helpers ----------------
__device__ __forceinline__ unsigned short f2bf(float f) {
  union { float f; unsigned u; } c; c.f = f;
  unsigned r = c.u + 0x7FFFu + ((c.u >> 16) & 1u);  // RNE
  return (unsigned short)(r >> 16);
}
__device__ __forceinline__ float bf2f(unsigned short h) {
  union { unsigned u; float f; } c; c.u = ((unsigned)h) << 16;
  return c.f;
}
__device__ __forceinline__ unsigned pk2(float a, float b) {
  return (unsigned)f2bf(a) | ((unsigned)f2bf(b) << 16);
}
// packed-bf16 dual-MAC via the HW dot instruction (VOP3P). Round-10's
// __has_builtin guard likely fell back to a 6-op unpack+fma sequence
// (VALUBusy implied ~470 instr/step vs ~128 ideal) -- force the instruction.
__device__ __forceinline__ float dot2(unsigned a, unsigned b, float c) {
  float d;
  asm("v_dot2_f32_bf16 %0, %1, %2, %3" : "=v"(d) : "v"(a), "v"(b), "v"(c));
  return d;
}

// ---------------- R transcode: fp32 [nh][d][g][e] -> packed bf16 pairs ----------------
// Rbb[((nh*4+g)*256+e)*128 + dp] = pack(R[2dp], R[2dp+1])   (registers part, dp<96)
// Rl[((j*4+nh)*1024 + col)*2 + p] = same value for dp = 96+2j+p  (LDS part, coalesced fill)
__global__ __launch_bounds__(256) void rtrans_k(const float* __restrict__ R,
                                                unsigned* __restrict__ Rbb,
                                                unsigned* __restrict__ Rl) {
  const int i = blockIdx.x * 256 + threadIdx.x;   // [0, 524288)
  const int dp = i & 127;
  const int e = (i >> 7) & 255;
  const int g = (i >> 15) & 3;
  const int nh = i >> 17;
  const float* rp = R + (((size_t)nh * 256 + 2 * dp) * 4 + g) * 256 + e;  // d-stride 1024
  unsigned lo = f2bf(rp[0]), hi = f2bf(rp[1024]);
  unsigned v = lo | (hi << 16);
  Rbb[i] = v;
  if (dp >= 96) {
    int j = (dp - 96) >> 1, p = (dp - 96) & 1;
    int col = g * 256 + e;
    Rl[((size_t)(j * 4 + nh) * 1024 + col) * 2 + p] = v;
  }
}

// ---------------- w_gates transcode: fp32 [g][nh][d][e] -> bf16 [nh][g][e][d] ----------------
__global__ __launch_bounds__(256) void wgt_k(const float* __restrict__ wg,
                                             unsigned short* __restrict__ wgb) {
  const int i = blockIdx.x * 256 + threadIdx.x;   // [0, 1048576)
  const int k = i & 255;
  const int e = (i >> 8) & 255;
  const int g = (i >> 16) & 3;
  const int nh = i >> 18;
  wgb[i] = f2bf(wg[(((size_t)(g * 4 + nh) * 256 + k) * 256) + e]);
}

// ---------------- generic fp32 -> bf16 weight transcode (layout-preserving) ----------------
__global__ __launch_bounds__(256) void wbf_k(const float* __restrict__ src,
                                             unsigned short* __restrict__ dst, int n) {
  int i = blockIdx.x * 256 + threadIdx.x;
  if (i < n) dst[i] = f2bf(src[i]);
}

// ---------------- row stats for LN1 fusion (xproj is bf16) ----------------
__global__ __launch_bounds__(256) void rowstats_k(const unsigned short* __restrict__ x,
                                                  float* __restrict__ rs) {
  const int r = blockIdx.x, tid = threadIdx.x;
  const int lane = tid & 63, wave = tid >> 6;
  ushort4 u = *(const ushort4*)(x + (size_t)r * H_ + tid * 4);
  float v0 = bf2f(u.x), v1 = bf2f(u.y), v2 = bf2f(u.z), v3 = bf2f(u.w);
  float s1 = v0 + v1 + v2 + v3;
  float s2 = v0 * v0 + v1 * v1 + v2 * v2 + v3 * v3;
#pragma unroll
  for (int off = 32; off; off >>= 1) { s1 += __shfl_xor(s1, off); s2 += __shfl_xor(s2, off); }
  __shared__ float a1[4], a2[4];
  if (lane == 0) { a1[wave] = s1; a2[wave] = s2; }
  __syncthreads();
  if (tid == 0) {
    float S1 = a1[0] + a1[1] + a1[2] + a1[3];
    float S2 = a2[0] + a2[1] + a2[2] + a2[3];
    float mu = S1 * (1.f / H_);
    float var = S2 * (1.f / H_) - mu * mu;
    rs[r * 2] = mu;
    rs[r * 2 + 1] = rsqrtf(var + 1e-5f);
  }
}

// ---------------- MFMA bf16 GEMM, 128x128 tile, BK=32, 4 waves of 64x64 ----------------
// AMODE: 0 = A fp32 (cvt), 1 = A bf16, 2 = A bf16 + fused LN
// BMODE: 0 = W fp32 (N,K), 1 = W bf16 gate-layout [col][256], 2 = W bf16 (N,K) stride K
template <int AMODE, int BMODE, bool RELU, int OUTMODE>
__global__ __launch_bounds__(256) void mgemm_k(
    const void* __restrict__ Av, const void* __restrict__ Wv,
    const float* __restrict__ bias, const float* __restrict__ rs,
    const float* __restrict__ lnw, unsigned short* __restrict__ Cb,
    int K, int lda, int chunk) {
  __shared__ uint4 As4[4][128];
  __shared__ uint4 Bs4[4][128];
  const int tid = threadIdx.x;
  const int lane = tid & 63, wave = tid >> 6;
  const int wr = wave >> 1, wc = wave & 1;
  const int col0 = blockIdx.y * 128;
  int nh = 0, g = 0, aoff = 0, bb = 0;
  size_t wbase = 0;
  if constexpr (OUTMODE == 1) {
    int z = blockIdx.z; nh = z >> 2; g = z & 3;
    aoff = nh * HD_;
    bb = blockIdx.x;
    wbase = (size_t)(nh * 4 + g) * 256 * 256;
  }
  auto arow = [&](int mm) -> int {
    if constexpr (OUTMODE == 1) return bb * 512 + chunk * TCH_ + mm;
    else return (int)blockIdx.x * 128 + mm;
  };
  f32x4 acc[4][4];
#pragma unroll
  for (int m = 0; m < 4; ++m)
#pragma unroll
    for (int n = 0; n < 4; ++n) acc[m][n] = 0.f;

  const int sm = tid >> 1;   // staging row
  const int sh = tid & 1;    // k half (16 elems)

  for (int k0 = 0; k0 < K; k0 += 32) {
    {
      int rg = arow(sm);
      unsigned pk[8];
      if constexpr (AMODE == 0) {
        const float* ap = (const float*)Av + (size_t)rg * lda + k0 + sh * 16;
#pragma unroll
        for (int q = 0; q < 4; ++q) {
          float4 f = ((const float4*)ap)[q];
          pk[2 * q] = pk2(f.x, f.y); pk[2 * q + 1] = pk2(f.z, f.w);
        }
      } else if constexpr (AMODE == 1) {
        const uint4* ap = (const uint4*)((const unsigned short*)Av + (size_t)rg * lda + aoff + k0 + sh * 16);
        uint4 u0 = ap[0], u1 = ap[1];
        pk[0] = u0.x; pk[1] = u0.y; pk[2] = u0.z; pk[3] = u0.w;
        pk[4] = u1.x; pk[5] = u1.y; pk[6] = u1.z; pk[7] = u1.w;
      } else {
        const uint4* ap = (const uint4*)((const unsigned short*)Av + (size_t)rg * lda + aoff + k0 + sh * 16);
        uint4 u0 = ap[0], u1 = ap[1];
        unsigned w8[8] = {u0.x, u0.y, u0.z, u0.w, u1.x, u1.y, u1.z, u1.w};
        float mu = rs[rg * 2], rstd = rs[rg * 2 + 1];
        const float* lw = lnw + aoff + k0 + sh * 16;
#pragma unroll
        for (int q = 0; q < 8; ++q) {
          float lo = (bf2f((unsigned short)w8[q]) - mu) * rstd * lw[2 * q];
          float hi = (bf2f((unsigned short)(w8[q] >> 16)) - mu) * rstd * lw[2 * q + 1];
          pk[q] = pk2(lo, hi);
        }
      }
      As4[2 * sh][sm]     = uint4{pk[0], pk[1], pk[2], pk[3]};
      As4[2 * sh + 1][sm] = uint4{pk[4], pk[5], pk[6], pk[7]};
    }
    {
      unsigned pk[8];
      if constexpr (BMODE == 0) {
        const float* wp = (const float*)Wv + (size_t)(col0 + sm) * K + k0 + sh * 16;
#pragma unroll
        for (int q = 0; q < 4; ++q) {
          float4 f = ((const float4*)wp)[q];
          pk[2 * q] = pk2(f.x, f.y); pk[2 * q + 1] = pk2(f.z, f.w);
        }
      } else if constexpr (BMODE == 1) {
        const uint4* wp = (const uint4*)((const unsigned short*)Wv + wbase + (size_t)(col0 + sm) * 256 + k0 + sh * 16);
        uint4 u0 = wp[0], u1 = wp[1];
        pk[0] = u0.x; pk[1] = u0.y; pk[2] = u0.z; pk[3] = u0.w;
        pk[4] = u1.x; pk[5] = u1.y; pk[6] = u1.z; pk[7] = u1.w;
      } else {
        const uint4* wp = (const uint4*)((const unsigned short*)Wv + (size_t)(col0 + sm) * K + k0 + sh * 16);
        uint4 u0 = wp[0], u1 = wp[1];
        pk[0] = u0.x; pk[1] = u0.y; pk[2] = u0.z; pk[3] = u0.w;
        pk[4] = u1.x; pk[5] = u1.y; pk[6] = u1.z; pk[7] = u1.w;
      }
      Bs4[2 * sh][sm]     = uint4{pk[0], pk[1], pk[2], pk[3]};
      Bs4[2 * sh + 1][sm] = uint4{pk[4], pk[5], pk[6], pk[7]};
    }
    __syncthreads();
    short8 af[4], bfv[4];
#pragma unroll
    for (int m = 0; m < 4; ++m)
      af[m] = *(const short8*)&As4[lane >> 4][wr * 64 + m * 16 + (lane & 15)];
#pragma unroll
    for (int n = 0; n < 4; ++n)
      bfv[n] = *(const short8*)&Bs4[lane >> 4][wc * 64 + n * 16 + (lane & 15)];
#pragma unroll
    for (int m = 0; m < 4; ++m)
#pragma unroll
      for (int n = 0; n < 4; ++n)
        acc[m][n] = __builtin_amdgcn_mfma_f32_16x16x32_bf16(af[m], bfv[n], acc[m][n], 0, 0, 0);
    __syncthreads();
  }
  if constexpr (OUTMODE == 0) {
#pragma unroll
    for (int n = 0; n < 4; ++n) {
      int c = col0 + wc * 64 + n * 16 + (lane & 15);
      float bc = bias ? bias[c] : 0.f;
#pragma unroll
      for (int m = 0; m < 4; ++m) {
        int r0 = arow(wr * 64 + m * 16 + ((lane >> 4) << 2));
#pragma unroll
        for (int i = 0; i < 4; ++i) {
          float v = acc[m][n][i] + bc;
          if constexpr (RELU) v = fmaxf(v, 0.f);
          Cb[(size_t)(r0 + i) * 1024 + c] = f2bf(v);
        }
      }
    }
  } else {
#pragma unroll
    for (int n = 0; n < 4; ++n) {
      int e = col0 + wc * 64 + n * 16 + (lane & 15);
#pragma unroll
      for (int m = 0; m < 4; ++m) {
        int sl0 = wr * 64 + m * 16 + ((lane >> 4) << 2);
#pragma unroll
        for (int i = 0; i < 4; ++i) {
          int sl = sl0 + i;
          size_t base = (size_t)(sl * 64 + bb) * 4096 + nh * 1024 + g * 256;
          Cb[base + e] = f2bf(acc[m][n][i]);
        }
      }
    }
  }
}

// ---------------- sLSTM scan: ZERO-EXCHANGE. 256 blocks = (nh, batch), 1024 thr ----------------
// Thread = one gate-column (g=tid>>8, e=tid&255) for ONE batch; full h update closes
// in-block. R: d 0..191 in regs (96 packed), d 192..255 in LDS. Round-11: HW dot2 asm;
// gate-parallel transcendentals (g=1/2/3 waves transform their raw pre-barrier --
// wave-uniform branch, no divergence, no extra barrier).
__global__ __launch_bounds__(1024, 1) void scan_k(
    const unsigned short* __restrict__ gxc, const unsigned* __restrict__ Rbb,
    const unsigned* __restrict__ Rl, const float* __restrict__ bgates,
    float* __restrict__ state, unsigned short* __restrict__ y, int chunk) {
  const int tid = threadIdx.x;
  const int bid = blockIdx.x;
  const int nh = bid >> 6, b = bid & 63;
  const int g = tid >> 8;
  __shared__ uint2 Rlds[16][1024];                 // 128KB: R d=192..255, [j][col]
  __shared__ float rawf[1024];                     // transformed raw[g*256+e]
  __shared__ alignas(16) unsigned short hsu[256];  // h packed bf16

#pragma unroll
  for (int j = 0; j < 16; ++j) {
    const uint2* src = (const uint2*)Rl + (size_t)(j * 4 + nh) * 1024 + tid;
    Rlds[j][tid] = *src;
  }
  unsigned rcol[96];
  {
    const unsigned* rp = Rbb + ((size_t)nh * 1024 + tid) * 128;
#pragma unroll
    for (int i = 0; i < 96; ++i) rcol[i] = rp[i];
  }
  const float bg = bgates[g * H_ + nh * HD_ + (tid & 255)];

  const size_t sbase = (size_t)b * H_ + nh * HD_ + tid;
  float c_ = 0.f, n_ = 0.f, m_ = 0.f, hlast = 0.f;
  if (tid < 256) {
    hlast = state[sbase];
    c_ = state[65536 + sbase];
    n_ = state[2 * 65536 + sbase];
    m_ = state[3 * 65536 + sbase];
    hsu[tid] = f2bf(hlast);
  }
  __syncthreads();

  const unsigned short* gp = gxc + ((size_t)b * 4 + nh) * 1024 + tid;
  unsigned short* yp = y + ((size_t)(chunk * TCH_) * 64 + b) * H_ + nh * HD_;

  unsigned short gcur = gp[0];

  for (int t = 0; t < TCH_; ++t) {
    float acc = bf2f(gcur) + bg;
    if (t < TCH_ - 1) gcur = gp[(size_t)(t + 1) * 262144];  // prefetch under matvec
    const uint4* h4 = (const uint4*)hsu;
#pragma unroll
    for (int q = 0; q < 24; ++q) {
      uint4 hu = h4[q];
      acc = dot2(rcol[4 * q + 0], hu.x, acc);
      acc = dot2(rcol[4 * q + 1], hu.y, acc);
      acc = dot2(rcol[4 * q + 2], hu.z, acc);
      acc = dot2(rcol[4 * q + 3], hu.w, acc);
    }
#pragma unroll
    for (int s = 0; s < 8; ++s) {
      uint4 hu = h4[24 + s];
      uint2 r0 = Rlds[2 * s][tid];
      uint2 r1 = Rlds[2 * s + 1][tid];
      acc = dot2(r0.x, hu.x, acc);
      acc = dot2(r0.y, hu.y, acc);
      acc = dot2(r1.x, hu.z, acc);
      acc = dot2(r1.y, hu.w, acc);
    }
    // gate-local transform (branch is wave-uniform: g constant per wave)
    float val;
    if (g == 0) {
      val = acc;                                   // iraw
    } else if (g == 1) {
      float ls = -log1pf(expf(-fabsf(acc)));       // log_sigmoid(fraw)
      if (acc < 0.f) ls += acc;
      val = ls;
    } else if (g == 2) {
      val = tanhf(acc);                            // tanh(zraw)
    } else {
      val = 1.f / (1.f + expf(-acc));              // sigmoid(oraw)
    }
    rawf[tid] = val;
    __syncthreads();
    if (tid < 256) {   // owner: only 2 exp + mul/div left
      float iraw = rawf[tid];
      float ls   = rawf[256 + tid];
      float tz   = rawf[512 + tid];
      float sg   = rawf[768 + tid];
      float lfm = m_ + ls;
      float mnew = fmaxf(iraw, lfm);
      float iv = expf(iraw - mnew);
      float fv = expf(lfm - mnew);
      c_ = fv * c_ + iv * tz;
      n_ = fv * n_ + iv;
      m_ = mnew;
      hlast = sg * c_ / n_;
      unsigned short hb = f2bf(hlast);
      hsu[tid] = hb;
      yp[(size_t)t * 65536 + tid] = hb;            // y[s][b][h] bf16
    }
    __syncthreads();
  }
  if (tid < 256) {
    state[sbase] = hlast;
    state[65536 + sbase] = c_;
    state[2 * 65536 + sbase] = n_;
    state[3 * 65536 + sbase] = m_;
  }
}

// ---------------- groupnorm + residual + post LN (bf16 in/out) ----------------
__global__ __launch_bounds__(256) void post_k(
    const unsigned short* __restrict__ y, const unsigned short* __restrict__ xp,
    const float* __restrict__ gnw, const float* __restrict__ lpw,
    unsigned short* __restrict__ outb) {
  const int r = blockIdx.x;            // r = b*512 + s
  const int b = r >> 9, s = r & 511;
  const int tid = threadIdx.x;
  const int lane = tid & 63, wave = tid >> 6;
  ushort4 yu = *(const ushort4*)(y + (size_t)(s * 64 + b) * H_ + tid * 4);
  float v[4] = {bf2f(yu.x), bf2f(yu.y), bf2f(yu.z), bf2f(yu.w)};
  float s1 = v[0] + v[1] + v[2] + v[3];
  float s2 = v[0] * v[0] + v[1] * v[1] + v[2] * v[2] + v[3] * v[3];
#pragma unroll
  for (int off = 32; off; off >>= 1) { s1 += __shfl_xor(s1, off); s2 += __shfl_xor(s2, off); }
  float mu = s1 * (1.f / HD_);
  float rstd = rsqrtf(s2 * (1.f / HD_) - mu * mu + 1e-5f);
  float4 g4 = *(const float4*)(gnw + tid * 4);
  ushort4 xu = *(const ushort4*)(xp + (size_t)r * H_ + tid * 4);
  float o[4];
  o[0] = fmaf((v[0] - mu) * rstd, g4.x, bf2f(xu.x));
  o[1] = fmaf((v[1] - mu) * rstd, g4.y, bf2f(xu.y));
  o[2] = fmaf((v[2] - mu) * rstd, g4.z, bf2f(xu.z));
  o[3] = fmaf((v[3] - mu) * rstd, g4.w, bf2f(xu.w));
  float t1 = o[0] + o[1] + o[2] + o[3];
  float t2 = o[0] * o[0] + o[1] * o[1] + o[2] * o[2] + o[3] * o[3];
#pragma unroll
  for (int off = 32; off; off >>= 1) { t1 += __shfl_xor(t1, off); t2 += __shfl_xor(t2, off); }
  __shared__ float a1[4], a2[4];
  if (lane == 0) { a1[wave] = t1; a2[wave] = t2; }
  __syncthreads();
  float T1 = a1[0] + a1[1] + a1[2] + a1[3];
  float T2 = a2[0] + a2[1] + a2[2] + a2[3];
  float MU = T1 * (1.f / H_);
  float RS = rsqrtf(T2 * (1.f / H_) - MU * MU + 1e-5f);
  float4 w4 = *(const float4*)(lpw + tid * 4);
  ushort4 res = {f2bf((o[0] - MU) * RS * w4.x), f2bf((o[1] - MU) * RS * w4.y),
                 f2bf((o[2] - MU) * RS * w4.z), f2bf((o[3] - MU) * RS * w4.w)};
  *(ushort4*)(outb + (size_t)r * H_ + tid * 4) = res;
}

// ---------------- logits + value heads (bf16 in, fp32 out) ----------------
__global__ __launch_bounds__(256) void heads_k(
    const unsigned short* __restrict__ hp, const unsigned short* __restrict__ hv,
    const float* __restrict__ Wact, const float* __restrict__ bact,
    const float* __restrict__ Wv, const float* __restrict__ bv,
    float* __restrict__ dout) {
  const int lane = threadIdx.x & 63, wave = threadIdx.x >> 6;
  const int r = blockIdx.x * 4 + wave;
  const unsigned short* hpr = hp + (size_t)r * HID_;
  const unsigned short* hvr = hv + (size_t)r * HID_;
  float acc[A_];
#pragma unroll
  for (int j = 0; j < A_; ++j) acc[j] = 0.f;
  float accv = 0.f;
  for (int i = 0; i < 16; ++i) {
    int k = i * 64 + lane;
    float hpv = bf2f(hpr[k]);
    float hvv = bf2f(hvr[k]);
#pragma unroll
    for (int j = 0; j < A_; ++j) acc[j] = fmaf(hpv, Wact[j * HID_ + k], acc[j]);
    accv = fmaf(hvv, Wv[k], accv);
  }
#pragma unroll
  for (int j = 0; j < A_; ++j)
#pragma unroll
    for (int off = 32; off; off >>= 1) acc[j] += __shfl_xor(acc[j], off);
#pragma unroll
  for (int off = 32; off; off >>= 1) accv += __shfl_xor(accv, off);
  if (lane == 0) {
#pragma unroll
    for (int j = 0; j < A_; ++j) dout[(size_t)r * A_ + j] = acc[j] + bact[j];
    dout[589824 + r] = accv + bv[0];
  }
}

// ---------------- launch ----------------
extern "C" void kernel_launch(void* const* d_in, const int* in_sizes, int n_in,
                              void* d_out, int out_size, void* d_ws, size_t ws_size,
                              hipStream_t stream) {
  const float* obs   = (const float*)d_in[0];
  const float* st    = (const float*)d_in[1];
  const float* W_in  = (const float*)d_in[2];
  const float* b_in  = (const float*)d_in[3];
  const float* ln1w  = (const float*)d_in[4];
  const float* wg    = (const float*)d_in[5];
  const float* R     = (const float*)d_in[6];
  const float* bgat  = (const float*)d_in[7];
  const float* gnw   = (const float*)d_in[8];
  const float* lpw   = (const float*)d_in[9];
  const float* W_hid = (const float*)d_in[10];
  const float* b_hid = (const float*)d_in[11];
  const float* W_pol = (const float*)d_in[12];
  const float* b_pol = (const float*)d_in[13];
  const float* W_val = (const float*)d_in[14];
  const float* b_val = (const float*)d_in[15];
  const float* W_act = (const float*)d_in[16];
  const float* b_act = (const float*)d_in[17];
  const float* W_v   = (const float*)d_in[18];
  const float* b_v   = (const float*)d_in[19];

  // Workspace layout:
  //  A [0,        67108864): xproj bf16  -> hh bf16
  //  B [67108864, 134217728): gx chunk bf16 (T=128) -> outb bf16 -> hv bf16
  //  C [134217728,201326592): y bf16 -> hp bf16
  //  ST[201326592,202375168): scan state fp32 (h,c,n,m) 4x64x1024
  //  RS[202375168,202899456): LN1 row stats
  //  RB[202899456,204996608): R packed bf16 pairs (register part source)
  //  WG[204996608,207093760): w_gates bf16 [nh][g][e][k]
  //  RL[207093760,207618048): R LDS-part
  //  WI[207618048,208666624): W_in  bf16
  //  WH[208666624,210763776): W_hid bf16
  //  WP[210763776,212860928): W_pol bf16
  //  WV[212860928,214958080): W_val bf16
  const size_t NEEDED = 214958080;
  if (ws_size < NEEDED) return;
  char* ws = (char*)d_ws;
  unsigned short* xproj = (unsigned short*)(ws + 0);
  unsigned short* gxc   = (unsigned short*)(ws + 67108864);
  unsigned short* ybuf  = (unsigned short*)(ws + 134217728);
  float* statebuf       = (float*)(ws + 201326592);
  float* rstat          = (float*)(ws + 202375168);
  unsigned* Rbb         = (unsigned*)(ws + 202899456);
  unsigned short* wgb   = (unsigned short*)(ws + 204996608);
  unsigned* Rl          = (unsigned*)(ws + 207093760);
  unsigned short* wib   = (unsigned short*)(ws + 207618048);
  unsigned short* whb   = (unsigned short*)(ws + 208666624);
  unsigned short* wpb   = (unsigned short*)(ws + 210763776);
  unsigned short* wvb   = (unsigned short*)(ws + 212860928);
  unsigned short* outb  = gxc;
  unsigned short* hh    = xproj;
  unsigned short* hp    = ybuf;
  unsigned short* hv    = gxc;
  float* dout = (float*)d_out;

  hipMemcpyAsync(statebuf, st, 4 * 65536 * sizeof(float), hipMemcpyDeviceToDevice, stream);
  rtrans_k<<<2048, 256, 0, stream>>>(R, Rbb, Rl);
  wgt_k<<<4096, 256, 0, stream>>>(wg, wgb);
  wbf_k<<<2048, 256, 0, stream>>>(W_in, wib, 524288);
  wbf_k<<<4096, 256, 0, stream>>>(W_hid, whb, 1048576);
  wbf_k<<<4096, 256, 0, stream>>>(W_pol, wpb, 1048576);
  wbf_k<<<4096, 256, 0, stream>>>(W_val, wvb, 1048576);
  mgemm_k<0, 2, false, 0><<<dim3(256, 8), 256, 0, stream>>>(
      obs, wib, b_in, nullptr, nullptr, xproj, 512, 512, 0);
  rowstats_k<<<32768, 256, 0, stream>>>(xproj, rstat);
  for (int c = 0; c < NCH_; ++c) {
    mgemm_k<2, 1, false, 1><<<dim3(64, 2, 16), 256, 0, stream>>>(
        xproj, wgb, nullptr, rstat, ln1w, gxc, 256, 1024, c);
    scan_k<<<256, 1024, 0, stream>>>(gxc, Rbb, Rl, bgat, statebuf, ybuf, c);
  }
  post_k<<<32768, 256, 0, stream>>>(ybuf, xproj, gnw, lpw, outb);
  mgemm_k<1, 2, true, 0><<<dim3(256, 8), 256, 0, stream>>>(
      outb, whb, b_hid, nullptr, nullptr, hh, 1024, 1024, 0);
  mgemm_k<1, 2, true, 0><<<dim3(256, 8), 256, 0, stream>>>(
      hh, wpb, b_pol, nullptr, nullptr, hp, 1024, 1024, 0);
  mgemm_k<1, 2, true, 0><<<dim3(256, 8), 256, 0, stream>>>(
      hh, wvb, b_val, nullptr, nullptr, hv, 1024, 1024, 0);
  heads_k<<<8192, 256, 0, stream>>>(hp, hv, W_act, b_act, W_v, b_v, dout);
}

// Round 12
// 2067.467 us; speedup vs baseline: 15.1326x; 1.0534x over previous
//
#include <hip/hip_runtime.h>
#include <cstdint>
#include <cstddef>

#define B_ 64
#define S_ 512
#define IN_ 512
#define H_ 1024
#define NH_ 4
#define HD_ 256
#define A_ 18
#define HID_ 1024
#define TCH_ 128            // scan time-chunk
#define NCH_ (S_ / TCH_)    // 4 chunks

using short8 = __attribute__((ext_vector_type(8))) short;
using f32x4  = __attribute__((ext_vector_type(4))) float;

// ---------------- helpers ----------------
__device__ __forceinline__ unsigned short f2bf(float f) {
  union { float f; unsigned u; } c; c.f = f;
  unsigned r = c.u + 0x7FFFu + ((c.u >> 16) & 1u);  // RNE
  return (unsigned short)(r >> 16);
}
__device__ __forceinline__ float bf2f(unsigned short h) {
  union { unsigned u; float f; } c; c.u = ((unsigned)h) << 16;
  return c.f;
}
__device__ __forceinline__ unsigned pk2(float a, float b) {
  return (unsigned)f2bf(a) | ((unsigned)f2bf(b) << 16);
}
// packed-bf16 dual-MAC (VOP3P HW dot). "v" constraints also force operands
// into arch VGPRs (defeats AGPR parking of the R columns).
__device__ __forceinline__ float dot2(unsigned a, unsigned b, float c) {
  float d;
  asm("v_dot2_f32_bf16 %0, %1, %2, %3" : "=v"(d) : "v"(a), "v"(b), "v"(c));
  return d;
}

// ---------------- R transcode: fp32 [nh][d][g][e] -> packed bf16 pairs ----------------
// Rbb[((nh*4+g)*256+e)*128 + dp] = pack(R[2dp], R[2dp+1])   (registers part, dp<96)
// Rl[((j*4+nh)*1024 + col)*2 + p] = same value for dp = 96+2j+p  (LDS part, coalesced fill)
__global__ __launch_bounds__(256) void rtrans_k(const float* __restrict__ R,
                                                unsigned* __restrict__ Rbb,
                                                unsigned* __restrict__ Rl) {
  const int i = blockIdx.x * 256 + threadIdx.x;   // [0, 524288)
  const int dp = i & 127;
  const int e = (i >> 7) & 255;
  const int g = (i >> 15) & 3;
  const int nh = i >> 17;
  const float* rp = R + (((size_t)nh * 256 + 2 * dp) * 4 + g) * 256 + e;  // d-stride 1024
  unsigned lo = f2bf(rp[0]), hi = f2bf(rp[1024]);
  unsigned v = lo | (hi << 16);
  Rbb[i] = v;
  if (dp >= 96) {
    int j = (dp - 96) >> 1, p = (dp - 96) & 1;
    int col = g * 256 + e;
    Rl[((size_t)(j * 4 + nh) * 1024 + col) * 2 + p] = v;
  }
}

// ---------------- w_gates transcode: fp32 [g][nh][d][e] -> bf16 [nh][g][e][d] ----------------
__global__ __launch_bounds__(256) void wgt_k(const float* __restrict__ wg,
                                             unsigned short* __restrict__ wgb) {
  const int i = blockIdx.x * 256 + threadIdx.x;   // [0, 1048576)
  const int k = i & 255;
  const int e = (i >> 8) & 255;
  const int g = (i >> 16) & 3;
  const int nh = i >> 18;
  wgb[i] = f2bf(wg[(((size_t)(g * 4 + nh) * 256 + k) * 256) + e]);
}

// ---------------- generic fp32 -> bf16 weight transcode (layout-preserving) ----------------
__global__ __launch_bounds__(256) void wbf_k(const float* __restrict__ src,
                                             unsigned short* __restrict__ dst, int n) {
  int i = blockIdx.x * 256 + threadIdx.x;
  if (i < n) dst[i] = f2bf(src[i]);
}

// ---------------- row stats for LN1 fusion (xproj is bf16) ----------------
__global__ __launch_bounds__(256) void rowstats_k(const unsigned short* __restrict__ x,
                                                  float* __restrict__ rs) {
  const int r = blockIdx.x, tid = threadIdx.x;
  const int lane = tid & 63, wave = tid >> 6;
  ushort4 u = *(const ushort4*)(x + (size_t)r * H_ + tid * 4);
  float v0 = bf2f(u.x), v1 = bf2f(u.y), v2 = bf2f(u.z), v3 = bf2f(u.w);
  float s1 = v0 + v1 + v2 + v3;
  float s2 = v0 * v0 + v1 * v1 + v2 * v2 + v3 * v3;
#pragma unroll
  for (int off = 32; off; off >>= 1) { s1 += __shfl_xor(s1, off); s2 += __shfl_xor(s2, off); }
  __shared__ float a1[4], a2[4];
  if (lane == 0) { a1[wave] = s1; a2[wave] = s2; }
  __syncthreads();
  if (tid == 0) {
    float S1 = a1[0] + a1[1] + a1[2] + a1[3];
    float S2 = a2[0] + a2[1] + a2[2] + a2[3];
    float mu = S1 * (1.f / H_);
    float var = S2 * (1.f / H_) - mu * mu;
    rs[r * 2] = mu;
    rs[r * 2 + 1] = rsqrtf(var + 1e-5f);
  }
}

// ---------------- MFMA bf16 GEMM, 128x128 tile, BK=32, 4 waves of 64x64 ----------------
// AMODE: 0 = A fp32 (cvt), 1 = A bf16, 2 = A bf16 + fused LN
// BMODE: 0 = W fp32 (N,K), 1 = W bf16 gate-layout [col][256], 2 = W bf16 (N,K) stride K
template <int AMODE, int BMODE, bool RELU, int OUTMODE>
__global__ __launch_bounds__(256) void mgemm_k(
    const void* __restrict__ Av, const void* __restrict__ Wv,
    const float* __restrict__ bias, const float* __restrict__ rs,
    const float* __restrict__ lnw, unsigned short* __restrict__ Cb,
    int K, int lda, int chunk) {
  __shared__ uint4 As4[4][128];
  __shared__ uint4 Bs4[4][128];
  const int tid = threadIdx.x;
  const int lane = tid & 63, wave = tid >> 6;
  const int wr = wave >> 1, wc = wave & 1;
  const int col0 = blockIdx.y * 128;
  int nh = 0, g = 0, aoff = 0, bb = 0;
  size_t wbase = 0;
  if constexpr (OUTMODE == 1) {
    int z = blockIdx.z; nh = z >> 2; g = z & 3;
    aoff = nh * HD_;
    bb = blockIdx.x;
    wbase = (size_t)(nh * 4 + g) * 256 * 256;
  }
  auto arow = [&](int mm) -> int {
    if constexpr (OUTMODE == 1) return bb * 512 + chunk * TCH_ + mm;
    else return (int)blockIdx.x * 128 + mm;
  };
  f32x4 acc[4][4];
#pragma unroll
  for (int m = 0; m < 4; ++m)
#pragma unroll
    for (int n = 0; n < 4; ++n) acc[m][n] = 0.f;

  const int sm = tid >> 1;   // staging row
  const int sh = tid & 1;    // k half (16 elems)

  for (int k0 = 0; k0 < K; k0 += 32) {
    {
      int rg = arow(sm);
      unsigned pk[8];
      if constexpr (AMODE == 0) {
        const float* ap = (const float*)Av + (size_t)rg * lda + k0 + sh * 16;
#pragma unroll
        for (int q = 0; q < 4; ++q) {
          float4 f = ((const float4*)ap)[q];
          pk[2 * q] = pk2(f.x, f.y); pk[2 * q + 1] = pk2(f.z, f.w);
        }
      } else if constexpr (AMODE == 1) {
        const uint4* ap = (const uint4*)((const unsigned short*)Av + (size_t)rg * lda + aoff + k0 + sh * 16);
        uint4 u0 = ap[0], u1 = ap[1];
        pk[0] = u0.x; pk[1] = u0.y; pk[2] = u0.z; pk[3] = u0.w;
        pk[4] = u1.x; pk[5] = u1.y; pk[6] = u1.z; pk[7] = u1.w;
      } else {
        const uint4* ap = (const uint4*)((const unsigned short*)Av + (size_t)rg * lda + aoff + k0 + sh * 16);
        uint4 u0 = ap[0], u1 = ap[1];
        unsigned w8[8] = {u0.x, u0.y, u0.z, u0.w, u1.x, u1.y, u1.z, u1.w};
        float mu = rs[rg * 2], rstd = rs[rg * 2 + 1];
        const float* lw = lnw + aoff + k0 + sh * 16;
#pragma unroll
        for (int q = 0; q < 8; ++q) {
          float lo = (bf2f((unsigned short)w8[q]) - mu) * rstd * lw[2 * q];
          float hi = (bf2f((unsigned short)(w8[q] >> 16)) - mu) * rstd * lw[2 * q + 1];
          pk[q] = pk2(lo, hi);
        }
      }
      As4[2 * sh][sm]     = uint4{pk[0], pk[1], pk[2], pk[3]};
      As4[2 * sh + 1][sm] = uint4{pk[4], pk[5], pk[6], pk[7]};
    }
    {
      unsigned pk[8];
      if constexpr (BMODE == 0) {
        const float* wp = (const float*)Wv + (size_t)(col0 + sm) * K + k0 + sh * 16;
#pragma unroll
        for (int q = 0; q < 4; ++q) {
          float4 f = ((const float4*)wp)[q];
          pk[2 * q] = pk2(f.x, f.y); pk[2 * q + 1] = pk2(f.z, f.w);
        }
      } else if constexpr (BMODE == 1) {
        const uint4* wp = (const uint4*)((const unsigned short*)Wv + wbase + (size_t)(col0 + sm) * 256 + k0 + sh * 16);
        uint4 u0 = wp[0], u1 = wp[1];
        pk[0] = u0.x; pk[1] = u0.y; pk[2] = u0.z; pk[3] = u0.w;
        pk[4] = u1.x; pk[5] = u1.y; pk[6] = u1.z; pk[7] = u1.w;
      } else {
        const uint4* wp = (const uint4*)((const unsigned short*)Wv + (size_t)(col0 + sm) * K + k0 + sh * 16);
        uint4 u0 = wp[0], u1 = wp[1];
        pk[0] = u0.x; pk[1] = u0.y; pk[2] = u0.z; pk[3] = u0.w;
        pk[4] = u1.x; pk[5] = u1.y; pk[6] = u1.z; pk[7] = u1.w;
      }
      Bs4[2 * sh][sm]     = uint4{pk[0], pk[1], pk[2], pk[3]};
      Bs4[2 * sh + 1][sm] = uint4{pk[4], pk[5], pk[6], pk[7]};
    }
    __syncthreads();
    short8 af[4], bfv[4];
#pragma unroll
    for (int m = 0; m < 4; ++m)
      af[m] = *(const short8*)&As4[lane >> 4][wr * 64 + m * 16 + (lane & 15)];
#pragma unroll
    for (int n = 0; n < 4; ++n)
      bfv[n] = *(const short8*)&Bs4[lane >> 4][wc * 64 + n * 16 + (lane & 15)];
#pragma unroll
    for (int m = 0; m < 4; ++m)
#pragma unroll
      for (int n = 0; n < 4; ++n)
        acc[m][n] = __builtin_amdgcn_mfma_f32_16x16x32_bf16(af[m], bfv[n], acc[m][n], 0, 0, 0);
    __syncthreads();
  }
  if constexpr (OUTMODE == 0) {
#pragma unroll
    for (int n = 0; n < 4; ++n) {
      int c = col0 + wc * 64 + n * 16 + (lane & 15);
      float bc = bias ? bias[c] : 0.f;
#pragma unroll
      for (int m = 0; m < 4; ++m) {
        int r0 = arow(wr * 64 + m * 16 + ((lane >> 4) << 2));
#pragma unroll
        for (int i = 0; i < 4; ++i) {
          float v = acc[m][n][i] + bc;
          if constexpr (RELU) v = fmaxf(v, 0.f);
          Cb[(size_t)(r0 + i) * 1024 + c] = f2bf(v);
        }
      }
    }
  } else {
#pragma unroll
    for (int n = 0; n < 4; ++n) {
      int e = col0 + wc * 64 + n * 16 + (lane & 15);
#pragma unroll
      for (int m = 0; m < 4; ++m) {
        int sl0 = wr * 64 + m * 16 + ((lane >> 4) << 2);
#pragma unroll
        for (int i = 0; i < 4; ++i) {
          int sl = sl0 + i;
          size_t base = (size_t)(sl * 64 + bb) * 4096 + nh * 1024 + g * 256;
          Cb[base + e] = f2bf(acc[m][n][i]);
        }
      }
    }
  }
}

// ---------------- sLSTM scan: zero-exchange, 512 thr x 2 columns/thread ----------------
// 256 blocks = (nh, batch). Thread owns cols tid and tid+512 (gates {0,2} or {1,3}).
// Round-12: halves LDS h-broadcast issues per CU (each b128 h read feeds 8 dot2) and
// 2 waves/SIMD with launch_bounds(512,2) gives a 256-VGPR budget so rcol (192 packed)
// stays in arch VGPRs (kills the accvgpr_read tax round 10/11 paid).
__global__ __launch_bounds__(512, 2) void scan_k(
    const unsigned short* __restrict__ gxc, const unsigned* __restrict__ Rbb,
    const unsigned* __restrict__ Rl, const float* __restrict__ bgates,
    float* __restrict__ state, unsigned short* __restrict__ y, int chunk) {
  const int tid = threadIdx.x;
  const int bid = blockIdx.x;
  const int nh = bid >> 6, b = bid & 63;
  const int col0 = tid, col1 = tid + 512;
  const int g0 = col0 >> 8, g1 = col1 >> 8;        // wave-uniform
  __shared__ uint2 Rlds[16][1024];                 // 128KB: R d=192..255, [j][col]
  __shared__ float rawf[1024];                     // transformed raw[g*256+e]
  __shared__ alignas(16) unsigned short hsu[256];  // h packed bf16

  // fill Rlds: 16384 uint2 by 512 threads = 32 iterations, coalesced
#pragma unroll
  for (int it = 0; it < 32; ++it) {
    int idx = it * 512 + tid;
    int j = idx >> 10, col = idx & 1023;
    Rlds[j][col] = ((const uint2*)Rl)[(size_t)(j * 4 + nh) * 1024 + col];
  }
  // register R for both columns: d 0..191 each (96 packed pairs per column)
  unsigned rc0[96], rc1[96];
  {
    const unsigned* rp0 = Rbb + ((size_t)nh * 1024 + col0) * 128;
    const unsigned* rp1 = Rbb + ((size_t)nh * 1024 + col1) * 128;
#pragma unroll
    for (int i = 0; i < 96; ++i) rc0[i] = rp0[i];
#pragma unroll
    for (int i = 0; i < 96; ++i) rc1[i] = rp1[i];
  }
  const float bg0 = bgates[g0 * H_ + nh * HD_ + (col0 & 255)];
  const float bg1 = bgates[g1 * H_ + nh * HD_ + (col1 & 255)];

  const size_t sbase = (size_t)b * H_ + nh * HD_ + tid;
  float c_ = 0.f, n_ = 0.f, m_ = 0.f, hlast = 0.f;
  if (tid < 256) {
    hlast = state[sbase];
    c_ = state[65536 + sbase];
    n_ = state[2 * 65536 + sbase];
    m_ = state[3 * 65536 + sbase];
    hsu[tid] = f2bf(hlast);
  }
  __syncthreads();

  const unsigned short* gp0 = gxc + ((size_t)b * 4 + nh) * 1024 + col0;
  const unsigned short* gp1 = gp0 + 512;
  unsigned short* yp = y + ((size_t)(chunk * TCH_) * 64 + b) * H_ + nh * HD_;

  unsigned short gc0 = gp0[0], gc1 = gp1[0];

  for (int t = 0; t < TCH_; ++t) {
    float acc0 = bf2f(gc0) + bg0;
    float acc1 = bf2f(gc1) + bg1;
    if (t < TCH_ - 1) {  // prefetch under matvec
      gc0 = gp0[(size_t)(t + 1) * 262144];
      gc1 = gp1[(size_t)(t + 1) * 262144];
    }
    const uint4* h4 = (const uint4*)hsu;
    // register part: d 0..191 — each h b128 read feeds 8 dot2 (2 cols x 4)
#pragma unroll
    for (int q = 0; q < 24; ++q) {
      uint4 hu = h4[q];
      acc0 = dot2(rc0[4 * q + 0], hu.x, acc0);
      acc1 = dot2(rc1[4 * q + 0], hu.x, acc1);
      acc0 = dot2(rc0[4 * q + 1], hu.y, acc0);
      acc1 = dot2(rc1[4 * q + 1], hu.y, acc1);
      acc0 = dot2(rc0[4 * q + 2], hu.z, acc0);
      acc1 = dot2(rc1[4 * q + 2], hu.z, acc1);
      acc0 = dot2(rc0[4 * q + 3], hu.w, acc0);
      acc1 = dot2(rc1[4 * q + 3], hu.w, acc1);
    }
    // LDS part: d 192..255
#pragma unroll
    for (int s = 0; s < 8; ++s) {
      uint4 hu = h4[24 + s];
      uint2 a0 = Rlds[2 * s][col0];
      uint2 a1 = Rlds[2 * s + 1][col0];
      uint2 b0 = Rlds[2 * s][col1];
      uint2 b1 = Rlds[2 * s + 1][col1];
      acc0 = dot2(a0.x, hu.x, acc0);
      acc1 = dot2(b0.x, hu.x, acc1);
      acc0 = dot2(a0.y, hu.y, acc0);
      acc1 = dot2(b0.y, hu.y, acc1);
      acc0 = dot2(a1.x, hu.z, acc0);
      acc1 = dot2(b1.x, hu.z, acc1);
      acc0 = dot2(a1.y, hu.w, acc0);
      acc1 = dot2(b1.y, hu.w, acc1);
    }
    // gate-local transforms (wave-uniform branches)
    float val0, val1;
    if (g0 == 0) {
      val0 = acc0;                                  // iraw
    } else {
      float ls = -log1pf(expf(-fabsf(acc0)));       // log_sigmoid(fraw)
      if (acc0 < 0.f) ls += acc0;
      val0 = ls;
    }
    if (g1 == 2) {
      val1 = tanhf(acc1);                           // tanh(zraw)
    } else {
      val1 = 1.f / (1.f + expf(-acc1));             // sigmoid(oraw)
    }
    rawf[col0] = val0;
    rawf[col1] = val1;
    __syncthreads();
    if (tid < 256) {   // owner: 2 exp + mul/div
      float iraw = rawf[tid];
      float ls   = rawf[256 + tid];
      float tz   = rawf[512 + tid];
      float sg   = rawf[768 + tid];
      float lfm = m_ + ls;
      float mnew = fmaxf(iraw, lfm);
      float iv = expf(iraw - mnew);
      float fv = expf(lfm - mnew);
      c_ = fv * c_ + iv * tz;
      n_ = fv * n_ + iv;
      m_ = mnew;
      hlast = sg * c_ / n_;
      unsigned short hb = f2bf(hlast);
      hsu[tid] = hb;
      yp[(size_t)t * 65536 + tid] = hb;            // y[s][b][h] bf16
    }
    __syncthreads();
  }
  if (tid < 256) {
    state[sbase] = hlast;
    state[65536 + sbase] = c_;
    state[2 * 65536 + sbase] = n_;
    state[3 * 65536 + sbase] = m_;
  }
}

// ---------------- groupnorm + residual + post LN (bf16 in/out) ----------------
__global__ __launch_bounds__(256) void post_k(
    const unsigned short* __restrict__ y, const unsigned short* __restrict__ xp,
    const float* __restrict__ gnw, const float* __restrict__ lpw,
    unsigned short* __restrict__ outb) {
  const int r = blockIdx.x;            // r = b*512 + s
  const int b = r >> 9, s = r & 511;
  const int tid = threadIdx.x;
  const int lane = tid & 63, wave = tid >> 6;
  ushort4 yu = *(const ushort4*)(y + (size_t)(s * 64 + b) * H_ + tid * 4);
  float v[4] = {bf2f(yu.x), bf2f(yu.y), bf2f(yu.z), bf2f(yu.w)};
  float s1 = v[0] + v[1] + v[2] + v[3];
  float s2 = v[0] * v[0] + v[1] * v[1] + v[2] * v[2] + v[3] * v[3];
#pragma unroll
  for (int off = 32; off; off >>= 1) { s1 += __shfl_xor(s1, off); s2 += __shfl_xor(s2, off); }
  float mu = s1 * (1.f / HD_);
  float rstd = rsqrtf(s2 * (1.f / HD_) - mu * mu + 1e-5f);
  float4 g4 = *(const float4*)(gnw + tid * 4);
  ushort4 xu = *(const ushort4*)(xp + (size_t)r * H_ + tid * 4);
  float o[4];
  o[0] = fmaf((v[0] - mu) * rstd, g4.x, bf2f(xu.x));
  o[1] = fmaf((v[1] - mu) * rstd, g4.y, bf2f(xu.y));
  o[2] = fmaf((v[2] - mu) * rstd, g4.z, bf2f(xu.z));
  o[3] = fmaf((v[3] - mu) * rstd, g4.w, bf2f(xu.w));
  float t1 = o[0] + o[1] + o[2] + o[3];
  float t2 = o[0] * o[0] + o[1] * o[1] + o[2] * o[2] + o[3] * o[3];
#pragma unroll
  for (int off = 32; off; off >>= 1) { t1 += __shfl_xor(t1, off); t2 += __shfl_xor(t2, off); }
  __shared__ float a1[4], a2[4];
  if (lane == 0) { a1[wave] = t1; a2[wave] = t2; }
  __syncthreads();
  float T1 = a1[0] + a1[1] + a1[2] + a1[3];
  float T2 = a2[0] + a2[1] + a2[2] + a2[3];
  float MU = T1 * (1.f / H_);
  float RS = rsqrtf(T2 * (1.f / H_) - MU * MU + 1e-5f);
  float4 w4 = *(const float4*)(lpw + tid * 4);
  ushort4 res = {f2bf((o[0] - MU) * RS * w4.x), f2bf((o[1] - MU) * RS * w4.y),
                 f2bf((o[2] - MU) * RS * w4.z), f2bf((o[3] - MU) * RS * w4.w)};
  *(ushort4*)(outb + (size_t)r * H_ + tid * 4) = res;
}

// ---------------- logits + value heads (bf16 in, fp32 out) ----------------
__global__ __launch_bounds__(256) void heads_k(
    const unsigned short* __restrict__ hp, const unsigned short* __restrict__ hv,
    const float* __restrict__ Wact, const float* __restrict__ bact,
    const float* __restrict__ Wv, const float* __restrict__ bv,
    float* __restrict__ dout) {
  const int lane = threadIdx.x & 63, wave = threadIdx.x >> 6;
  const int r = blockIdx.x * 4 + wave;
  const unsigned short* hpr = hp + (size_t)r * HID_;
  const unsigned short* hvr = hv + (size_t)r * HID_;
  float acc[A_];
#pragma unroll
  for (int j = 0; j < A_; ++j) acc[j] = 0.f;
  float accv = 0.f;
  for (int i = 0; i < 16; ++i) {
    int k = i * 64 + lane;
    float hpv = bf2f(hpr[k]);
    float hvv = bf2f(hvr[k]);
#pragma unroll
    for (int j = 0; j < A_; ++j) acc[j] = fmaf(hpv, Wact[j * HID_ + k], acc[j]);
    accv = fmaf(hvv, Wv[k], accv);
  }
#pragma unroll
  for (int j = 0; j < A_; ++j)
#pragma unroll
    for (int off = 32; off; off >>= 1) acc[j] += __shfl_xor(acc[j], off);
#pragma unroll
  for (int off = 32; off; off >>= 1) accv += __shfl_xor(accv, off);
  if (lane == 0) {
#pragma unroll
    for (int j = 0; j < A_; ++j) dout[(size_t)r * A_ + j] = acc[j] + bact[j];
    dout[589824 + r] = accv + bv[0];
  }
}

// ---------------- launch ----------------
extern "C" void kernel_launch(void* const* d_in, const int* in_sizes, int n_in,
                              void* d_out, int out_size, void* d_ws, size_t ws_size,
                              hipStream_t stream) {
  const float* obs   = (const float*)d_in[0];
  const float* st    = (const float*)d_in[1];
  const float* W_in  = (const float*)d_in[2];
  const float* b_in  = (const float*)d_in[3];
  const float* ln1w  = (const float*)d_in[4];
  const float* wg    = (const float*)d_in[5];
  const float* R     = (const float*)d_in[6];
  const float* bgat  = (const float*)d_in[7];
  const float* gnw   = (const float*)d_in[8];
  const float* lpw   = (const float*)d_in[9];
  const float* W_hid = (const float*)d_in[10];
  const float* b_hid = (const float*)d_in[11];
  const float* W_pol = (const float*)d_in[12];
  const float* b_pol = (const float*)d_in[13];
  const float* W_val = (const float*)d_in[14];
  const float* b_val = (const float*)d_in[15];
  const float* W_act = (const float*)d_in[16];
  const float* b_act = (const float*)d_in[17];
  const float* W_v   = (const float*)d_in[18];
  const float* b_v   = (const float*)d_in[19];

  // Workspace layout:
  //  A [0,        67108864): xproj bf16  -> hh bf16
  //  B [67108864, 134217728): gx chunk bf16 (T=128) -> outb bf16 -> hv bf16
  //  C [134217728,201326592): y bf16 -> hp bf16
  //  ST[201326592,202375168): scan state fp32 (h,c,n,m) 4x64x1024
  //  RS[202375168,202899456): LN1 row stats
  //  RB[202899456,204996608): R packed bf16 pairs (register part source)
  //  WG[204996608,207093760): w_gates bf16 [nh][g][e][k]
  //  RL[207093760,207618048): R LDS-part
  //  WI[207618048,208666624): W_in  bf16
  //  WH[208666624,210763776): W_hid bf16
  //  WP[210763776,212860928): W_pol bf16
  //  WV[212860928,214958080): W_val bf16
  const size_t NEEDED = 214958080;
  if (ws_size < NEEDED) return;
  char* ws = (char*)d_ws;
  unsigned short* xproj = (unsigned short*)(ws + 0);
  unsigned short* gxc   = (unsigned short*)(ws + 67108864);
  unsigned short* ybuf  = (unsigned short*)(ws + 134217728);
  float* statebuf       = (float*)(ws + 201326592);
  float* rstat          = (float*)(ws + 202375168);
  unsigned* Rbb         = (unsigned*)(ws + 202899456);
  unsigned short* wgb   = (unsigned short*)(ws + 204996608);
  unsigned* Rl          = (unsigned*)(ws + 207093760);
  unsigned short* wib   = (unsigned short*)(ws + 207618048);
  unsigned short* whb   = (unsigned short*)(ws + 208666624);
  unsigned short* wpb   = (unsigned short*)(ws + 210763776);
  unsigned short* wvb   = (unsigned short*)(ws + 212860928);
  unsigned short* outb  = gxc;
  unsigned short* hh    = xproj;
  unsigned short* hp    = ybuf;
  unsigned short* hv    = gxc;
  float* dout = (float*)d_out;

  hipMemcpyAsync(statebuf, st, 4 * 65536 * sizeof(float), hipMemcpyDeviceToDevice, stream);
  rtrans_k<<<2048, 256, 0, stream>>>(R, Rbb, Rl);
  wgt_k<<<4096, 256, 0, stream>>>(wg, wgb);
  wbf_k<<<2048, 256, 0, stream>>>(W_in, wib, 524288);
  wbf_k<<<4096, 256, 0, stream>>>(W_hid, whb, 1048576);
  wbf_k<<<4096, 256, 0, stream>>>(W_pol, wpb, 1048576);
  wbf_k<<<4096, 256, 0, stream>>>(W_val, wvb, 1048576);
  mgemm_k<0, 2, false, 0><<<dim3(256, 8), 256, 0, stream>>>(
      obs, wib, b_in, nullptr, nullptr, xproj, 512, 512, 0);
  rowstats_k<<<32768, 256, 0, stream>>>(xproj, rstat);
  for (int c = 0; c < NCH_; ++c) {
    mgemm_k<2, 1, false, 1><<<dim3(64, 2, 16), 256, 0, stream>>>(
        xproj, wgb, nullptr, rstat, ln1w, gxc, 256, 1024, c);
    scan_k<<<256, 512, 0, stream>>>(gxc, Rbb, Rl, bgat, statebuf, ybuf, c);
  }
  post_k<<<32768, 256, 0, stream>>>(ybuf, xproj, gnw, lpw, outb);
  mgemm_k<1, 2, true, 0><<<dim3(256, 8), 256, 0, stream>>>(
      outb, whb, b_hid, nullptr, nullptr, hh, 1024, 1024, 0);
  mgemm_k<1, 2, true, 0><<<dim3(256, 8), 256, 0, stream>>>(
      hh, wpb, b_pol, nullptr, nullptr, hp, 1024, 1024, 0);
  mgemm_k<1, 2, true, 0><<<dim3(256, 8), 256, 0, stream>>>(
      hh, wvb, b_val, nullptr, nullptr, hv, 1024, 1024, 0);
  heads_k<<<8192, 256, 0, stream>>>(hp, hv, W_act, b_act, W_v, b_v, dout);
}

// Round 13
// 2011.555 us; speedup vs baseline: 15.5532x; 1.0278x over previous
//
#include <hip/hip_runtime.h>
#include <cstdint>
#include <cstddef>

#define B_ 64
#define S_ 512
#define IN_ 512
#define H_ 1024
#define NH_ 4
#define HD_ 256
#define A_ 18
#define HID_ 1024
#define TCH_ 128            // scan time-chunk
#define NCH_ (S_ / TCH_)    // 4 chunks

using short8 = __attribute__((ext_vector_type(8))) short;
using f32x4  = __attribute__((ext_vector_type(4))) float;

// ---------------- helpers ----------------
__device__ __forceinline__ unsigned short f2bf(float f) {
  union { float f; unsigned u; } c; c.f = f;
  unsigned r = c.u + 0x7FFFu + ((c.u >> 16) & 1u);  // RNE
  return (unsigned short)(r >> 16);
}
__device__ __forceinline__ float bf2f(unsigned short h) {
  union { unsigned u; float f; } c; c.u = ((unsigned)h) << 16;
  return c.f;
}
__device__ __forceinline__ unsigned pk2(float a, float b) {
  return (unsigned)f2bf(a) | ((unsigned)f2bf(b) << 16);
}
// packed-bf16 dual-MAC, h operand in SGPR (VOP3P allows one scalar source).
// R stays per-lane in VGPR; h is wave-uniform (from v_readlane) -> scalar slot.
__device__ __forceinline__ float dot2s(unsigned r, unsigned h_sgpr, float c) {
  float d;
  asm("v_dot2_f32_bf16 %0, %1, %2, %3" : "=v"(d) : "v"(r), "s"(h_sgpr), "v"(c));
  return d;
}

// ---------------- R transcode: fp32 [nh][d][g][e] -> packed bf16 pairs ----------------
// Rbb[((nh*4+g)*256+e)*128 + dp] = pack(R[2dp], R[2dp+1])      (register part, dp<96)
// Rl flat uint: ((nh*1024+col)*8 + s)*4 + j  for dp = 96+4s+j  (LDS part, uint4-grouped)
__global__ __launch_bounds__(256) void rtrans_k(const float* __restrict__ R,
                                                unsigned* __restrict__ Rbb,
                                                unsigned* __restrict__ Rl) {
  const int i = blockIdx.x * 256 + threadIdx.x;   // [0, 524288)
  const int dp = i & 127;
  const int e = (i >> 7) & 255;
  const int g = (i >> 15) & 3;
  const int nh = i >> 17;
  const float* rp = R + (((size_t)nh * 256 + 2 * dp) * 4 + g) * 256 + e;  // d-stride 1024
  unsigned lo = f2bf(rp[0]), hi = f2bf(rp[1024]);
  unsigned v = lo | (hi << 16);
  Rbb[i] = v;
  if (dp >= 96) {
    int s = (dp - 96) >> 2, j = (dp - 96) & 3;
    int col = g * 256 + e;
    Rl[((size_t)(nh * 1024 + col) * 8 + s) * 4 + j] = v;
  }
}

// ---------------- w_gates transcode: fp32 [g][nh][d][e] -> bf16 [nh][g][e][d] ----------------
__global__ __launch_bounds__(256) void wgt_k(const float* __restrict__ wg,
                                             unsigned short* __restrict__ wgb) {
  const int i = blockIdx.x * 256 + threadIdx.x;   // [0, 1048576)
  const int k = i & 255;
  const int e = (i >> 8) & 255;
  const int g = (i >> 16) & 3;
  const int nh = i >> 18;
  wgb[i] = f2bf(wg[(((size_t)(g * 4 + nh) * 256 + k) * 256) + e]);
}

// ---------------- generic fp32 -> bf16 weight transcode (layout-preserving) ----------------
__global__ __launch_bounds__(256) void wbf_k(const float* __restrict__ src,
                                             unsigned short* __restrict__ dst, int n) {
  int i = blockIdx.x * 256 + threadIdx.x;
  if (i < n) dst[i] = f2bf(src[i]);
}

// ---------------- row stats for LN1 fusion (xproj is bf16) ----------------
__global__ __launch_bounds__(256) void rowstats_k(const unsigned short* __restrict__ x,
                                                  float* __restrict__ rs) {
  const int r = blockIdx.x, tid = threadIdx.x;
  const int lane = tid & 63, wave = tid >> 6;
  ushort4 u = *(const ushort4*)(x + (size_t)r * H_ + tid * 4);
  float v0 = bf2f(u.x), v1 = bf2f(u.y), v2 = bf2f(u.z), v3 = bf2f(u.w);
  float s1 = v0 + v1 + v2 + v3;
  float s2 = v0 * v0 + v1 * v1 + v2 * v2 + v3 * v3;
#pragma unroll
  for (int off = 32; off; off >>= 1) { s1 += __shfl_xor(s1, off); s2 += __shfl_xor(s2, off); }
  __shared__ float a1[4], a2[4];
  if (lane == 0) { a1[wave] = s1; a2[wave] = s2; }
  __syncthreads();
  if (tid == 0) {
    float S1 = a1[0] + a1[1] + a1[2] + a1[3];
    float S2 = a2[0] + a2[1] + a2[2] + a2[3];
    float mu = S1 * (1.f / H_);
    float var = S2 * (1.f / H_) - mu * mu;
    rs[r * 2] = mu;
    rs[r * 2 + 1] = rsqrtf(var + 1e-5f);
  }
}

// ---------------- MFMA bf16 GEMM, 128x128 tile, BK=32, 4 waves of 64x64 ----------------
// AMODE: 0 = A fp32 (cvt), 1 = A bf16, 2 = A bf16 + fused LN
// BMODE: 0 = W fp32 (N,K), 1 = W bf16 gate-layout [col][256], 2 = W bf16 (N,K) stride K
template <int AMODE, int BMODE, bool RELU, int OUTMODE>
__global__ __launch_bounds__(256) void mgemm_k(
    const void* __restrict__ Av, const void* __restrict__ Wv,
    const float* __restrict__ bias, const float* __restrict__ rs,
    const float* __restrict__ lnw, unsigned short* __restrict__ Cb,
    int K, int lda, int chunk) {
  __shared__ uint4 As4[4][128];
  __shared__ uint4 Bs4[4][128];
  const int tid = threadIdx.x;
  const int lane = tid & 63, wave = tid >> 6;
  const int wr = wave >> 1, wc = wave & 1;
  const int col0 = blockIdx.y * 128;
  int nh = 0, g = 0, aoff = 0, bb = 0;
  size_t wbase = 0;
  if constexpr (OUTMODE == 1) {
    int z = blockIdx.z; nh = z >> 2; g = z & 3;
    aoff = nh * HD_;
    bb = blockIdx.x;
    wbase = (size_t)(nh * 4 + g) * 256 * 256;
  }
  auto arow = [&](int mm) -> int {
    if constexpr (OUTMODE == 1) return bb * 512 + chunk * TCH_ + mm;
    else return (int)blockIdx.x * 128 + mm;
  };
  f32x4 acc[4][4];
#pragma unroll
  for (int m = 0; m < 4; ++m)
#pragma unroll
    for (int n = 0; n < 4; ++n) acc[m][n] = 0.f;

  const int sm = tid >> 1;   // staging row
  const int sh = tid & 1;    // k half (16 elems)

  for (int k0 = 0; k0 < K; k0 += 32) {
    {
      int rg = arow(sm);
      unsigned pk[8];
      if constexpr (AMODE == 0) {
        const float* ap = (const float*)Av + (size_t)rg * lda + k0 + sh * 16;
#pragma unroll
        for (int q = 0; q < 4; ++q) {
          float4 f = ((const float4*)ap)[q];
          pk[2 * q] = pk2(f.x, f.y); pk[2 * q + 1] = pk2(f.z, f.w);
        }
      } else if constexpr (AMODE == 1) {
        const uint4* ap = (const uint4*)((const unsigned short*)Av + (size_t)rg * lda + aoff + k0 + sh * 16);
        uint4 u0 = ap[0], u1 = ap[1];
        pk[0] = u0.x; pk[1] = u0.y; pk[2] = u0.z; pk[3] = u0.w;
        pk[4] = u1.x; pk[5] = u1.y; pk[6] = u1.z; pk[7] = u1.w;
      } else {
        const uint4* ap = (const uint4*)((const unsigned short*)Av + (size_t)rg * lda + aoff + k0 + sh * 16);
        uint4 u0 = ap[0], u1 = ap[1];
        unsigned w8[8] = {u0.x, u0.y, u0.z, u0.w, u1.x, u1.y, u1.z, u1.w};
        float mu = rs[rg * 2], rstd = rs[rg * 2 + 1];
        const float* lw = lnw + aoff + k0 + sh * 16;
#pragma unroll
        for (int q = 0; q < 8; ++q) {
          float lo = (bf2f((unsigned short)w8[q]) - mu) * rstd * lw[2 * q];
          float hi = (bf2f((unsigned short)(w8[q] >> 16)) - mu) * rstd * lw[2 * q + 1];
          pk[q] = pk2(lo, hi);
        }
      }
      As4[2 * sh][sm]     = uint4{pk[0], pk[1], pk[2], pk[3]};
      As4[2 * sh + 1][sm] = uint4{pk[4], pk[5], pk[6], pk[7]};
    }
    {
      unsigned pk[8];
      if constexpr (BMODE == 0) {
        const float* wp = (const float*)Wv + (size_t)(col0 + sm) * K + k0 + sh * 16;
#pragma unroll
        for (int q = 0; q < 4; ++q) {
          float4 f = ((const float4*)wp)[q];
          pk[2 * q] = pk2(f.x, f.y); pk[2 * q + 1] = pk2(f.z, f.w);
        }
      } else if constexpr (BMODE == 1) {
        const uint4* wp = (const uint4*)((const unsigned short*)Wv + wbase + (size_t)(col0 + sm) * 256 + k0 + sh * 16);
        uint4 u0 = wp[0], u1 = wp[1];
        pk[0] = u0.x; pk[1] = u0.y; pk[2] = u0.z; pk[3] = u0.w;
        pk[4] = u1.x; pk[5] = u1.y; pk[6] = u1.z; pk[7] = u1.w;
      } else {
        const uint4* wp = (const uint4*)((const unsigned short*)Wv + (size_t)(col0 + sm) * K + k0 + sh * 16);
        uint4 u0 = wp[0], u1 = wp[1];
        pk[0] = u0.x; pk[1] = u0.y; pk[2] = u0.z; pk[3] = u0.w;
        pk[4] = u1.x; pk[5] = u1.y; pk[6] = u1.z; pk[7] = u1.w;
      }
      Bs4[2 * sh][sm]     = uint4{pk[0], pk[1], pk[2], pk[3]};
      Bs4[2 * sh + 1][sm] = uint4{pk[4], pk[5], pk[6], pk[7]};
    }
    __syncthreads();
    short8 af[4], bfv[4];
#pragma unroll
    for (int m = 0; m < 4; ++m)
      af[m] = *(const short8*)&As4[lane >> 4][wr * 64 + m * 16 + (lane & 15)];
#pragma unroll
    for (int n = 0; n < 4; ++n)
      bfv[n] = *(const short8*)&Bs4[lane >> 4][wc * 64 + n * 16 + (lane & 15)];
#pragma unroll
    for (int m = 0; m < 4; ++m)
#pragma unroll
      for (int n = 0; n < 4; ++n)
        acc[m][n] = __builtin_amdgcn_mfma_f32_16x16x32_bf16(af[m], bfv[n], acc[m][n], 0, 0, 0);
    __syncthreads();
  }
  if constexpr (OUTMODE == 0) {
#pragma unroll
    for (int n = 0; n < 4; ++n) {
      int c = col0 + wc * 64 + n * 16 + (lane & 15);
      float bc = bias ? bias[c] : 0.f;
#pragma unroll
      for (int m = 0; m < 4; ++m) {
        int r0 = arow(wr * 64 + m * 16 + ((lane >> 4) << 2));
#pragma unroll
        for (int i = 0; i < 4; ++i) {
          float v = acc[m][n][i] + bc;
          if constexpr (RELU) v = fmaxf(v, 0.f);
          Cb[(size_t)(r0 + i) * 1024 + c] = f2bf(v);
        }
      }
    }
  } else {
#pragma unroll
    for (int n = 0; n < 4; ++n) {
      int e = col0 + wc * 64 + n * 16 + (lane & 15);
#pragma unroll
      for (int m = 0; m < 4; ++m) {
        int sl0 = wr * 64 + m * 16 + ((lane >> 4) << 2);
#pragma unroll
        for (int i = 0; i < 4; ++i) {
          int sl = sl0 + i;
          size_t base = (size_t)(sl * 64 + bb) * 4096 + nh * 1024 + g * 256;
          Cb[base + e] = f2bf(acc[m][n][i]);
        }
      }
    }
  }
}

// ---------------- sLSTM scan: zero-exchange, 512 thr x 2 cols, register-broadcast h ----------
// Round-13: the scan was LDS-pipe-bound (8 waves x 64 LDS reads/step ~ 1.9us of the 2.8us
// step). h-broadcast now goes through registers: each lane does ONE ds_read_b128 of its
// own 16B h-chunk; v_readlane lifts chunk q to SGPRs; dot2 consumes the SGPR directly
// (VOP3P scalar slot). LDS per thread per step: 64 -> 17 instructions.
__global__ __launch_bounds__(512, 2) void scan_k(
    const unsigned short* __restrict__ gxc, const unsigned* __restrict__ Rbb,
    const unsigned* __restrict__ Rl, const float* __restrict__ bgates,
    float* __restrict__ state, unsigned short* __restrict__ y, int chunk) {
  const int tid = threadIdx.x;
  const int lane = tid & 63;
  const int bid = blockIdx.x;
  const int nh = bid >> 6, b = bid & 63;
  const int col0 = tid, col1 = tid + 512;
  const int g0 = col0 >> 8, g1 = col1 >> 8;        // wave-uniform
  __shared__ uint4 Rlds4[8][1024];                 // 128KB: R dp 96..127, [s][col]
  __shared__ float rawf[1024];                     // transformed raw[g*256+e]
  __shared__ alignas(16) unsigned short hsu[256];  // h packed bf16 (32 uint4 chunks)

  // fill Rlds4: 8192 uint4 by 512 threads = 16 iters; global flat = nh*8192 + idx (coalesced)
#pragma unroll
  for (int it = 0; it < 16; ++it) {
    int idx = it * 512 + tid;
    Rlds4[idx & 7][idx >> 3] = ((const uint4*)Rl)[(size_t)nh * 8192 + idx];
  }
  // register R for both columns: dp 0..95 each
  unsigned rc0[96], rc1[96];
  {
    const unsigned* rp0 = Rbb + ((size_t)nh * 1024 + col0) * 128;
    const unsigned* rp1 = Rbb + ((size_t)nh * 1024 + col1) * 128;
#pragma unroll
    for (int i = 0; i < 96; ++i) rc0[i] = rp0[i];
#pragma unroll
    for (int i = 0; i < 96; ++i) rc1[i] = rp1[i];
  }
  const float bg0 = bgates[g0 * H_ + nh * HD_ + (col0 & 255)];
  const float bg1 = bgates[g1 * H_ + nh * HD_ + (col1 & 255)];

  const size_t sbase = (size_t)b * H_ + nh * HD_ + tid;
  float c_ = 0.f, n_ = 0.f, m_ = 0.f, hlast = 0.f;
  if (tid < 256) {
    hlast = state[sbase];
    c_ = state[65536 + sbase];
    n_ = state[2 * 65536 + sbase];
    m_ = state[3 * 65536 + sbase];
    hsu[tid] = f2bf(hlast);
  }
  __syncthreads();

  const unsigned short* gp0 = gxc + ((size_t)b * 4 + nh) * 1024 + col0;
  const unsigned short* gp1 = gp0 + 512;
  unsigned short* yp = y + ((size_t)(chunk * TCH_) * 64 + b) * H_ + nh * HD_;

  unsigned short gc0 = gp0[0], gc1 = gp1[0];

  for (int t = 0; t < TCH_; ++t) {
    float a0a = bf2f(gc0) + bg0, a0b = 0.f;        // 4 independent dot2 chains
    float a1a = bf2f(gc1) + bg1, a1b = 0.f;
    if (t < TCH_ - 1) {  // prefetch under matvec
      gc0 = gp0[(size_t)(t + 1) * 262144];
      gc1 = gp1[(size_t)(t + 1) * 262144];
    }
    // ONE LDS read of this lane's h chunk; chunks are duplicated across half-waves
    uint4 hc = ((const uint4*)hsu)[lane & 31];
    // register part: chunks q=0..23 (dp = 4q+j), h via readlane -> SGPR
#pragma unroll
    for (int q = 0; q < 24; ++q) {
      unsigned h0 = __builtin_amdgcn_readlane(hc.x, q);
      unsigned h1 = __builtin_amdgcn_readlane(hc.y, q);
      unsigned h2 = __builtin_amdgcn_readlane(hc.z, q);
      unsigned h3 = __builtin_amdgcn_readlane(hc.w, q);
      a0a = dot2s(rc0[4 * q + 0], h0, a0a);
      a1a = dot2s(rc1[4 * q + 0], h0, a1a);
      a0a = dot2s(rc0[4 * q + 1], h1, a0a);
      a1a = dot2s(rc1[4 * q + 1], h1, a1a);
      a0b = dot2s(rc0[4 * q + 2], h2, a0b);
      a1b = dot2s(rc1[4 * q + 2], h2, a1b);
      a0b = dot2s(rc0[4 * q + 3], h3, a0b);
      a1b = dot2s(rc1[4 * q + 3], h3, a1b);
    }
    // LDS part: chunks q=24..31 (dp = 96+4s+j), R from Rlds4 (b128)
#pragma unroll
    for (int s = 0; s < 8; ++s) {
      int q = 24 + s;
      unsigned h0 = __builtin_amdgcn_readlane(hc.x, q);
      unsigned h1 = __builtin_amdgcn_readlane(hc.y, q);
      unsigned h2 = __builtin_amdgcn_readlane(hc.z, q);
      unsigned h3 = __builtin_amdgcn_readlane(hc.w, q);
      uint4 ra = Rlds4[s][col0];
      uint4 rb = Rlds4[s][col1];
      a0a = dot2s(ra.x, h0, a0a);
      a1a = dot2s(rb.x, h0, a1a);
      a0a = dot2s(ra.y, h1, a0a);
      a1a = dot2s(rb.y, h1, a1a);
      a0b = dot2s(ra.z, h2, a0b);
      a1b = dot2s(rb.z, h2, a1b);
      a0b = dot2s(ra.w, h3, a0b);
      a1b = dot2s(rb.w, h3, a1b);
    }
    float acc0 = a0a + a0b;
    float acc1 = a1a + a1b;
    // gate-local transforms (wave-uniform branches)
    float val0, val1;
    if (g0 == 0) {
      val0 = acc0;                                  // iraw
    } else {
      float ls = -log1pf(expf(-fabsf(acc0)));       // log_sigmoid(fraw)
      if (acc0 < 0.f) ls += acc0;
      val0 = ls;
    }
    if (g1 == 2) {
      val1 = tanhf(acc1);                           // tanh(zraw)
    } else {
      val1 = 1.f / (1.f + expf(-acc1));             // sigmoid(oraw)
    }
    rawf[col0] = val0;
    rawf[col1] = val1;
    __syncthreads();
    if (tid < 256) {   // owner: 2 exp + mul/div
      float iraw = rawf[tid];
      float ls   = rawf[256 + tid];
      float tz   = rawf[512 + tid];
      float sg   = rawf[768 + tid];
      float lfm = m_ + ls;
      float mnew = fmaxf(iraw, lfm);
      float iv = expf(iraw - mnew);
      float fv = expf(lfm - mnew);
      c_ = fv * c_ + iv * tz;
      n_ = fv * n_ + iv;
      m_ = mnew;
      hlast = sg * c_ / n_;
      unsigned short hb = f2bf(hlast);
      hsu[tid] = hb;
      yp[(size_t)t * 65536 + tid] = hb;            // y[s][b][h] bf16
    }
    __syncthreads();
  }
  if (tid < 256) {
    state[sbase] = hlast;
    state[65536 + sbase] = c_;
    state[2 * 65536 + sbase] = n_;
    state[3 * 65536 + sbase] = m_;
  }
}

// ---------------- groupnorm + residual + post LN (bf16 in/out) ----------------
__global__ __launch_bounds__(256) void post_k(
    const unsigned short* __restrict__ y, const unsigned short* __restrict__ xp,
    const float* __restrict__ gnw, const float* __restrict__ lpw,
    unsigned short* __restrict__ outb) {
  const int r = blockIdx.x;            // r = b*512 + s
  const int b = r >> 9, s = r & 511;
  const int tid = threadIdx.x;
  const int lane = tid & 63, wave = tid >> 6;
  ushort4 yu = *(const ushort4*)(y + (size_t)(s * 64 + b) * H_ + tid * 4);
  float v[4] = {bf2f(yu.x), bf2f(yu.y), bf2f(yu.z), bf2f(yu.w)};
  float s1 = v[0] + v[1] + v[2] + v[3];
  float s2 = v[0] * v[0] + v[1] * v[1] + v[2] * v[2] + v[3] * v[3];
#pragma unroll
  for (int off = 32; off; off >>= 1) { s1 += __shfl_xor(s1, off); s2 += __shfl_xor(s2, off); }
  float mu = s1 * (1.f / HD_);
  float rstd = rsqrtf(s2 * (1.f / HD_) - mu * mu + 1e-5f);
  float4 g4 = *(const float4*)(gnw + tid * 4);
  ushort4 xu = *(const ushort4*)(xp + (size_t)r * H_ + tid * 4);
  float o[4];
  o[0] = fmaf((v[0] - mu) * rstd, g4.x, bf2f(xu.x));
  o[1] = fmaf((v[1] - mu) * rstd, g4.y, bf2f(xu.y));
  o[2] = fmaf((v[2] - mu) * rstd, g4.z, bf2f(xu.z));
  o[3] = fmaf((v[3] - mu) * rstd, g4.w, bf2f(xu.w));
  float t1 = o[0] + o[1] + o[2] + o[3];
  float t2 = o[0] * o[0] + o[1] * o[1] + o[2] * o[2] + o[3] * o[3];
#pragma unroll
  for (int off = 32; off; off >>= 1) { t1 += __shfl_xor(t1, off); t2 += __shfl_xor(t2, off); }
  __shared__ float a1[4], a2[4];
  if (lane == 0) { a1[wave] = t1; a2[wave] = t2; }
  __syncthreads();
  float T1 = a1[0] + a1[1] + a1[2] + a1[3];
  float T2 = a2[0] + a2[1] + a2[2] + a2[3];
  float MU = T1 * (1.f / H_);
  float RS = rsqrtf(T2 * (1.f / H_) - MU * MU + 1e-5f);
  float4 w4 = *(const float4*)(lpw + tid * 4);
  ushort4 res = {f2bf((o[0] - MU) * RS * w4.x), f2bf((o[1] - MU) * RS * w4.y),
                 f2bf((o[2] - MU) * RS * w4.z), f2bf((o[3] - MU) * RS * w4.w)};
  *(ushort4*)(outb + (size_t)r * H_ + tid * 4) = res;
}

// ---------------- logits + value heads (bf16 in, fp32 out) ----------------
__global__ __launch_bounds__(256) void heads_k(
    const unsigned short* __restrict__ hp, const unsigned short* __restrict__ hv,
    const float* __restrict__ Wact, const float* __restrict__ bact,
    const float* __restrict__ Wv, const float* __restrict__ bv,
    float* __restrict__ dout) {
  const int lane = threadIdx.x & 63, wave = threadIdx.x >> 6;
  const int r = blockIdx.x * 4 + wave;
  const unsigned short* hpr = hp + (size_t)r * HID_;
  const unsigned short* hvr = hv + (size_t)r * HID_;
  float acc[A_];
#pragma unroll
  for (int j = 0; j < A_; ++j) acc[j] = 0.f;
  float accv = 0.f;
  for (int i = 0; i < 16; ++i) {
    int k = i * 64 + lane;
    float hpv = bf2f(hpr[k]);
    float hvv = bf2f(hvr[k]);
#pragma unroll
    for (int j = 0; j < A_; ++j) acc[j] = fmaf(hpv, Wact[j * HID_ + k], acc[j]);
    accv = fmaf(hvv, Wv[k], accv);
  }
#pragma unroll
  for (int j = 0; j < A_; ++j)
#pragma unroll
    for (int off = 32; off; off >>= 1) acc[j] += __shfl_xor(acc[j], off);
#pragma unroll
  for (int off = 32; off; off >>= 1) accv += __shfl_xor(accv, off);
  if (lane == 0) {
#pragma unroll
    for (int j = 0; j < A_; ++j) dout[(size_t)r * A_ + j] = acc[j] + bact[j];
    dout[589824 + r] = accv + bv[0];
  }
}

// ---------------- launch ----------------
extern "C" void kernel_launch(void* const* d_in, const int* in_sizes, int n_in,
                              void* d_out, int out_size, void* d_ws, size_t ws_size,
                              hipStream_t stream) {
  const float* obs   = (const float*)d_in[0];
  const float* st    = (const float*)d_in[1];
  const float* W_in  = (const float*)d_in[2];
  const float* b_in  = (const float*)d_in[3];
  const float* ln1w  = (const float*)d_in[4];
  const float* wg    = (const float*)d_in[5];
  const float* R     = (const float*)d_in[6];
  const float* bgat  = (const float*)d_in[7];
  const float* gnw   = (const float*)d_in[8];
  const float* lpw   = (const float*)d_in[9];
  const float* W_hid = (const float*)d_in[10];
  const float* b_hid = (const float*)d_in[11];
  const float* W_pol = (const float*)d_in[12];
  const float* b_pol = (const float*)d_in[13];
  const float* W_val = (const float*)d_in[14];
  const float* b_val = (const float*)d_in[15];
  const float* W_act = (const float*)d_in[16];
  const float* b_act = (const float*)d_in[17];
  const float* W_v   = (const float*)d_in[18];
  const float* b_v   = (const float*)d_in[19];

  // Workspace layout (identical offsets to round 12):
  //  A [0,        67108864): xproj bf16  -> hh bf16
  //  B [67108864, 134217728): gx chunk bf16 (T=128) -> outb bf16 -> hv bf16
  //  C [134217728,201326592): y bf16 -> hp bf16
  //  ST[201326592,202375168): scan state fp32 (h,c,n,m) 4x64x1024
  //  RS[202375168,202899456): LN1 row stats
  //  RB[202899456,204996608): R packed bf16 pairs (register part source)
  //  WG[204996608,207093760): w_gates bf16 [nh][g][e][k]
  //  RL[207093760,207618048): R LDS-part (uint4-grouped)
  //  WI[207618048,208666624): W_in  bf16
  //  WH[208666624,210763776): W_hid bf16
  //  WP[210763776,212860928): W_pol bf16
  //  WV[212860928,214958080): W_val bf16
  const size_t NEEDED = 214958080;
  if (ws_size < NEEDED) return;
  char* ws = (char*)d_ws;
  unsigned short* xproj = (unsigned short*)(ws + 0);
  unsigned short* gxc   = (unsigned short*)(ws + 67108864);
  unsigned short* ybuf  = (unsigned short*)(ws + 134217728);
  float* statebuf       = (float*)(ws + 201326592);
  float* rstat          = (float*)(ws + 202375168);
  unsigned* Rbb         = (unsigned*)(ws + 202899456);
  unsigned short* wgb   = (unsigned short*)(ws + 204996608);
  unsigned* Rl          = (unsigned*)(ws + 207093760);
  unsigned short* wib   = (unsigned short*)(ws + 207618048);
  unsigned short* whb   = (unsigned short*)(ws + 208666624);
  unsigned short* wpb   = (unsigned short*)(ws + 210763776);
  unsigned short* wvb   = (unsigned short*)(ws + 212860928);
  unsigned short* outb  = gxc;
  unsigned short* hh    = xproj;
  unsigned short* hp    = ybuf;
  unsigned short* hv    = gxc;
  float* dout = (float*)d_out;

  hipMemcpyAsync(statebuf, st, 4 * 65536 * sizeof(float), hipMemcpyDeviceToDevice, stream);
  rtrans_k<<<2048, 256, 0, stream>>>(R, Rbb, Rl);
  wgt_k<<<4096, 256, 0, stream>>>(wg, wgb);
  wbf_k<<<2048, 256, 0, stream>>>(W_in, wib, 524288);
  wbf_k<<<4096, 256, 0, stream>>>(W_hid, whb, 1048576);
  wbf_k<<<4096, 256, 0, stream>>>(W_pol, wpb, 1048576);
  wbf_k<<<4096, 256, 0, stream>>>(W_val, wvb, 1048576);
  mgemm_k<0, 2, false, 0><<<dim3(256, 8), 256, 0, stream>>>(
      obs, wib, b_in, nullptr, nullptr, xproj, 512, 512, 0);
  rowstats_k<<<32768, 256, 0, stream>>>(xproj, rstat);
  for (int c = 0; c < NCH_; ++c) {
    mgemm_k<2, 1, false, 1><<<dim3(64, 2, 16), 256, 0, stream>>>(
        xproj, wgb, nullptr, rstat, ln1w, gxc, 256, 1024, c);
    scan_k<<<256, 512, 0, stream>>>(gxc, Rbb, Rl, bgat, statebuf, ybuf, c);
  }
  post_k<<<32768, 256, 0, stream>>>(ybuf, xproj, gnw, lpw, outb);
  mgemm_k<1, 2, true, 0><<<dim3(256, 8), 256, 0, stream>>>(
      outb, whb, b_hid, nullptr, nullptr, hh, 1024, 1024, 0);
  mgemm_k<1, 2, true, 0><<<dim3(256, 8), 256, 0, stream>>>(
      hh, wpb, b_pol, nullptr, nullptr, hp, 1024, 1024, 0);
  mgemm_k<1, 2, true, 0><<<dim3(256, 8), 256, 0, stream>>>(
      hh, wvb, b_val, nullptr, nullptr, hv, 1024, 1024, 0);
  heads_k<<<8192, 256, 0, stream>>>(hp, hv, W_act, b_act, W_v, b_v, dout);
}